// Round 1
// baseline (491.527 us; speedup 1.0000x reference)
//
#include <hip/hip_runtime.h>
#include <math.h>

// Problem constants: B=8, H=W=56, C=512, N=3136, c4=128, HEADS=8, hd=64, SR=2
// kv sequence length = 14*14 = 196 (padded to 224 for attention)

typedef _Float16 half8 __attribute__((ext_vector_type(8)));
typedef _Float16 half4v __attribute__((ext_vector_type(4)));
typedef float f32x4 __attribute__((ext_vector_type(4)));

// ---------------- workspace layout (offsets in halves; all 16B-aligned) ----
static const size_t OFF_X16  = 0;          // 25088*512 (dead after q/r gemms; reused as conv partials 0,1)
static const size_t OFF_Q16  = 12845056;   // 25088*512
static const size_t OFF_CAT  = 25690112;   // 25088*640
static const size_t OFF_R16  = 41746432;   // 25088*128
static const size_t OFF_PAD  = 44957696;   // 8*900*512  (30x30 zero-padded DWT)
static const size_t OFF_DWTB = 48644096;   // 8*784*512
static const size_t OFF_KVIN = 51855360;   // 1568*512 floats = 3,211,264 halves
static const size_t OFF_LN16 = 55066624;   // 1568*512
static const size_t OFF_KV16 = 55869440;   // 1568*1024
static const size_t OFF_WT   = 57475072;   // 512*4608
static const size_t OFF_KT   = 59834368;   // 512*2048
static const size_t OFF_QW   = 60882944;   // 512*512
static const size_t OFF_KVW  = 61145088;   // 1024*512
static const size_t OFF_PW   = 61669376;   // 512*640
static const size_t OFF_RW   = 61997056;   // 128*512
static const size_t OFF_VT   = 62062592;   // 8*8*64*224 = 917504 (V^T, m-padded)
static const size_t OFF_PART = 62980096;   // conv partials 2,3: 2*3,211,264 floats
// total = 75,825,152 halves = 151.7 MB (<= 153.9 MB proven available in R1)

#define BN_RSQ 0.9999950000374997f
#define SCL2   0.1803368801111204f   /* 0.125 * log2(e) */
#define PART_STRIDE 3211264          /* 6272*512 floats per conv partial */

__device__ __forceinline__ void async_copy16(const _Float16* g, _Float16* l) {
    __builtin_amdgcn_global_load_lds(
        (const __attribute__((address_space(1))) void*)g,
        (__attribute__((address_space(3))) void*)l, 16, 0, 0);
}

// =====================================================================
// MFMA fp16 NT GEMM: out[m][n] = sum_k A[m][k]*W[n][k] (+ epilogue)
// ALOAD: 0 plain row-major (lda), 2 kve 2x2 stride-2 on 28x28x512 NHWC
// EPI:   0 = +bias -> fp32, 1 = +bias,BN,ReLU -> fp16, 2 = +bias -> fp16
// 128x128 tile, BK=32, 256 threads (4 waves 2x2), 16x16x32 MFMA.
// =====================================================================
template <int ALOAD, int EPI>
__global__ __launch_bounds__(256) void gemm16(
    const _Float16* __restrict__ A, const _Float16* __restrict__ W,
    void* __restrict__ outp, int M, int K, int lda, int ldc,
    const float* __restrict__ bias, const float* __restrict__ bng,
    const float* __restrict__ bnb)
{
    __shared__ _Float16 sA[128 * 32];
    __shared__ _Float16 sB[128 * 32];
    const int t = threadIdx.x;
    const int lane = t & 63, wid = t >> 6;
    const int m0 = blockIdx.x * 128, n0 = blockIdx.y * 128;

    const int sr = wid * 16 + (lane >> 2);   // staging tile row (instr0)
    const int sc = (lane & 3) * 8;           // staging col offset (halves)
    _Float16* ldsA0 = sA + wid * 512;
    _Float16* ldsA1 = sA + 2048 + wid * 512;
    _Float16* ldsB0 = sB + wid * 512;
    _Float16* ldsB1 = sB + 2048 + wid * 512;

    const _Float16 *aP0, *aP1;
    if constexpr (ALOAD == 0) {
        int r0 = m0 + sr;      if (r0 > M - 1) r0 = M - 1;
        int r1 = m0 + 64 + sr; if (r1 > M - 1) r1 = M - 1;
        aP0 = A + (size_t)r0 * lda + sc;
        aP1 = A + (size_t)r1 * lda + sc;
    } else {
        int m_ = m0 + sr; if (m_ > M - 1) m_ = M - 1;
        int b_ = m_ / 196, rem = m_ - b_ * 196, i_ = rem / 14, j_ = rem - i_ * 14;
        aP0 = A + ((size_t)(b_ * 784 + 2 * i_ * 28 + 2 * j_)) * 512 + sc;
        m_ = m0 + 64 + sr; if (m_ > M - 1) m_ = M - 1;
        b_ = m_ / 196; rem = m_ - b_ * 196; i_ = rem / 14; j_ = rem - i_ * 14;
        aP1 = A + ((size_t)(b_ * 784 + 2 * i_ * 28 + 2 * j_)) * 512 + sc;
    }
    const _Float16* bP0 = W + (size_t)(n0 + sr) * K + sc;
    const _Float16* bP1 = W + (size_t)(n0 + 64 + sr) * K + sc;

    const int mw = wid & 1, nw = wid >> 1;
    const _Float16* pA = sA + (mw * 64 + (lane & 15)) * 32 + (lane >> 4) * 8;
    const _Float16* pB = sB + (nw * 64 + (lane & 15)) * 32 + (lane >> 4) * 8;

    f32x4 acc[4][4];
#pragma unroll
    for (int i = 0; i < 4; ++i)
#pragma unroll
        for (int j = 0; j < 4; ++j) acc[i][j] = (f32x4)(0.0f);

    for (int k0 = 0; k0 < K; k0 += 32) {
        int aOff;
        if constexpr (ALOAD == 0) {
            aOff = k0;
        } else {
            int sub = k0 >> 9; int ky = sub >> 1, kx = sub & 1;
            aOff = (ky * 28 + kx) * 512 + (k0 & 511);
        }
        __syncthreads();   // prior iteration's ds_reads done before overwrite
        async_copy16(aP0 + aOff, ldsA0);
        async_copy16(aP1 + aOff, ldsA1);
        async_copy16(bP0 + k0, ldsB0);
        async_copy16(bP1 + k0, ldsB1);
        __syncthreads();   // vmcnt(0) drain -> staged data visible

        half8 aF[4], bF[4];
#pragma unroll
        for (int i = 0; i < 4; ++i) aF[i] = *(const half8*)(pA + i * 512);
#pragma unroll
        for (int j = 0; j < 4; ++j) bF[j] = *(const half8*)(pB + j * 512);
#pragma unroll
        for (int i = 0; i < 4; ++i)
#pragma unroll
            for (int j = 0; j < 4; ++j)
                acc[i][j] = __builtin_amdgcn_mfma_f32_16x16x32_f16(
                    aF[i], bF[j], acc[i][j], 0, 0, 0);
    }

    // epilogue: C/D layout col=lane&15, row=(lane>>4)*4+reg
    const int orow = m0 + mw * 64 + (lane >> 4) * 4;
    const int ocol = n0 + nw * 64 + (lane & 15);
#pragma unroll
    for (int j = 0; j < 4; ++j) {
        int col = ocol + j * 16;
        float bv = bias[col];
        float g = 0.0f, b2 = 0.0f;
        if constexpr (EPI == 1) { g = bng[col] * BN_RSQ; b2 = bnb[col]; }
#pragma unroll
        for (int i = 0; i < 4; ++i) {
#pragma unroll
            for (int r = 0; r < 4; ++r) {
                int row = orow + i * 16 + r;
                if (row >= M) continue;
                float v = acc[i][j][r] + bv;
                if constexpr (EPI == 1) v = fmaxf(v * g + b2, 0.0f);
                if constexpr (EPI == 0)
                    ((float*)outp)[(size_t)row * ldc + col] = v;
                else
                    ((_Float16*)outp)[(size_t)row * ldc + col] = (_Float16)v;
            }
        }
    }
}

// =====================================================================
// conv3x3 split-K partial GEMM: grid (49, 4, 4); K-group bz covers
// k in [bz*1152, (bz+1)*1152). Writes fp32 partial (no bias).
// A = padded 30x30x512 NHWC fp16; W = wT[n][(ky*3+kx)*512+ci].
// =====================================================================
__global__ __launch_bounds__(256) void conv_splitk(
    const _Float16* __restrict__ A, const _Float16* __restrict__ W,
    float* __restrict__ partA, float* __restrict__ partB)
{
    __shared__ _Float16 sA[128 * 32];
    __shared__ _Float16 sB[128 * 32];
    const int t = threadIdx.x;
    const int lane = t & 63, wid = t >> 6;
    const int m0 = blockIdx.x * 128, n0 = blockIdx.y * 128;
    const int kbase = blockIdx.z * 1152;

    const int sr = wid * 16 + (lane >> 2);
    const int sc = (lane & 3) * 8;
    _Float16* ldsA0 = sA + wid * 512;
    _Float16* ldsA1 = sA + 2048 + wid * 512;
    _Float16* ldsB0 = sB + wid * 512;
    _Float16* ldsB1 = sB + 2048 + wid * 512;

    int m_ = m0 + sr;
    int b_ = m_ / 784, rem = m_ - b_ * 784, y_ = rem / 28, x_ = rem - y_ * 28;
    const _Float16* aP0 = A + ((size_t)(b_ * 900 + (y_ + 1) * 30 + (x_ + 1))) * 512 + sc;
    m_ = m0 + 64 + sr;
    b_ = m_ / 784; rem = m_ - b_ * 784; y_ = rem / 28; x_ = rem - x_ * 0 - y_ * 28;
    // (identical arithmetic as original; kept explicit)
    x_ = rem - y_ * 28;
    const _Float16* aP1 = A + ((size_t)(b_ * 900 + (y_ + 1) * 30 + (x_ + 1))) * 512 + sc;
    const _Float16* bP0 = W + (size_t)(n0 + sr) * 4608 + sc;
    const _Float16* bP1 = W + (size_t)(n0 + 64 + sr) * 4608 + sc;

    const int mw = wid & 1, nw = wid >> 1;
    const _Float16* pA = sA + (mw * 64 + (lane & 15)) * 32 + (lane >> 4) * 8;
    const _Float16* pB = sB + (nw * 64 + (lane & 15)) * 32 + (lane >> 4) * 8;

    f32x4 acc[4][4];
#pragma unroll
    for (int i = 0; i < 4; ++i)
#pragma unroll
        for (int j = 0; j < 4; ++j) acc[i][j] = (f32x4)(0.0f);

    for (int k0 = kbase; k0 < kbase + 1152; k0 += 32) {
        int sub = k0 >> 9; int s3 = sub / 3;
        int dy = s3 - 1, dx = sub - s3 * 3 - 1;
        int aOff = (dy * 30 + dx) * 512 + (k0 & 511);
        __syncthreads();
        async_copy16(aP0 + aOff, ldsA0);
        async_copy16(aP1 + aOff, ldsA1);
        async_copy16(bP0 + k0, ldsB0);
        async_copy16(bP1 + k0, ldsB1);
        __syncthreads();

        half8 aF[4], bF[4];
#pragma unroll
        for (int i = 0; i < 4; ++i) aF[i] = *(const half8*)(pA + i * 512);
#pragma unroll
        for (int j = 0; j < 4; ++j) bF[j] = *(const half8*)(pB + j * 512);
#pragma unroll
        for (int i = 0; i < 4; ++i)
#pragma unroll
            for (int j = 0; j < 4; ++j)
                acc[i][j] = __builtin_amdgcn_mfma_f32_16x16x32_f16(
                    aF[i], bF[j], acc[i][j], 0, 0, 0);
    }

    float* dst = (blockIdx.z < 2) ? (partA + (size_t)blockIdx.z * PART_STRIDE)
                                  : (partB + (size_t)(blockIdx.z - 2) * PART_STRIDE);
    const int orow = m0 + mw * 64 + (lane >> 4) * 4;
    const int ocol = n0 + nw * 64 + (lane & 15);
#pragma unroll
    for (int j = 0; j < 4; ++j) {
#pragma unroll
        for (int i = 0; i < 4; ++i)
#pragma unroll
            for (int r = 0; r < 4; ++r)
                dst[(size_t)(orow + i * 16 + r) * 512 + ocol + j * 16] = acc[i][j][r];
    }
}

// conv epilogue: dwtb16 = fp16(relu((p0+p1+p2+p3 + bias) * g*BN_RSQ + beta))
__global__ __launch_bounds__(256) void conv_epi(
    const float* __restrict__ pA, const float* __restrict__ pB,
    _Float16* __restrict__ o, const float* __restrict__ bias,
    const float* __restrict__ bng, const float* __restrict__ bnb)
{
    int i = blockIdx.x * 256 + threadIdx.x;      // 401,408 groups of 8
    size_t base = (size_t)i * 8;
    int c = (int)(base & 511);
    half8 hv;
#pragma unroll
    for (int u = 0; u < 8; u += 4) {
        float4 a0 = *(const float4*)(pA + base + u);
        float4 a1 = *(const float4*)(pA + PART_STRIDE + base + u);
        float4 a2 = *(const float4*)(pB + base + u);
        float4 a3 = *(const float4*)(pB + PART_STRIDE + base + u);
        float s[4] = {a0.x + a1.x + a2.x + a3.x, a0.y + a1.y + a2.y + a3.y,
                      a0.z + a1.z + a2.z + a3.z, a0.w + a1.w + a2.w + a3.w};
#pragma unroll
        for (int v = 0; v < 4; ++v) {
            int cc = c + u + v;
            float val = (s[v] + bias[cc]) * (bng[cc] * BN_RSQ) + bnb[cc];
            hv[u + v] = (_Float16)fmaxf(val, 0.0f);
        }
    }
    *(half8*)(o + base) = hv;
}

// =====================================================================
// small utility kernels
// =====================================================================
__global__ __launch_bounds__(256) void cvt_f32_f16(
    const float* __restrict__ s, _Float16* __restrict__ d, int n8)
{
    int i = blockIdx.x * 256 + threadIdx.x;
    if (i >= n8) return;
    const float4* sp = (const float4*)(s + (size_t)i * 8);
    float4 a = sp[0], b = sp[1];
    half8 h;
    h[0] = (_Float16)a.x; h[1] = (_Float16)a.y; h[2] = (_Float16)a.z; h[3] = (_Float16)a.w;
    h[4] = (_Float16)b.x; h[5] = (_Float16)b.y; h[6] = (_Float16)b.z; h[7] = (_Float16)b.w;
    *(half8*)(d + (size_t)i * 8) = h;
}

__global__ __launch_bounds__(256) void zero_half(_Float16* __restrict__ p, int n8)
{
    int i = blockIdx.x * 256 + threadIdx.x;
    if (i < n8) *(float4*)(p + (size_t)i * 8) = make_float4(0.f, 0.f, 0.f, 0.f);
}

__global__ __launch_bounds__(256) void transpose_filter16(
    const float* __restrict__ fw, _Float16* __restrict__ wT)
{   // wT[n][(ky*3+kx)*512 + ci] = fw[n][ci][ky][kx]; 512*4608
    int idx = blockIdx.x * 256 + threadIdx.x;
    int n = idx / 4608; int r = idx - n * 4608;
    int sub = r >> 9; int ci = r & 511;
    wT[idx] = (_Float16)fw[(size_t)n * 4608 + ci * 9 + sub];
}

__global__ __launch_bounds__(256) void transpose_kve16(
    const float* __restrict__ kw, _Float16* __restrict__ kT)
{   // kT[n][(ky*2+kx)*512 + ci] = kw[n][ci][ky][kx]; 512*2048
    int idx = blockIdx.x * 256 + threadIdx.x;
    int n = idx >> 11; int r = idx & 2047;
    int sub = r >> 9; int ci = r & 511;
    kT[idx] = (_Float16)kw[((size_t)n << 11) + (ci << 2) + sub];
}

// V^T prep: vt[((b*8+h)*64+d)*224 + m] = kv[b][m][512 + h*64 + d], 0 for m>=196
__global__ __launch_bounds__(256) void vt_prep(
    const _Float16* __restrict__ kv, _Float16* __restrict__ vt)
{
    int idx = blockIdx.x * 256 + threadIdx.x;   // 917504 total
    int m = idx % 224;
    int rest = idx / 224;
    int d = rest & 63;
    int bh = rest >> 6;
    int b = bh >> 3, h = bh & 7;
    _Float16 v = (_Float16)0.0f;
    if (m < 196)
        v = kv[((size_t)(b * 196 + m)) * 1024 + 512 + h * 64 + d];
    vt[idx] = v;
}

// =====================================================================
// Haar DWT: rbuf16 (B,56,56,128 NHWC fp16) -> padded (B,30,30,512 NHWC fp16)
// =====================================================================
__global__ __launch_bounds__(128) void dwt_kernel(
    const _Float16* __restrict__ r, _Float16* __restrict__ pad)
{
    int bid = blockIdx.x;            // b*784 + i*28 + j
    int b = bid / 784; int rem = bid - b * 784;
    int i = rem / 28;  int j = rem - i * 28;
    int c = threadIdx.x;
    int y = 2 * i, x = 2 * j;
    size_t base = (size_t)b * 3136;
    _Float16 f1 = r[(base + (size_t)y * 56 + x) * 128 + c];
    _Float16 f2 = r[(base + (size_t)(y + 1) * 56 + x) * 128 + c];
    _Float16 f3 = r[(base + (size_t)y * 56 + (x + 1)) * 128 + c];
    _Float16 f4 = r[(base + (size_t)(y + 1) * 56 + (x + 1)) * 128 + c];
    _Float16 h = (_Float16)0.5f;
    _Float16 x1 = f1 * h, x2 = f2 * h, x3 = f3 * h, x4 = f4 * h;
    _Float16 ll = ((x1 + x2) + x3) + x4;
    _Float16 hl = (((-x1) - x2) + x3) + x4;
    _Float16 lh = (((-x1) + x2) - x3) + x4;
    _Float16 hh = ((x1 - x2) - x3) + x4;
    size_t ob = ((size_t)b * 900 + (size_t)(i + 1) * 30 + (j + 1)) * 512;
    pad[ob + c]       = ll;
    pad[ob + 128 + c] = hl;
    pad[ob + 256 + c] = lh;
    pad[ob + 384 + c] = hh;
}

// =====================================================================
// Haar IDWT: dwt_b16 (B,28,28,512 NHWC fp16) -> cat16 cols 512..639
// =====================================================================
__global__ __launch_bounds__(128) void idwt_kernel(
    const _Float16* __restrict__ d, _Float16* __restrict__ cat)
{
    int bid = blockIdx.x;
    int b = bid / 784; int rem = bid - b * 784;
    int i = rem / 28;  int j = rem - i * 28;
    int c = threadIdx.x;
    size_t ib = ((size_t)b * 784 + (size_t)i * 28 + j) * 512;
    _Float16 ll = d[ib + c];
    _Float16 hl = d[ib + 128 + c];
    _Float16 lh = d[ib + 256 + c];
    _Float16 hh = d[ib + 384 + c];
    _Float16 h = (_Float16)0.5f;
    _Float16 p1 = (((ll - hl) - lh) + hh) * h;
    _Float16 p2 = (((ll - hl) + lh) - hh) * h;
    _Float16 p3 = (((ll + hl) - lh) - hh) * h;
    _Float16 p4 = (((ll + hl) + lh) + hh) * h;
    int y = 2 * i, x = 2 * j;
    size_t rb = (size_t)b * 3136;
    cat[(rb + (size_t)y * 56 + x) * 640 + 512 + c]           = p1;
    cat[(rb + (size_t)y * 56 + x + 1) * 640 + 512 + c]       = p3;
    cat[(rb + (size_t)(y + 1) * 56 + x) * 640 + 512 + c]     = p2;
    cat[(rb + (size_t)(y + 1) * 56 + x + 1) * 640 + 512 + c] = p4;
}

// =====================================================================
// LayerNorm over C=512 (fp32 in, fp16 out), one wave per row
// =====================================================================
__global__ __launch_bounds__(256) void ln_kernel(
    const float* __restrict__ p, _Float16* __restrict__ o,
    const float* __restrict__ g, const float* __restrict__ bta)
{
    int wave = threadIdx.x >> 6;
    int lane = threadIdx.x & 63;
    int row = blockIdx.x * 4 + wave;            // 392*4 = 1568
    const float* rp = p + (size_t)row * 512;
    float v[8];
    *(float4*)&v[0] = *(const float4*)(rp + lane * 8);
    *(float4*)&v[4] = *(const float4*)(rp + lane * 8 + 4);
    float s = ((v[0] + v[1]) + (v[2] + v[3])) + ((v[4] + v[5]) + (v[6] + v[7]));
#pragma unroll
    for (int off = 32; off; off >>= 1) s += __shfl_xor(s, off);
    float mu = s * (1.0f / 512.0f);
    float sq = 0.0f;
#pragma unroll
    for (int i = 0; i < 8; ++i) { v[i] -= mu; sq += v[i] * v[i]; }
#pragma unroll
    for (int off = 32; off; off >>= 1) sq += __shfl_xor(sq, off);
    float inv = 1.0f / sqrtf(sq * (1.0f / 512.0f) + 1e-5f);
    int c = lane * 8;
    half8 hv;
#pragma unroll
    for (int i = 0; i < 8; ++i) hv[i] = (_Float16)(v[i] * inv * g[c + i] + bta[c + i]);
    *(half8*)(o + (size_t)row * 512 + c) = hv;
}

// =====================================================================
// MFMA flash attention. Block = (b, h, 64 q-rows); 4 waves x 16 q-rows.
// Unnormalized softmax (scores tiny), one reduction at the end.
// =====================================================================
__global__ __launch_bounds__(256) void attn_mfma(
    const _Float16* __restrict__ q, const _Float16* __restrict__ kv,
    const _Float16* __restrict__ vt, _Float16* __restrict__ cat)
{
    __shared__ _Float16 sK[64][72];    // K[m][d]
    __shared__ _Float16 sVT[64][72];   // V^T[d][m-chunk]
    __shared__ _Float16 sP[4][16][40]; // per-wave P round-trip
    int bid = blockIdx.x;
    int qt = bid % 49;
    int h  = (bid / 49) & 7;
    int b  = bid / 392;
    int n0 = qt * 64;
    int t = threadIdx.x, lane = t & 63, wid = t >> 6;
    int quad = lane >> 4, l16 = lane & 15;

    const _Float16* qp = q + ((size_t)(b * 3136 + n0 + wid * 16 + l16)) * 512
                           + h * 64 + quad * 8;
    half8 aQ0 = *(const half8*)qp;
    half8 aQ1 = *(const half8*)(qp + 32);

    f32x4 oacc[4];
#pragma unroll
    for (int i = 0; i < 4; ++i) oacc[i] = (f32x4)(0.0f);
    float lsum[4] = {0.f, 0.f, 0.f, 0.f};

    const _Float16* vtb = vt + ((size_t)((b * 8 + h) * 64)) * 224;

    for (int c0 = 0; c0 < 224; c0 += 64) {
        __syncthreads();
#pragma unroll
        for (int it = 0; it < 2; ++it) {
            int slot = t + 256 * it;
            int row = slot >> 3, c8 = (slot & 7) * 8;
            int m = c0 + row; if (m > 195) m = 195;
            *(half8*)&sK[row][c8] =
                *(const half8*)(kv + ((size_t)(b * 196 + m)) * 1024 + h * 64 + c8);
        }
#pragma unroll
        for (int it = 0; it < 2; ++it) {
            int slot = t + 256 * it;
            int row = slot >> 3, c8 = (slot & 7) * 8;
            *(half8*)&sVT[row][c8] =
                *(const half8*)(vtb + (size_t)row * 224 + c0 + c8);
        }
        __syncthreads();

#pragma unroll
        for (int sc = 0; sc < 64; sc += 32) {
            half8 bk00 = *(const half8*)&sK[sc + l16][quad * 8];
            half8 bk01 = *(const half8*)&sK[sc + l16][32 + quad * 8];
            half8 bk10 = *(const half8*)&sK[sc + 16 + l16][quad * 8];
            half8 bk11 = *(const half8*)&sK[sc + 16 + l16][32 + quad * 8];
            f32x4 s0 = (f32x4)(0.0f), s1 = (f32x4)(0.0f);
            s0 = __builtin_amdgcn_mfma_f32_16x16x32_f16(aQ0, bk00, s0, 0, 0, 0);
            s0 = __builtin_amdgcn_mfma_f32_16x16x32_f16(aQ1, bk01, s0, 0, 0, 0);
            s1 = __builtin_amdgcn_mfma_f32_16x16x32_f16(aQ0, bk10, s1, 0, 0, 0);
            s1 = __builtin_amdgcn_mfma_f32_16x16x32_f16(aQ1, bk11, s1, 0, 0, 0);

            int col0 = c0 + sc + l16;
            float msk0 = (col0 < 196) ? 0.0f : -INFINITY;
            float msk1 = (col0 + 16 < 196) ? 0.0f : -INFINITY;
            float p0[4], p1[4];
#pragma unroll
            for (int r = 0; r < 4; ++r) {
                p0[r] = exp2f(s0[r] * SCL2 + msk0);
                p1[r] = exp2f(s1[r] * SCL2 + msk1);
                lsum[r] += p0[r] + p1[r];
            }
#pragma unroll
            for (int r = 0; r < 4; ++r) {
                sP[wid][quad * 4 + r][l16]      = (_Float16)p0[r];
                sP[wid][quad * 4 + r][16 + l16] = (_Float16)p1[r];
            }
            half8 aP = *(const half8*)&sP[wid][l16][quad * 8];
            half8 bv0 = *(const half8*)&sVT[l16][sc + quad * 8];
            half8 bv1 = *(const half8*)&sVT[16 + l16][sc + quad * 8];
            half8 bv2 = *(const half8*)&sVT[32 + l16][sc + quad * 8];
            half8 bv3 = *(const half8*)&sVT[48 + l16][sc + quad * 8];
            oacc[0] = __builtin_amdgcn_mfma_f32_16x16x32_f16(aP, bv0, oacc[0], 0, 0, 0);
            oacc[1] = __builtin_amdgcn_mfma_f32_16x16x32_f16(aP, bv1, oacc[1], 0, 0, 0);
            oacc[2] = __builtin_amdgcn_mfma_f32_16x16x32_f16(aP, bv2, oacc[2], 0, 0, 0);
            oacc[3] = __builtin_amdgcn_mfma_f32_16x16x32_f16(aP, bv3, oacc[3], 0, 0, 0);
        }
    }

    float inv[4];
#pragma unroll
    for (int r = 0; r < 4; ++r) {
        float s = lsum[r];
        s += __shfl_xor(s, 1);
        s += __shfl_xor(s, 2);
        s += __shfl_xor(s, 4);
        s += __shfl_xor(s, 8);
        inv[r] = 1.0f / s;
    }
#pragma unroll
    for (int r = 0; r < 4; ++r) {
        size_t rowoff = ((size_t)(b * 3136 + n0 + wid * 16 + quad * 4 + r)) * 640
                        + h * 64 + l16;
#pragma unroll
        for (int tv = 0; tv < 4; ++tv)
            cat[rowoff + tv * 16] = (_Float16)(oacc[tv][r] * inv[r]);
    }
}

// =====================================================================
extern "C" void kernel_launch(void* const* d_in, const int* in_sizes, int n_in,
                              void* d_out, int out_size, void* d_ws, size_t ws_size,
                              hipStream_t stream)
{
    const float* x           = (const float*)d_in[0];
    const float* reduce_w    = (const float*)d_in[3];
    const float* reduce_b    = (const float*)d_in[4];
    const float* reduce_g    = (const float*)d_in[5];
    const float* reduce_beta = (const float*)d_in[6];
    const float* filter_w    = (const float*)d_in[7];
    const float* filter_b    = (const float*)d_in[8];
    const float* filter_g    = (const float*)d_in[9];
    const float* filter_beta = (const float*)d_in[10];
    const float* q_w         = (const float*)d_in[11];
    const float* q_b         = (const float*)d_in[12];
    const float* ln_g        = (const float*)d_in[13];
    const float* ln_b        = (const float*)d_in[14];
    const float* kv_w        = (const float*)d_in[15];
    const float* kv_b        = (const float*)d_in[16];
    const float* kve_w       = (const float*)d_in[17];
    const float* kve_b       = (const float*)d_in[18];
    const float* proj_w      = (const float*)d_in[19];
    const float* proj_b      = (const float*)d_in[20];
    float* out = (float*)d_out;
    _Float16* hws = (_Float16*)d_ws;

    _Float16* x16    = hws + OFF_X16;
    _Float16* q16    = hws + OFF_Q16;
    _Float16* cat16  = hws + OFF_CAT;
    _Float16* r16    = hws + OFF_R16;
    _Float16* pad16  = hws + OFF_PAD;
    _Float16* dwtb16 = hws + OFF_DWTB;
    float*    kv_in  = (float*)(hws + OFF_KVIN);
    _Float16* ln16   = hws + OFF_LN16;
    _Float16* kv16   = hws + OFF_KV16;
    _Float16* wT16   = hws + OFF_WT;
    _Float16* kT16   = hws + OFF_KT;
    _Float16* qw16   = hws + OFF_QW;
    _Float16* kvw16  = hws + OFF_KVW;
    _Float16* pw16   = hws + OFF_PW;
    _Float16* rw16   = hws + OFF_RW;
    _Float16* vt16   = hws + OFF_VT;
    float*    partA  = (float*)(hws + OFF_X16);   // partials 0,1 (x16 is dead by then)
    float*    partB  = (float*)(hws + OFF_PART);  // partials 2,3

    // conversions / transposes / padding init
    cvt_f32_f16<<<dim3(6272), dim3(256), 0, stream>>>(x, x16, 1605632);
    cvt_f32_f16<<<dim3(128),  dim3(256), 0, stream>>>(q_w, qw16, 32768);
    cvt_f32_f16<<<dim3(256),  dim3(256), 0, stream>>>(kv_w, kvw16, 65536);
    cvt_f32_f16<<<dim3(160),  dim3(256), 0, stream>>>(proj_w, pw16, 40960);
    cvt_f32_f16<<<dim3(32),   dim3(256), 0, stream>>>(reduce_w, rw16, 8192);
    transpose_filter16<<<dim3(9216), dim3(256), 0, stream>>>(filter_w, wT16);
    transpose_kve16<<<dim3(4096), dim3(256), 0, stream>>>(kve_w, kT16);
    zero_half<<<dim3(1800), dim3(256), 0, stream>>>(pad16, 460800);

    // q = x @ q_w.T + q_b  -> fp16
    gemm16<0, 2><<<dim3(196, 4), dim3(256), 0, stream>>>(
        x16, qw16, q16, 25088, 512, 512, 512, q_b, nullptr, nullptr);

    // r = fp16(relu(bn(conv1x1(x))))  (25088 x 128 NHWC fp16)
    gemm16<0, 1><<<dim3(196, 1), dim3(256), 0, stream>>>(
        x16, rw16, r16, 25088, 512, 512, 128, reduce_b, reduce_g, reduce_beta);

    // DWT -> padded 30x30x512
    dwt_kernel<<<dim3(6272), dim3(128), 0, stream>>>(r16, pad16);

    // 3x3 conv split-K x4 (x16 now dead; partials 0,1 overwrite it)
    conv_splitk<<<dim3(49, 4, 4), dim3(256), 0, stream>>>(pad16, wT16, partA, partB);
    conv_epi<<<dim3(1568), dim3(256), 0, stream>>>(
        partA, partB, dwtb16, filter_b, filter_g, filter_beta);

    // IDWT -> cat cols 512..639
    idwt_kernel<<<dim3(6272), dim3(128), 0, stream>>>(dwtb16, cat16);

    // kve 2x2 s2 conv -> kv_in (fp32)
    gemm16<2, 0><<<dim3(13, 4), dim3(256), 0, stream>>>(
        dwtb16, kT16, kv_in, 1568, 2048, 0, 512, kve_b, nullptr, nullptr);

    // LayerNorm -> fp16
    ln_kernel<<<dim3(392), dim3(256), 0, stream>>>(kv_in, ln16, ln_g, ln_b);

    // kv = ln @ kv_w.T + kv_b -> fp16 (1568 x 1024)
    gemm16<0, 2><<<dim3(13, 8), dim3(256), 0, stream>>>(
        ln16, kvw16, kv16, 1568, 512, 512, 1024, kv_b, nullptr, nullptr);

    // V^T for attention B-operand
    vt_prep<<<dim3(3584), dim3(256), 0, stream>>>(kv16, vt16);

    // attention -> cat cols 0..511
    attn_mfma<<<dim3(3136), dim3(256), 0, stream>>>(q16, kv16, vt16, cat16);

    // out = cat @ proj_w.T + proj_b  (fp32)
    gemm16<0, 0><<<dim3(196, 4), dim3(256), 0, stream>>>(
        cat16, pw16, out, 25088, 640, 640, 512, proj_b, nullptr, nullptr);
}

// Round 2
// 480.763 us; speedup vs baseline: 1.0224x; 1.0224x over previous
//
#include <hip/hip_runtime.h>
#include <math.h>

// Problem constants: B=8, H=W=56, C=512, N=3136, c4=128, HEADS=8, hd=64, SR=2
// kv sequence length = 14*14 = 196 (padded to 224 for attention)

typedef _Float16 half8 __attribute__((ext_vector_type(8)));
typedef _Float16 half4v __attribute__((ext_vector_type(4)));
typedef float f32x4 __attribute__((ext_vector_type(4)));

// ---------------- workspace layout (offsets in halves; all 16B-aligned) ----
static const size_t OFF_X16  = 0;          // 25088*512 (dead after q/r gemms; reused as conv partials 0,1)
static const size_t OFF_Q16  = 12845056;   // 25088*512
static const size_t OFF_CAT  = 25690112;   // 25088*640
static const size_t OFF_R16  = 41746432;   // 25088*128
static const size_t OFF_PAD  = 44957696;   // 8*900*512  (30x30 zero-padded DWT)
static const size_t OFF_DWTB = 48644096;   // 8*784*512
static const size_t OFF_KVIN = 51855360;   // 1568*512 floats = 3,211,264 halves
static const size_t OFF_LN16 = 55066624;   // 1568*512
static const size_t OFF_KV16 = 55869440;   // 1568*1024
static const size_t OFF_WT   = 57475072;   // 512*4608
static const size_t OFF_KT   = 59834368;   // 512*2048
static const size_t OFF_QW   = 60882944;   // 512*512
static const size_t OFF_KVW  = 61145088;   // 1024*512
static const size_t OFF_PW   = 61669376;   // 512*640
static const size_t OFF_RW   = 61997056;   // 128*512
static const size_t OFF_VT   = 62062592;   // 8*8*64*224 = 917504 (V^T, m-padded)
static const size_t OFF_PART = 62980096;   // conv partials 2,3: 2*3,211,264 floats
// total = 75,825,152 halves = 151.7 MB

#define BN_RSQ 0.9999950000374997f
#define SCL2   0.1803368801111204f   /* 0.125 * log2(e) */
#define PART_STRIDE 3211264          /* 6272*512 floats per conv partial */

__device__ __forceinline__ void async_copy16(const _Float16* g, _Float16* l) {
    __builtin_amdgcn_global_load_lds(
        (const __attribute__((address_space(1))) void*)g,
        (__attribute__((address_space(3))) void*)l, 16, 0, 0);
}

// =====================================================================
// MFMA fp16 NT GEMM: out[m][n] = sum_k A[m][k]*W[n][k] (+ epilogue)
// ALOAD: 0 plain row-major (lda), 2 kve 2x2 stride-2 on 28x28x512 NHWC
// EPI:   0 = +bias -> fp32, 1 = +bias,BN,ReLU -> fp16, 2 = +bias -> fp16
// 128x128 tile, BK=32, 256 threads (4 waves 2x2), 16x16x32 MFMA.
// 2-phase double-buffered LDS: stage k0+32 into buf^1 BEFORE computing
// buf (T3 minimum recipe) -> one __syncthreads per K-step; its implicit
// vmcnt(0) drain lands after the MFMAs, hiding stage latency.
// =====================================================================
template <int ALOAD, int EPI>
__global__ __launch_bounds__(256) void gemm16(
    const _Float16* __restrict__ A, const _Float16* __restrict__ W,
    void* __restrict__ outp, int M, int K, int lda, int ldc,
    const float* __restrict__ bias, const float* __restrict__ bng,
    const float* __restrict__ bnb)
{
    __shared__ _Float16 sA[2][128 * 32];
    __shared__ _Float16 sB[2][128 * 32];
    const int t = threadIdx.x;
    const int lane = t & 63, wid = t >> 6;
    const int m0 = blockIdx.x * 128, n0 = blockIdx.y * 128;

    const int sr = wid * 16 + (lane >> 2);   // staging tile row (instr0)
    const int sc = (lane & 3) * 8;           // staging col offset (halves)
    const int stA0 = wid * 512;              // dest offsets within a buffer
    const int stA1 = 2048 + wid * 512;

    const _Float16 *aP0, *aP1;
    if constexpr (ALOAD == 0) {
        int r0 = m0 + sr;      if (r0 > M - 1) r0 = M - 1;
        int r1 = m0 + 64 + sr; if (r1 > M - 1) r1 = M - 1;
        aP0 = A + (size_t)r0 * lda + sc;
        aP1 = A + (size_t)r1 * lda + sc;
    } else {
        int m_ = m0 + sr; if (m_ > M - 1) m_ = M - 1;
        int b_ = m_ / 196, rem = m_ - b_ * 196, i_ = rem / 14, j_ = rem - i_ * 14;
        aP0 = A + ((size_t)(b_ * 784 + 2 * i_ * 28 + 2 * j_)) * 512 + sc;
        m_ = m0 + 64 + sr; if (m_ > M - 1) m_ = M - 1;
        b_ = m_ / 196; rem = m_ - b_ * 196; i_ = rem / 14; j_ = rem - i_ * 14;
        aP1 = A + ((size_t)(b_ * 784 + 2 * i_ * 28 + 2 * j_)) * 512 + sc;
    }
    const _Float16* bP0 = W + (size_t)(n0 + sr) * K + sc;
    const _Float16* bP1 = W + (size_t)(n0 + 64 + sr) * K + sc;

    const int mw = wid & 1, nw = wid >> 1;
    const int pAoff = (mw * 64 + (lane & 15)) * 32 + (lane >> 4) * 8;
    const int pBoff = (nw * 64 + (lane & 15)) * 32 + (lane >> 4) * 8;

    f32x4 acc[4][4];
#pragma unroll
    for (int i = 0; i < 4; ++i)
#pragma unroll
        for (int j = 0; j < 4; ++j) acc[i][j] = (f32x4)(0.0f);

    // A-offset for a given k
    auto aoff_of = [&](int k) -> int {
        if constexpr (ALOAD == 0) {
            return k;
        } else {
            int sub = k >> 9; int ky = sub >> 1, kx = sub & 1;
            return (ky * 28 + kx) * 512 + (k & 511);
        }
    };

    // prologue: stage k=0 into buf 0
    {
        int aOff = aoff_of(0);
        async_copy16(aP0 + aOff, &sA[0][stA0]);
        async_copy16(aP1 + aOff, &sA[0][stA1]);
        async_copy16(bP0, &sB[0][stA0]);
        async_copy16(bP1, &sB[0][stA1]);
    }
    __syncthreads();   // vmcnt(0) drain -> buf0 visible

    int cur = 0;
    for (int k0 = 0; k0 < K; k0 += 32) {
        int kn = k0 + 32;
        if (kn < K) {   // stage next tile into the other buffer (overlaps compute)
            int aOff = aoff_of(kn);
            async_copy16(aP0 + aOff, &sA[cur ^ 1][stA0]);
            async_copy16(aP1 + aOff, &sA[cur ^ 1][stA1]);
            async_copy16(bP0 + kn, &sB[cur ^ 1][stA0]);
            async_copy16(bP1 + kn, &sB[cur ^ 1][stA1]);
        }
        const _Float16* pA = &sA[cur][0] + pAoff;
        const _Float16* pB = &sB[cur][0] + pBoff;
        half8 aF[4], bF[4];
#pragma unroll
        for (int i = 0; i < 4; ++i) aF[i] = *(const half8*)(pA + i * 512);
#pragma unroll
        for (int j = 0; j < 4; ++j) bF[j] = *(const half8*)(pB + j * 512);
#pragma unroll
        for (int i = 0; i < 4; ++i)
#pragma unroll
            for (int j = 0; j < 4; ++j)
                acc[i][j] = __builtin_amdgcn_mfma_f32_16x16x32_f16(
                    aF[i], bF[j], acc[i][j], 0, 0, 0);
        __syncthreads();   // drains vmcnt (next stage done) + everyone done reading cur
        cur ^= 1;
    }

    // epilogue: C/D layout col=lane&15, row=(lane>>4)*4+reg
    const int orow = m0 + mw * 64 + (lane >> 4) * 4;
    const int ocol = n0 + nw * 64 + (lane & 15);
#pragma unroll
    for (int j = 0; j < 4; ++j) {
        int col = ocol + j * 16;
        float bv = bias[col];
        float g = 0.0f, b2 = 0.0f;
        if constexpr (EPI == 1) { g = bng[col] * BN_RSQ; b2 = bnb[col]; }
#pragma unroll
        for (int i = 0; i < 4; ++i) {
#pragma unroll
            for (int r = 0; r < 4; ++r) {
                int row = orow + i * 16 + r;
                if (row >= M) continue;
                float v = acc[i][j][r] + bv;
                if constexpr (EPI == 1) v = fmaxf(v * g + b2, 0.0f);
                if constexpr (EPI == 0)
                    ((float*)outp)[(size_t)row * ldc + col] = v;
                else
                    ((_Float16*)outp)[(size_t)row * ldc + col] = (_Float16)v;
            }
        }
    }
}

// =====================================================================
// conv3x3 split-K partial GEMM: grid (49, 4, 4); K-group bz covers
// k in [bz*1152, (bz+1)*1152). Writes fp32 partial (no bias).
// A = padded 30x30x512 NHWC fp16; W = wT[n][(ky*3+kx)*512+ci].
// Same 2-phase double-buffer as gemm16.
// =====================================================================
__global__ __launch_bounds__(256) void conv_splitk(
    const _Float16* __restrict__ A, const _Float16* __restrict__ W,
    float* __restrict__ partA, float* __restrict__ partB)
{
    __shared__ _Float16 sA[2][128 * 32];
    __shared__ _Float16 sB[2][128 * 32];
    const int t = threadIdx.x;
    const int lane = t & 63, wid = t >> 6;
    const int m0 = blockIdx.x * 128, n0 = blockIdx.y * 128;
    const int kbase = blockIdx.z * 1152;

    const int sr = wid * 16 + (lane >> 2);
    const int sc = (lane & 3) * 8;
    const int stA0 = wid * 512;
    const int stA1 = 2048 + wid * 512;

    int m_ = m0 + sr;
    int b_ = m_ / 784, rem = m_ - b_ * 784, y_ = rem / 28, x_ = rem - y_ * 28;
    const _Float16* aP0 = A + ((size_t)(b_ * 900 + (y_ + 1) * 30 + (x_ + 1))) * 512 + sc;
    m_ = m0 + 64 + sr;
    b_ = m_ / 784; rem = m_ - b_ * 784; y_ = rem / 28; x_ = rem - y_ * 28;
    const _Float16* aP1 = A + ((size_t)(b_ * 900 + (y_ + 1) * 30 + (x_ + 1))) * 512 + sc;
    const _Float16* bP0 = W + (size_t)(n0 + sr) * 4608 + sc;
    const _Float16* bP1 = W + (size_t)(n0 + 64 + sr) * 4608 + sc;

    const int mw = wid & 1, nw = wid >> 1;
    const int pAoff = (mw * 64 + (lane & 15)) * 32 + (lane >> 4) * 8;
    const int pBoff = (nw * 64 + (lane & 15)) * 32 + (lane >> 4) * 8;

    f32x4 acc[4][4];
#pragma unroll
    for (int i = 0; i < 4; ++i)
#pragma unroll
        for (int j = 0; j < 4; ++j) acc[i][j] = (f32x4)(0.0f);

    auto aoff_of = [&](int k) -> int {
        int sub = k >> 9; int s3 = sub / 3;
        int dy = s3 - 1, dx = sub - s3 * 3 - 1;
        return (dy * 30 + dx) * 512 + (k & 511);
    };

    {
        int aOff = aoff_of(kbase);
        async_copy16(aP0 + aOff, &sA[0][stA0]);
        async_copy16(aP1 + aOff, &sA[0][stA1]);
        async_copy16(bP0 + kbase, &sB[0][stA0]);
        async_copy16(bP1 + kbase, &sB[0][stA1]);
    }
    __syncthreads();

    int cur = 0;
    const int kend = kbase + 1152;
    for (int k0 = kbase; k0 < kend; k0 += 32) {
        int kn = k0 + 32;
        if (kn < kend) {
            int aOff = aoff_of(kn);
            async_copy16(aP0 + aOff, &sA[cur ^ 1][stA0]);
            async_copy16(aP1 + aOff, &sA[cur ^ 1][stA1]);
            async_copy16(bP0 + kn, &sB[cur ^ 1][stA0]);
            async_copy16(bP1 + kn, &sB[cur ^ 1][stA1]);
        }
        const _Float16* pA = &sA[cur][0] + pAoff;
        const _Float16* pB = &sB[cur][0] + pBoff;
        half8 aF[4], bF[4];
#pragma unroll
        for (int i = 0; i < 4; ++i) aF[i] = *(const half8*)(pA + i * 512);
#pragma unroll
        for (int j = 0; j < 4; ++j) bF[j] = *(const half8*)(pB + j * 512);
#pragma unroll
        for (int i = 0; i < 4; ++i)
#pragma unroll
            for (int j = 0; j < 4; ++j)
                acc[i][j] = __builtin_amdgcn_mfma_f32_16x16x32_f16(
                    aF[i], bF[j], acc[i][j], 0, 0, 0);
        __syncthreads();
        cur ^= 1;
    }

    float* dst = (blockIdx.z < 2) ? (partA + (size_t)blockIdx.z * PART_STRIDE)
                                  : (partB + (size_t)(blockIdx.z - 2) * PART_STRIDE);
    const int orow = m0 + mw * 64 + (lane >> 4) * 4;
    const int ocol = n0 + nw * 64 + (lane & 15);
#pragma unroll
    for (int j = 0; j < 4; ++j) {
#pragma unroll
        for (int i = 0; i < 4; ++i)
#pragma unroll
            for (int r = 0; r < 4; ++r)
                dst[(size_t)(orow + i * 16 + r) * 512 + ocol + j * 16] = acc[i][j][r];
    }
}

// conv epilogue: dwtb16 = fp16(relu((p0+p1+p2+p3 + bias) * g*BN_RSQ + beta))
__global__ __launch_bounds__(256) void conv_epi(
    const float* __restrict__ pA, const float* __restrict__ pB,
    _Float16* __restrict__ o, const float* __restrict__ bias,
    const float* __restrict__ bng, const float* __restrict__ bnb)
{
    int i = blockIdx.x * 256 + threadIdx.x;      // 401,408 groups of 8
    size_t base = (size_t)i * 8;
    int c = (int)(base & 511);
    half8 hv;
#pragma unroll
    for (int u = 0; u < 8; u += 4) {
        float4 a0 = *(const float4*)(pA + base + u);
        float4 a1 = *(const float4*)(pA + PART_STRIDE + base + u);
        float4 a2 = *(const float4*)(pB + base + u);
        float4 a3 = *(const float4*)(pB + PART_STRIDE + base + u);
        float s[4] = {a0.x + a1.x + a2.x + a3.x, a0.y + a1.y + a2.y + a3.y,
                      a0.z + a1.z + a2.z + a3.z, a0.w + a1.w + a2.w + a3.w};
#pragma unroll
        for (int v = 0; v < 4; ++v) {
            int cc = c + u + v;
            float val = (s[v] + bias[cc]) * (bng[cc] * BN_RSQ) + bnb[cc];
            hv[u + v] = (_Float16)fmaxf(val, 0.0f);
        }
    }
    *(half8*)(o + base) = hv;
}

// =====================================================================
// small utility kernels
// =====================================================================
__global__ __launch_bounds__(256) void cvt_f32_f16(
    const float* __restrict__ s, _Float16* __restrict__ d, int n8)
{
    int i = blockIdx.x * 256 + threadIdx.x;
    if (i >= n8) return;
    const float4* sp = (const float4*)(s + (size_t)i * 8);
    float4 a = sp[0], b = sp[1];
    half8 h;
    h[0] = (_Float16)a.x; h[1] = (_Float16)a.y; h[2] = (_Float16)a.z; h[3] = (_Float16)a.w;
    h[4] = (_Float16)b.x; h[5] = (_Float16)b.y; h[6] = (_Float16)b.z; h[7] = (_Float16)b.w;
    *(half8*)(d + (size_t)i * 8) = h;
}

__global__ __launch_bounds__(256) void zero_half(_Float16* __restrict__ p, int n8)
{
    int i = blockIdx.x * 256 + threadIdx.x;
    if (i < n8) *(float4*)(p + (size_t)i * 8) = make_float4(0.f, 0.f, 0.f, 0.f);
}

__global__ __launch_bounds__(256) void transpose_filter16(
    const float* __restrict__ fw, _Float16* __restrict__ wT)
{   // wT[n][(ky*3+kx)*512 + ci] = fw[n][ci][ky][kx]; 512*4608
    int idx = blockIdx.x * 256 + threadIdx.x;
    int n = idx / 4608; int r = idx - n * 4608;
    int sub = r >> 9; int ci = r & 511;
    wT[idx] = (_Float16)fw[(size_t)n * 4608 + ci * 9 + sub];
}

__global__ __launch_bounds__(256) void transpose_kve16(
    const float* __restrict__ kw, _Float16* __restrict__ kT)
{   // kT[n][(ky*2+kx)*512 + ci] = kw[n][ci][ky][kx]; 512*2048
    int idx = blockIdx.x * 256 + threadIdx.x;
    int n = idx >> 11; int r = idx & 2047;
    int sub = r >> 9; int ci = r & 511;
    kT[idx] = (_Float16)kw[((size_t)n << 11) + (ci << 2) + sub];
}

// V^T prep: vt[((b*8+h)*64+d)*224 + m] = kv[b][m][512 + h*64 + d], 0 for m>=196
__global__ __launch_bounds__(256) void vt_prep(
    const _Float16* __restrict__ kv, _Float16* __restrict__ vt)
{
    int idx = blockIdx.x * 256 + threadIdx.x;   // 917504 total
    int m = idx % 224;
    int rest = idx / 224;
    int d = rest & 63;
    int bh = rest >> 6;
    int b = bh >> 3, h = bh & 7;
    _Float16 v = (_Float16)0.0f;
    if (m < 196)
        v = kv[((size_t)(b * 196 + m)) * 1024 + 512 + h * 64 + d];
    vt[idx] = v;
}

// =====================================================================
// Haar DWT: rbuf16 (B,56,56,128 NHWC fp16) -> padded (B,30,30,512 NHWC fp16)
// =====================================================================
__global__ __launch_bounds__(128) void dwt_kernel(
    const _Float16* __restrict__ r, _Float16* __restrict__ pad)
{
    int bid = blockIdx.x;            // b*784 + i*28 + j
    int b = bid / 784; int rem = bid - b * 784;
    int i = rem / 28;  int j = rem - i * 28;
    int c = threadIdx.x;
    int y = 2 * i, x = 2 * j;
    size_t base = (size_t)b * 3136;
    _Float16 f1 = r[(base + (size_t)y * 56 + x) * 128 + c];
    _Float16 f2 = r[(base + (size_t)(y + 1) * 56 + x) * 128 + c];
    _Float16 f3 = r[(base + (size_t)y * 56 + (x + 1)) * 128 + c];
    _Float16 f4 = r[(base + (size_t)(y + 1) * 56 + (x + 1)) * 128 + c];
    _Float16 h = (_Float16)0.5f;
    _Float16 x1 = f1 * h, x2 = f2 * h, x3 = f3 * h, x4 = f4 * h;
    _Float16 ll = ((x1 + x2) + x3) + x4;
    _Float16 hl = (((-x1) - x2) + x3) + x4;
    _Float16 lh = (((-x1) + x2) - x3) + x4;
    _Float16 hh = ((x1 - x2) - x3) + x4;
    size_t ob = ((size_t)b * 900 + (size_t)(i + 1) * 30 + (j + 1)) * 512;
    pad[ob + c]       = ll;
    pad[ob + 128 + c] = hl;
    pad[ob + 256 + c] = lh;
    pad[ob + 384 + c] = hh;
}

// =====================================================================
// Haar IDWT: dwt_b16 (B,28,28,512 NHWC fp16) -> cat16 cols 512..639
// =====================================================================
__global__ __launch_bounds__(128) void idwt_kernel(
    const _Float16* __restrict__ d, _Float16* __restrict__ cat)
{
    int bid = blockIdx.x;
    int b = bid / 784; int rem = bid - b * 784;
    int i = rem / 28;  int j = rem - i * 28;
    int c = threadIdx.x;
    size_t ib = ((size_t)b * 784 + (size_t)i * 28 + j) * 512;
    _Float16 ll = d[ib + c];
    _Float16 hl = d[ib + 128 + c];
    _Float16 lh = d[ib + 256 + c];
    _Float16 hh = d[ib + 384 + c];
    _Float16 h = (_Float16)0.5f;
    _Float16 p1 = (((ll - hl) - lh) + hh) * h;
    _Float16 p2 = (((ll - hl) + lh) - hh) * h;
    _Float16 p3 = (((ll + hl) - lh) - hh) * h;
    _Float16 p4 = (((ll + hl) + lh) + hh) * h;
    int y = 2 * i, x = 2 * j;
    size_t rb = (size_t)b * 3136;
    cat[(rb + (size_t)y * 56 + x) * 640 + 512 + c]           = p1;
    cat[(rb + (size_t)y * 56 + x + 1) * 640 + 512 + c]       = p3;
    cat[(rb + (size_t)(y + 1) * 56 + x) * 640 + 512 + c]     = p2;
    cat[(rb + (size_t)(y + 1) * 56 + x + 1) * 640 + 512 + c] = p4;
}

// =====================================================================
// LayerNorm over C=512 (fp32 in, fp16 out), one wave per row
// =====================================================================
__global__ __launch_bounds__(256) void ln_kernel(
    const float* __restrict__ p, _Float16* __restrict__ o,
    const float* __restrict__ g, const float* __restrict__ bta)
{
    int wave = threadIdx.x >> 6;
    int lane = threadIdx.x & 63;
    int row = blockIdx.x * 4 + wave;            // 392*4 = 1568
    const float* rp = p + (size_t)row * 512;
    float v[8];
    *(float4*)&v[0] = *(const float4*)(rp + lane * 8);
    *(float4*)&v[4] = *(const float4*)(rp + lane * 8 + 4);
    float s = ((v[0] + v[1]) + (v[2] + v[3])) + ((v[4] + v[5]) + (v[6] + v[7]));
#pragma unroll
    for (int off = 32; off; off >>= 1) s += __shfl_xor(s, off);
    float mu = s * (1.0f / 512.0f);
    float sq = 0.0f;
#pragma unroll
    for (int i = 0; i < 8; ++i) { v[i] -= mu; sq += v[i] * v[i]; }
#pragma unroll
    for (int off = 32; off; off >>= 1) sq += __shfl_xor(sq, off);
    float inv = 1.0f / sqrtf(sq * (1.0f / 512.0f) + 1e-5f);
    int c = lane * 8;
    half8 hv;
#pragma unroll
    for (int i = 0; i < 8; ++i) hv[i] = (_Float16)(v[i] * inv * g[c + i] + bta[c + i]);
    *(half8*)(o + (size_t)row * 512 + c) = hv;
}

// =====================================================================
// MFMA flash attention. Block = (b, h, 64 q-rows); 4 waves x 16 q-rows.
// Unnormalized softmax (scores tiny), one reduction at the end.
// =====================================================================
__global__ __launch_bounds__(256) void attn_mfma(
    const _Float16* __restrict__ q, const _Float16* __restrict__ kv,
    const _Float16* __restrict__ vt, _Float16* __restrict__ cat)
{
    __shared__ _Float16 sK[64][72];    // K[m][d]
    __shared__ _Float16 sVT[64][72];   // V^T[d][m-chunk]
    __shared__ _Float16 sP[4][16][40]; // per-wave P round-trip
    int bid = blockIdx.x;
    int qt = bid % 49;
    int h  = (bid / 49) & 7;
    int b  = bid / 392;
    int n0 = qt * 64;
    int t = threadIdx.x, lane = t & 63, wid = t >> 6;
    int quad = lane >> 4, l16 = lane & 15;

    const _Float16* qp = q + ((size_t)(b * 3136 + n0 + wid * 16 + l16)) * 512
                           + h * 64 + quad * 8;
    half8 aQ0 = *(const half8*)qp;
    half8 aQ1 = *(const half8*)(qp + 32);

    f32x4 oacc[4];
#pragma unroll
    for (int i = 0; i < 4; ++i) oacc[i] = (f32x4)(0.0f);
    float lsum[4] = {0.f, 0.f, 0.f, 0.f};

    const _Float16* vtb = vt + ((size_t)((b * 8 + h) * 64)) * 224;

    for (int c0 = 0; c0 < 224; c0 += 64) {
        __syncthreads();
#pragma unroll
        for (int it = 0; it < 2; ++it) {
            int slot = t + 256 * it;
            int row = slot >> 3, c8 = (slot & 7) * 8;
            int m = c0 + row; if (m > 195) m = 195;
            *(half8*)&sK[row][c8] =
                *(const half8*)(kv + ((size_t)(b * 196 + m)) * 1024 + h * 64 + c8);
        }
#pragma unroll
        for (int it = 0; it < 2; ++it) {
            int slot = t + 256 * it;
            int row = slot >> 3, c8 = (slot & 7) * 8;
            *(half8*)&sVT[row][c8] =
                *(const half8*)(vtb + (size_t)row * 224 + c0 + c8);
        }
        __syncthreads();

#pragma unroll
        for (int sc = 0; sc < 64; sc += 32) {
            half8 bk00 = *(const half8*)&sK[sc + l16][quad * 8];
            half8 bk01 = *(const half8*)&sK[sc + l16][32 + quad * 8];
            half8 bk10 = *(const half8*)&sK[sc + 16 + l16][quad * 8];
            half8 bk11 = *(const half8*)&sK[sc + 16 + l16][32 + quad * 8];
            f32x4 s0 = (f32x4)(0.0f), s1 = (f32x4)(0.0f);
            s0 = __builtin_amdgcn_mfma_f32_16x16x32_f16(aQ0, bk00, s0, 0, 0, 0);
            s0 = __builtin_amdgcn_mfma_f32_16x16x32_f16(aQ1, bk01, s0, 0, 0, 0);
            s1 = __builtin_amdgcn_mfma_f32_16x16x32_f16(aQ0, bk10, s1, 0, 0, 0);
            s1 = __builtin_amdgcn_mfma_f32_16x16x32_f16(aQ1, bk11, s1, 0, 0, 0);

            int col0 = c0 + sc + l16;
            float msk0 = (col0 < 196) ? 0.0f : -INFINITY;
            float msk1 = (col0 + 16 < 196) ? 0.0f : -INFINITY;
            float p0[4], p1[4];
#pragma unroll
            for (int r = 0; r < 4; ++r) {
                p0[r] = exp2f(s0[r] * SCL2 + msk0);
                p1[r] = exp2f(s1[r] * SCL2 + msk1);
                lsum[r] += p0[r] + p1[r];
            }
#pragma unroll
            for (int r = 0; r < 4; ++r) {
                sP[wid][quad * 4 + r][l16]      = (_Float16)p0[r];
                sP[wid][quad * 4 + r][16 + l16] = (_Float16)p1[r];
            }
            half8 aP = *(const half8*)&sP[wid][l16][quad * 8];
            half8 bv0 = *(const half8*)&sVT[l16][sc + quad * 8];
            half8 bv1 = *(const half8*)&sVT[16 + l16][sc + quad * 8];
            half8 bv2 = *(const half8*)&sVT[32 + l16][sc + quad * 8];
            half8 bv3 = *(const half8*)&sVT[48 + l16][sc + quad * 8];
            oacc[0] = __builtin_amdgcn_mfma_f32_16x16x32_f16(aP, bv0, oacc[0], 0, 0, 0);
            oacc[1] = __builtin_amdgcn_mfma_f32_16x16x32_f16(aP, bv1, oacc[1], 0, 0, 0);
            oacc[2] = __builtin_amdgcn_mfma_f32_16x16x32_f16(aP, bv2, oacc[2], 0, 0, 0);
            oacc[3] = __builtin_amdgcn_mfma_f32_16x16x32_f16(aP, bv3, oacc[3], 0, 0, 0);
        }
    }

    float inv[4];
#pragma unroll
    for (int r = 0; r < 4; ++r) {
        float s = lsum[r];
        s += __shfl_xor(s, 1);
        s += __shfl_xor(s, 2);
        s += __shfl_xor(s, 4);
        s += __shfl_xor(s, 8);
        inv[r] = 1.0f / s;
    }
#pragma unroll
    for (int r = 0; r < 4; ++r) {
        size_t rowoff = ((size_t)(b * 3136 + n0 + wid * 16 + quad * 4 + r)) * 640
                        + h * 64 + l16;
#pragma unroll
        for (int tv = 0; tv < 4; ++tv)
            cat[rowoff + tv * 16] = (_Float16)(oacc[tv][r] * inv[r]);
    }
}

// =====================================================================
extern "C" void kernel_launch(void* const* d_in, const int* in_sizes, int n_in,
                              void* d_out, int out_size, void* d_ws, size_t ws_size,
                              hipStream_t stream)
{
    const float* x           = (const float*)d_in[0];
    const float* reduce_w    = (const float*)d_in[3];
    const float* reduce_b    = (const float*)d_in[4];
    const float* reduce_g    = (const float*)d_in[5];
    const float* reduce_beta = (const float*)d_in[6];
    const float* filter_w    = (const float*)d_in[7];
    const float* filter_b    = (const float*)d_in[8];
    const float* filter_g    = (const float*)d_in[9];
    const float* filter_beta = (const float*)d_in[10];
    const float* q_w         = (const float*)d_in[11];
    const float* q_b         = (const float*)d_in[12];
    const float* ln_g        = (const float*)d_in[13];
    const float* ln_b        = (const float*)d_in[14];
    const float* kv_w        = (const float*)d_in[15];
    const float* kv_b        = (const float*)d_in[16];
    const float* kve_w       = (const float*)d_in[17];
    const float* kve_b       = (const float*)d_in[18];
    const float* proj_w      = (const float*)d_in[19];
    const float* proj_b      = (const float*)d_in[20];
    float* out = (float*)d_out;
    _Float16* hws = (_Float16*)d_ws;

    _Float16* x16    = hws + OFF_X16;
    _Float16* q16    = hws + OFF_Q16;
    _Float16* cat16  = hws + OFF_CAT;
    _Float16* r16    = hws + OFF_R16;
    _Float16* pad16  = hws + OFF_PAD;
    _Float16* dwtb16 = hws + OFF_DWTB;
    float*    kv_in  = (float*)(hws + OFF_KVIN);
    _Float16* ln16   = hws + OFF_LN16;
    _Float16* kv16   = hws + OFF_KV16;
    _Float16* wT16   = hws + OFF_WT;
    _Float16* kT16   = hws + OFF_KT;
    _Float16* qw16   = hws + OFF_QW;
    _Float16* kvw16  = hws + OFF_KVW;
    _Float16* pw16   = hws + OFF_PW;
    _Float16* rw16   = hws + OFF_RW;
    _Float16* vt16   = hws + OFF_VT;
    float*    partA  = (float*)(hws + OFF_X16);   // partials 0,1 (x16 is dead by then)
    float*    partB  = (float*)(hws + OFF_PART);  // partials 2,3

    // conversions / transposes / padding init
    cvt_f32_f16<<<dim3(6272), dim3(256), 0, stream>>>(x, x16, 1605632);
    cvt_f32_f16<<<dim3(128),  dim3(256), 0, stream>>>(q_w, qw16, 32768);
    cvt_f32_f16<<<dim3(256),  dim3(256), 0, stream>>>(kv_w, kvw16, 65536);
    cvt_f32_f16<<<dim3(160),  dim3(256), 0, stream>>>(proj_w, pw16, 40960);
    cvt_f32_f16<<<dim3(32),   dim3(256), 0, stream>>>(reduce_w, rw16, 8192);
    transpose_filter16<<<dim3(9216), dim3(256), 0, stream>>>(filter_w, wT16);
    transpose_kve16<<<dim3(4096), dim3(256), 0, stream>>>(kve_w, kT16);
    zero_half<<<dim3(1800), dim3(256), 0, stream>>>(pad16, 460800);

    // q = x @ q_w.T + q_b  -> fp16
    gemm16<0, 2><<<dim3(196, 4), dim3(256), 0, stream>>>(
        x16, qw16, q16, 25088, 512, 512, 512, q_b, nullptr, nullptr);

    // r = fp16(relu(bn(conv1x1(x))))  (25088 x 128 NHWC fp16)
    gemm16<0, 1><<<dim3(196, 1), dim3(256), 0, stream>>>(
        x16, rw16, r16, 25088, 512, 512, 128, reduce_b, reduce_g, reduce_beta);

    // DWT -> padded 30x30x512
    dwt_kernel<<<dim3(6272), dim3(128), 0, stream>>>(r16, pad16);

    // 3x3 conv split-K x4 (x16 now dead; partials 0,1 overwrite it)
    conv_splitk<<<dim3(49, 4, 4), dim3(256), 0, stream>>>(pad16, wT16, partA, partB);
    conv_epi<<<dim3(1568), dim3(256), 0, stream>>>(
        partA, partB, dwtb16, filter_b, filter_g, filter_beta);

    // IDWT -> cat cols 512..639
    idwt_kernel<<<dim3(6272), dim3(128), 0, stream>>>(dwtb16, cat16);

    // kve 2x2 s2 conv -> kv_in (fp32)
    gemm16<2, 0><<<dim3(13, 4), dim3(256), 0, stream>>>(
        dwtb16, kT16, kv_in, 1568, 2048, 0, 512, kve_b, nullptr, nullptr);

    // LayerNorm -> fp16
    ln_kernel<<<dim3(392), dim3(256), 0, stream>>>(kv_in, ln16, ln_g, ln_b);

    // kv = ln @ kv_w.T + kv_b -> fp16 (1568 x 1024)
    gemm16<0, 2><<<dim3(13, 8), dim3(256), 0, stream>>>(
        ln16, kvw16, kv16, 1568, 512, 512, 1024, kv_b, nullptr, nullptr);

    // V^T for attention B-operand
    vt_prep<<<dim3(3584), dim3(256), 0, stream>>>(kv16, vt16);

    // attention -> cat cols 0..511
    attn_mfma<<<dim3(3136), dim3(256), 0, stream>>>(q16, kv16, vt16, cat16);

    // out = cat @ proj_w.T + proj_b  (fp32)
    gemm16<0, 0><<<dim3(196, 4), dim3(256), 0, stream>>>(
        cat16, pw16, out, 25088, 640, 640, 512, proj_b, nullptr, nullptr);
}

// Round 3
// 452.660 us; speedup vs baseline: 1.0859x; 1.0621x over previous
//
#include <hip/hip_runtime.h>
#include <math.h>

// Problem constants: B=8, H=W=56, C=512, N=3136, c4=128, HEADS=8, hd=64, SR=2
// kv sequence length = 14*14 = 196 (padded to 224 for attention)

typedef _Float16 half8 __attribute__((ext_vector_type(8)));
typedef _Float16 half4v __attribute__((ext_vector_type(4)));
typedef float f32x4 __attribute__((ext_vector_type(4)));

// ---------------- workspace layout (offsets in halves; all 16B-aligned) ----
static const size_t OFF_X16  = 0;          // 25088*512 (dead after q/r gemms; reused as conv partials 0,1)
static const size_t OFF_Q16  = 12845056;   // 25088*512
static const size_t OFF_CAT  = 25690112;   // 25088*640
static const size_t OFF_R16  = 41746432;   // 25088*128
static const size_t OFF_PAD  = 44957696;   // 8*900*512  (30x30 zero-padded DWT)
static const size_t OFF_DWTB = 48644096;   // 8*784*512
static const size_t OFF_KVIN = 51855360;   // 1568*512 floats = 3,211,264 halves
static const size_t OFF_LN16 = 55066624;   // 1568*512
static const size_t OFF_KV16 = 55869440;   // 1568*1024
static const size_t OFF_WT   = 57475072;   // 512*4608
static const size_t OFF_KT   = 59834368;   // 512*2048
static const size_t OFF_QW   = 60882944;   // 512*512
static const size_t OFF_KVW  = 61145088;   // 1024*512
static const size_t OFF_PW   = 61669376;   // 512*640
static const size_t OFF_RW   = 61997056;   // 128*512
static const size_t OFF_VT   = 62062592;   // 8*8*64*224 = 917504 (V^T, m-padded)
static const size_t OFF_PART = 62980096;   // conv partials 2,3: 2*3,211,264 floats
// total = 75,825,152 halves = 151.7 MB

#define BN_RSQ 0.9999950000374997f
#define SCL2   0.1803368801111204f   /* 0.125 * log2(e) */
#define PART_STRIDE 3211264          /* 6272*512 floats per conv partial */

__device__ __forceinline__ void async_copy16(const _Float16* g, _Float16* l) {
    __builtin_amdgcn_global_load_lds(
        (const __attribute__((address_space(1))) void*)g,
        (__attribute__((address_space(3))) void*)l, 16, 0, 0);
}

// counted-vmcnt barrier (T4): wait until <=N VMEM ops outstanding, then
// barrier — fused in ONE asm so the compiler can neither reorder LDS ops
// between them nor inject its own vmcnt(0) drain. "memory" clobber = IR fence.
#define WAIT4_BARRIER() asm volatile("s_waitcnt vmcnt(4)\n\ts_barrier" ::: "memory")
#define WAIT0_BARRIER() asm volatile("s_waitcnt vmcnt(0)\n\ts_barrier" ::: "memory")

// =====================================================================
// MFMA fp16 NT GEMM: out[m][n] = sum_k A[m][k]*W[n][k] (+ epilogue)
// ALOAD: 0 plain row-major (lda), 2 kve 2x2 stride-2 on 28x28x512 NHWC
// EPI:   0 = +bias -> fp32, 1 = +bias,BN,ReLU -> fp16, 2 = +bias -> fp16
// 128x128 tile, BK=32, 256 threads (4 waves 2x2), 16x16x32 MFMA.
// 3-buffer LDS, 2-deep prefetch, counted vmcnt(4) (never 0 in main loop).
// =====================================================================
template <int ALOAD, int EPI>
__global__ __launch_bounds__(256) void gemm16(
    const _Float16* __restrict__ A, const _Float16* __restrict__ W,
    void* __restrict__ outp, int M, int K, int lda, int ldc,
    const float* __restrict__ bias, const float* __restrict__ bng,
    const float* __restrict__ bnb)
{
    __shared__ _Float16 sA[3][128 * 32];
    __shared__ _Float16 sB[3][128 * 32];
    const int t = threadIdx.x;
    const int lane = t & 63, wid = t >> 6;
    const int m0 = blockIdx.x * 128, n0 = blockIdx.y * 128;

    const int sr = wid * 16 + (lane >> 2);   // staging tile row (instr0)
    const int sc = (lane & 3) * 8;           // staging col offset (halves)
    const int stA0 = wid * 512;              // dest offsets within a buffer
    const int stA1 = 2048 + wid * 512;

    const _Float16 *aP0, *aP1;
    if constexpr (ALOAD == 0) {
        int r0 = m0 + sr;      if (r0 > M - 1) r0 = M - 1;
        int r1 = m0 + 64 + sr; if (r1 > M - 1) r1 = M - 1;
        aP0 = A + (size_t)r0 * lda + sc;
        aP1 = A + (size_t)r1 * lda + sc;
    } else {
        int m_ = m0 + sr; if (m_ > M - 1) m_ = M - 1;
        int b_ = m_ / 196, rem = m_ - b_ * 196, i_ = rem / 14, j_ = rem - i_ * 14;
        aP0 = A + ((size_t)(b_ * 784 + 2 * i_ * 28 + 2 * j_)) * 512 + sc;
        m_ = m0 + 64 + sr; if (m_ > M - 1) m_ = M - 1;
        b_ = m_ / 196; rem = m_ - b_ * 196; i_ = rem / 14; j_ = rem - i_ * 14;
        aP1 = A + ((size_t)(b_ * 784 + 2 * i_ * 28 + 2 * j_)) * 512 + sc;
    }
    const _Float16* bP0 = W + (size_t)(n0 + sr) * K + sc;
    const _Float16* bP1 = W + (size_t)(n0 + 64 + sr) * K + sc;

    const int mw = wid & 1, nw = wid >> 1;
    const int pAoff = (mw * 64 + (lane & 15)) * 32 + (lane >> 4) * 8;
    const int pBoff = (nw * 64 + (lane & 15)) * 32 + (lane >> 4) * 8;

    f32x4 acc[4][4];
#pragma unroll
    for (int i = 0; i < 4; ++i)
#pragma unroll
        for (int j = 0; j < 4; ++j) acc[i][j] = (f32x4)(0.0f);

    auto aoff_of = [&](int k) -> int {
        if constexpr (ALOAD == 0) {
            return k;
        } else {
            int sub = k >> 9; int ky = sub >> 1, kx = sub & 1;
            return (ky * 28 + kx) * 512 + (k & 511);
        }
    };
    auto stage = [&](int ti, int buf) {
        int k = ti * 32;
        int aOff = aoff_of(k);
        async_copy16(aP0 + aOff, &sA[buf][stA0]);
        async_copy16(aP1 + aOff, &sA[buf][stA1]);
        async_copy16(bP0 + k, &sB[buf][stA0]);
        async_copy16(bP1 + k, &sB[buf][stA1]);
    };

    const int nt = K >> 5;
    // prologue: 2-deep prefetch
    stage(0, 0);
    if (nt > 1) { stage(1, 1); WAIT4_BARRIER(); }
    else        { WAIT0_BARRIER(); }

    int cur = 0;
    for (int i = 0; i < nt; ++i) {
        const _Float16* pA = &sA[cur][0] + pAoff;
        const _Float16* pB = &sB[cur][0] + pBoff;
        half8 aF[4], bF[4];
#pragma unroll
        for (int u = 0; u < 4; ++u) aF[u] = *(const half8*)(pA + u * 512);
#pragma unroll
        for (int u = 0; u < 4; ++u) bF[u] = *(const half8*)(pB + u * 512);

        const bool st = (i + 2 < nt);
        if (st) {
            int nb = cur + 2; if (nb >= 3) nb -= 3;
            stage(i + 2, nb);
        }
#pragma unroll
        for (int u = 0; u < 4; ++u)
#pragma unroll
            for (int j = 0; j < 4; ++j)
                acc[u][j] = __builtin_amdgcn_mfma_f32_16x16x32_f16(
                    aF[u], bF[j], acc[u][j], 0, 0, 0);

        if (i + 1 < nt) {
            if (st) WAIT4_BARRIER();   // tile i+1 done, tile i+2 stays in flight
            else    WAIT0_BARRIER();   // last tile: drain
        }
        ++cur; if (cur == 3) cur = 0;
    }

    // epilogue: C/D layout col=lane&15, row=(lane>>4)*4+reg
    const int orow = m0 + mw * 64 + (lane >> 4) * 4;
    const int ocol = n0 + nw * 64 + (lane & 15);
#pragma unroll
    for (int j = 0; j < 4; ++j) {
        int col = ocol + j * 16;
        float bv = bias[col];
        float g = 0.0f, b2 = 0.0f;
        if constexpr (EPI == 1) { g = bng[col] * BN_RSQ; b2 = bnb[col]; }
#pragma unroll
        for (int i = 0; i < 4; ++i) {
#pragma unroll
            for (int r = 0; r < 4; ++r) {
                int row = orow + i * 16 + r;
                if (row >= M) continue;
                float v = acc[i][j][r] + bv;
                if constexpr (EPI == 1) v = fmaxf(v * g + b2, 0.0f);
                if constexpr (EPI == 0)
                    ((float*)outp)[(size_t)row * ldc + col] = v;
                else
                    ((_Float16*)outp)[(size_t)row * ldc + col] = (_Float16)v;
            }
        }
    }
}

// =====================================================================
// conv3x3 split-K partial GEMM: grid (49, 4, 4); K-group bz covers
// k in [bz*1152, (bz+1)*1152). Writes fp32 partial (no bias).
// A = padded 30x30x512 NHWC fp16; W = wT[n][(ky*3+kx)*512+ci].
// Same 3-buffer counted-vmcnt pipeline as gemm16.
// =====================================================================
__global__ __launch_bounds__(256) void conv_splitk(
    const _Float16* __restrict__ A, const _Float16* __restrict__ W,
    float* __restrict__ partA, float* __restrict__ partB)
{
    __shared__ _Float16 sA[3][128 * 32];
    __shared__ _Float16 sB[3][128 * 32];
    const int t = threadIdx.x;
    const int lane = t & 63, wid = t >> 6;
    const int m0 = blockIdx.x * 128, n0 = blockIdx.y * 128;
    const int kbase = blockIdx.z * 1152;

    const int sr = wid * 16 + (lane >> 2);
    const int sc = (lane & 3) * 8;
    const int stA0 = wid * 512;
    const int stA1 = 2048 + wid * 512;

    int m_ = m0 + sr;
    int b_ = m_ / 784, rem = m_ - b_ * 784, y_ = rem / 28, x_ = rem - y_ * 28;
    const _Float16* aP0 = A + ((size_t)(b_ * 900 + (y_ + 1) * 30 + (x_ + 1))) * 512 + sc;
    m_ = m0 + 64 + sr;
    b_ = m_ / 784; rem = m_ - b_ * 784; y_ = rem / 28; x_ = rem - y_ * 28;
    const _Float16* aP1 = A + ((size_t)(b_ * 900 + (y_ + 1) * 30 + (x_ + 1))) * 512 + sc;
    const _Float16* bP0 = W + (size_t)(n0 + sr) * 4608 + sc;
    const _Float16* bP1 = W + (size_t)(n0 + 64 + sr) * 4608 + sc;

    const int mw = wid & 1, nw = wid >> 1;
    const int pAoff = (mw * 64 + (lane & 15)) * 32 + (lane >> 4) * 8;
    const int pBoff = (nw * 64 + (lane & 15)) * 32 + (lane >> 4) * 8;

    f32x4 acc[4][4];
#pragma unroll
    for (int i = 0; i < 4; ++i)
#pragma unroll
        for (int j = 0; j < 4; ++j) acc[i][j] = (f32x4)(0.0f);

    auto aoff_of = [&](int k) -> int {
        int sub = k >> 9; int s3 = sub / 3;
        int dy = s3 - 1, dx = sub - s3 * 3 - 1;
        return (dy * 30 + dx) * 512 + (k & 511);
    };
    auto stage = [&](int ti, int buf) {
        int k = kbase + ti * 32;
        int aOff = aoff_of(k);
        async_copy16(aP0 + aOff, &sA[buf][stA0]);
        async_copy16(aP1 + aOff, &sA[buf][stA1]);
        async_copy16(bP0 + k, &sB[buf][stA0]);
        async_copy16(bP1 + k, &sB[buf][stA1]);
    };

    const int nt = 36;   // 1152/32
    stage(0, 0);
    stage(1, 1);
    WAIT4_BARRIER();

    int cur = 0;
    for (int i = 0; i < nt; ++i) {
        const _Float16* pA = &sA[cur][0] + pAoff;
        const _Float16* pB = &sB[cur][0] + pBoff;
        half8 aF[4], bF[4];
#pragma unroll
        for (int u = 0; u < 4; ++u) aF[u] = *(const half8*)(pA + u * 512);
#pragma unroll
        for (int u = 0; u < 4; ++u) bF[u] = *(const half8*)(pB + u * 512);

        const bool st = (i + 2 < nt);
        if (st) {
            int nb = cur + 2; if (nb >= 3) nb -= 3;
            stage(i + 2, nb);
        }
#pragma unroll
        for (int u = 0; u < 4; ++u)
#pragma unroll
            for (int j = 0; j < 4; ++j)
                acc[u][j] = __builtin_amdgcn_mfma_f32_16x16x32_f16(
                    aF[u], bF[j], acc[u][j], 0, 0, 0);

        if (i + 1 < nt) {
            if (st) WAIT4_BARRIER();
            else    WAIT0_BARRIER();
        }
        ++cur; if (cur == 3) cur = 0;
    }

    float* dst = (blockIdx.z < 2) ? (partA + (size_t)blockIdx.z * PART_STRIDE)
                                  : (partB + (size_t)(blockIdx.z - 2) * PART_STRIDE);
    const int orow = m0 + mw * 64 + (lane >> 4) * 4;
    const int ocol = n0 + nw * 64 + (lane & 15);
#pragma unroll
    for (int j = 0; j < 4; ++j) {
#pragma unroll
        for (int i = 0; i < 4; ++i)
#pragma unroll
            for (int r = 0; r < 4; ++r)
                dst[(size_t)(orow + i * 16 + r) * 512 + ocol + j * 16] = acc[i][j][r];
    }
}

// conv epilogue: dwtb16 = fp16(relu((p0+p1+p2+p3 + bias) * g*BN_RSQ + beta))
__global__ __launch_bounds__(256) void conv_epi(
    const float* __restrict__ pA, const float* __restrict__ pB,
    _Float16* __restrict__ o, const float* __restrict__ bias,
    const float* __restrict__ bng, const float* __restrict__ bnb)
{
    int i = blockIdx.x * 256 + threadIdx.x;      // 401,408 groups of 8
    size_t base = (size_t)i * 8;
    int c = (int)(base & 511);
    half8 hv;
#pragma unroll
    for (int u = 0; u < 8; u += 4) {
        float4 a0 = *(const float4*)(pA + base + u);
        float4 a1 = *(const float4*)(pA + PART_STRIDE + base + u);
        float4 a2 = *(const float4*)(pB + base + u);
        float4 a3 = *(const float4*)(pB + PART_STRIDE + base + u);
        float s[4] = {a0.x + a1.x + a2.x + a3.x, a0.y + a1.y + a2.y + a3.y,
                      a0.z + a1.z + a2.z + a3.z, a0.w + a1.w + a2.w + a3.w};
#pragma unroll
        for (int v = 0; v < 4; ++v) {
            int cc = c + u + v;
            float val = (s[v] + bias[cc]) * (bng[cc] * BN_RSQ) + bnb[cc];
            hv[u + v] = (_Float16)fmaxf(val, 0.0f);
        }
    }
    *(half8*)(o + base) = hv;
}

// =====================================================================
// small utility kernels
// =====================================================================
__global__ __launch_bounds__(256) void cvt_f32_f16(
    const float* __restrict__ s, _Float16* __restrict__ d, int n8)
{
    int i = blockIdx.x * 256 + threadIdx.x;
    if (i >= n8) return;
    const float4* sp = (const float4*)(s + (size_t)i * 8);
    float4 a = sp[0], b = sp[1];
    half8 h;
    h[0] = (_Float16)a.x; h[1] = (_Float16)a.y; h[2] = (_Float16)a.z; h[3] = (_Float16)a.w;
    h[4] = (_Float16)b.x; h[5] = (_Float16)b.y; h[6] = (_Float16)b.z; h[7] = (_Float16)b.w;
    *(half8*)(d + (size_t)i * 8) = h;
}

__global__ __launch_bounds__(256) void zero_half(_Float16* __restrict__ p, int n8)
{
    int i = blockIdx.x * 256 + threadIdx.x;
    if (i < n8) *(float4*)(p + (size_t)i * 8) = make_float4(0.f, 0.f, 0.f, 0.f);
}

__global__ __launch_bounds__(256) void transpose_filter16(
    const float* __restrict__ fw, _Float16* __restrict__ wT)
{   // wT[n][(ky*3+kx)*512 + ci] = fw[n][ci][ky][kx]; 512*4608
    int idx = blockIdx.x * 256 + threadIdx.x;
    int n = idx / 4608; int r = idx - n * 4608;
    int sub = r >> 9; int ci = r & 511;
    wT[idx] = (_Float16)fw[(size_t)n * 4608 + ci * 9 + sub];
}

__global__ __launch_bounds__(256) void transpose_kve16(
    const float* __restrict__ kw, _Float16* __restrict__ kT)
{   // kT[n][(ky*2+kx)*512 + ci] = kw[n][ci][ky][kx]; 512*2048
    int idx = blockIdx.x * 256 + threadIdx.x;
    int n = idx >> 11; int r = idx & 2047;
    int sub = r >> 9; int ci = r & 511;
    kT[idx] = (_Float16)kw[((size_t)n << 11) + (ci << 2) + sub];
}

// V^T prep: vt[((b*8+h)*64+d)*224 + m] = kv[b][m][512 + h*64 + d], 0 for m>=196
__global__ __launch_bounds__(256) void vt_prep(
    const _Float16* __restrict__ kv, _Float16* __restrict__ vt)
{
    int idx = blockIdx.x * 256 + threadIdx.x;   // 917504 total
    int m = idx % 224;
    int rest = idx / 224;
    int d = rest & 63;
    int bh = rest >> 6;
    int b = bh >> 3, h = bh & 7;
    _Float16 v = (_Float16)0.0f;
    if (m < 196)
        v = kv[((size_t)(b * 196 + m)) * 1024 + 512 + h * 64 + d];
    vt[idx] = v;
}

// =====================================================================
// Haar DWT: rbuf16 (B,56,56,128 NHWC fp16) -> padded (B,30,30,512 NHWC fp16)
// =====================================================================
__global__ __launch_bounds__(128) void dwt_kernel(
    const _Float16* __restrict__ r, _Float16* __restrict__ pad)
{
    int bid = blockIdx.x;            // b*784 + i*28 + j
    int b = bid / 784; int rem = bid - b * 784;
    int i = rem / 28;  int j = rem - i * 28;
    int c = threadIdx.x;
    int y = 2 * i, x = 2 * j;
    size_t base = (size_t)b * 3136;
    _Float16 f1 = r[(base + (size_t)y * 56 + x) * 128 + c];
    _Float16 f2 = r[(base + (size_t)(y + 1) * 56 + x) * 128 + c];
    _Float16 f3 = r[(base + (size_t)y * 56 + (x + 1)) * 128 + c];
    _Float16 f4 = r[(base + (size_t)(y + 1) * 56 + (x + 1)) * 128 + c];
    _Float16 h = (_Float16)0.5f;
    _Float16 x1 = f1 * h, x2 = f2 * h, x3 = f3 * h, x4 = f4 * h;
    _Float16 ll = ((x1 + x2) + x3) + x4;
    _Float16 hl = (((-x1) - x2) + x3) + x4;
    _Float16 lh = (((-x1) + x2) - x3) + x4;
    _Float16 hh = ((x1 - x2) - x3) + x4;
    size_t ob = ((size_t)b * 900 + (size_t)(i + 1) * 30 + (j + 1)) * 512;
    pad[ob + c]       = ll;
    pad[ob + 128 + c] = hl;
    pad[ob + 256 + c] = lh;
    pad[ob + 384 + c] = hh;
}

// =====================================================================
// Haar IDWT: dwt_b16 (B,28,28,512 NHWC fp16) -> cat16 cols 512..639
// =====================================================================
__global__ __launch_bounds__(128) void idwt_kernel(
    const _Float16* __restrict__ d, _Float16* __restrict__ cat)
{
    int bid = blockIdx.x;
    int b = bid / 784; int rem = bid - b * 784;
    int i = rem / 28;  int j = rem - i * 28;
    int c = threadIdx.x;
    size_t ib = ((size_t)b * 784 + (size_t)i * 28 + j) * 512;
    _Float16 ll = d[ib + c];
    _Float16 hl = d[ib + 128 + c];
    _Float16 lh = d[ib + 256 + c];
    _Float16 hh = d[ib + 384 + c];
    _Float16 h = (_Float16)0.5f;
    _Float16 p1 = (((ll - hl) - lh) + hh) * h;
    _Float16 p2 = (((ll - hl) + lh) - hh) * h;
    _Float16 p3 = (((ll + hl) - lh) - hh) * h;
    _Float16 p4 = (((ll + hl) + lh) + hh) * h;
    int y = 2 * i, x = 2 * j;
    size_t rb = (size_t)b * 3136;
    cat[(rb + (size_t)y * 56 + x) * 640 + 512 + c]           = p1;
    cat[(rb + (size_t)y * 56 + x + 1) * 640 + 512 + c]       = p3;
    cat[(rb + (size_t)(y + 1) * 56 + x) * 640 + 512 + c]     = p2;
    cat[(rb + (size_t)(y + 1) * 56 + x + 1) * 640 + 512 + c] = p4;
}

// =====================================================================
// LayerNorm over C=512 (fp32 in, fp16 out), one wave per row
// =====================================================================
__global__ __launch_bounds__(256) void ln_kernel(
    const float* __restrict__ p, _Float16* __restrict__ o,
    const float* __restrict__ g, const float* __restrict__ bta)
{
    int wave = threadIdx.x >> 6;
    int lane = threadIdx.x & 63;
    int row = blockIdx.x * 4 + wave;            // 392*4 = 1568
    const float* rp = p + (size_t)row * 512;
    float v[8];
    *(float4*)&v[0] = *(const float4*)(rp + lane * 8);
    *(float4*)&v[4] = *(const float4*)(rp + lane * 8 + 4);
    float s = ((v[0] + v[1]) + (v[2] + v[3])) + ((v[4] + v[5]) + (v[6] + v[7]));
#pragma unroll
    for (int off = 32; off; off >>= 1) s += __shfl_xor(s, off);
    float mu = s * (1.0f / 512.0f);
    float sq = 0.0f;
#pragma unroll
    for (int i = 0; i < 8; ++i) { v[i] -= mu; sq += v[i] * v[i]; }
#pragma unroll
    for (int off = 32; off; off >>= 1) sq += __shfl_xor(sq, off);
    float inv = 1.0f / sqrtf(sq * (1.0f / 512.0f) + 1e-5f);
    int c = lane * 8;
    half8 hv;
#pragma unroll
    for (int i = 0; i < 8; ++i) hv[i] = (_Float16)(v[i] * inv * g[c + i] + bta[c + i]);
    *(half8*)(o + (size_t)row * 512 + c) = hv;
}

// =====================================================================
// MFMA flash attention. Block = (b, h, 64 q-rows); 4 waves x 16 q-rows.
// Unnormalized softmax (scores tiny), one reduction at the end.
// =====================================================================
__global__ __launch_bounds__(256) void attn_mfma(
    const _Float16* __restrict__ q, const _Float16* __restrict__ kv,
    const _Float16* __restrict__ vt, _Float16* __restrict__ cat)
{
    __shared__ _Float16 sK[64][72];    // K[m][d]
    __shared__ _Float16 sVT[64][72];   // V^T[d][m-chunk]
    __shared__ _Float16 sP[4][16][40]; // per-wave P round-trip
    int bid = blockIdx.x;
    int qt = bid % 49;
    int h  = (bid / 49) & 7;
    int b  = bid / 392;
    int n0 = qt * 64;
    int t = threadIdx.x, lane = t & 63, wid = t >> 6;
    int quad = lane >> 4, l16 = lane & 15;

    const _Float16* qp = q + ((size_t)(b * 3136 + n0 + wid * 16 + l16)) * 512
                           + h * 64 + quad * 8;
    half8 aQ0 = *(const half8*)qp;
    half8 aQ1 = *(const half8*)(qp + 32);

    f32x4 oacc[4];
#pragma unroll
    for (int i = 0; i < 4; ++i) oacc[i] = (f32x4)(0.0f);
    float lsum[4] = {0.f, 0.f, 0.f, 0.f};

    const _Float16* vtb = vt + ((size_t)((b * 8 + h) * 64)) * 224;

    for (int c0 = 0; c0 < 224; c0 += 64) {
        __syncthreads();
#pragma unroll
        for (int it = 0; it < 2; ++it) {
            int slot = t + 256 * it;
            int row = slot >> 3, c8 = (slot & 7) * 8;
            int m = c0 + row; if (m > 195) m = 195;
            *(half8*)&sK[row][c8] =
                *(const half8*)(kv + ((size_t)(b * 196 + m)) * 1024 + h * 64 + c8);
        }
#pragma unroll
        for (int it = 0; it < 2; ++it) {
            int slot = t + 256 * it;
            int row = slot >> 3, c8 = (slot & 7) * 8;
            *(half8*)&sVT[row][c8] =
                *(const half8*)(vtb + (size_t)row * 224 + c0 + c8);
        }
        __syncthreads();

#pragma unroll
        for (int sc = 0; sc < 64; sc += 32) {
            half8 bk00 = *(const half8*)&sK[sc + l16][quad * 8];
            half8 bk01 = *(const half8*)&sK[sc + l16][32 + quad * 8];
            half8 bk10 = *(const half8*)&sK[sc + 16 + l16][quad * 8];
            half8 bk11 = *(const half8*)&sK[sc + 16 + l16][32 + quad * 8];
            f32x4 s0 = (f32x4)(0.0f), s1 = (f32x4)(0.0f);
            s0 = __builtin_amdgcn_mfma_f32_16x16x32_f16(aQ0, bk00, s0, 0, 0, 0);
            s0 = __builtin_amdgcn_mfma_f32_16x16x32_f16(aQ1, bk01, s0, 0, 0, 0);
            s1 = __builtin_amdgcn_mfma_f32_16x16x32_f16(aQ0, bk10, s1, 0, 0, 0);
            s1 = __builtin_amdgcn_mfma_f32_16x16x32_f16(aQ1, bk11, s1, 0, 0, 0);

            int col0 = c0 + sc + l16;
            float msk0 = (col0 < 196) ? 0.0f : -INFINITY;
            float msk1 = (col0 + 16 < 196) ? 0.0f : -INFINITY;
            float p0[4], p1[4];
#pragma unroll
            for (int r = 0; r < 4; ++r) {
                p0[r] = exp2f(s0[r] * SCL2 + msk0);
                p1[r] = exp2f(s1[r] * SCL2 + msk1);
                lsum[r] += p0[r] + p1[r];
            }
#pragma unroll
            for (int r = 0; r < 4; ++r) {
                sP[wid][quad * 4 + r][l16]      = (_Float16)p0[r];
                sP[wid][quad * 4 + r][16 + l16] = (_Float16)p1[r];
            }
            half8 aP = *(const half8*)&sP[wid][l16][quad * 8];
            half8 bv0 = *(const half8*)&sVT[l16][sc + quad * 8];
            half8 bv1 = *(const half8*)&sVT[16 + l16][sc + quad * 8];
            half8 bv2 = *(const half8*)&sVT[32 + l16][sc + quad * 8];
            half8 bv3 = *(const half8*)&sVT[48 + l16][sc + quad * 8];
            oacc[0] = __builtin_amdgcn_mfma_f32_16x16x32_f16(aP, bv0, oacc[0], 0, 0, 0);
            oacc[1] = __builtin_amdgcn_mfma_f32_16x16x32_f16(aP, bv1, oacc[1], 0, 0, 0);
            oacc[2] = __builtin_amdgcn_mfma_f32_16x16x32_f16(aP, bv2, oacc[2], 0, 0, 0);
            oacc[3] = __builtin_amdgcn_mfma_f32_16x16x32_f16(aP, bv3, oacc[3], 0, 0, 0);
        }
    }

    float inv[4];
#pragma unroll
    for (int r = 0; r < 4; ++r) {
        float s = lsum[r];
        s += __shfl_xor(s, 1);
        s += __shfl_xor(s, 2);
        s += __shfl_xor(s, 4);
        s += __shfl_xor(s, 8);
        inv[r] = 1.0f / s;
    }
#pragma unroll
    for (int r = 0; r < 4; ++r) {
        size_t rowoff = ((size_t)(b * 3136 + n0 + wid * 16 + quad * 4 + r)) * 640
                        + h * 64 + l16;
#pragma unroll
        for (int tv = 0; tv < 4; ++tv)
            cat[rowoff + tv * 16] = (_Float16)(oacc[tv][r] * inv[r]);
    }
}

// =====================================================================
extern "C" void kernel_launch(void* const* d_in, const int* in_sizes, int n_in,
                              void* d_out, int out_size, void* d_ws, size_t ws_size,
                              hipStream_t stream)
{
    const float* x           = (const float*)d_in[0];
    const float* reduce_w    = (const float*)d_in[3];
    const float* reduce_b    = (const float*)d_in[4];
    const float* reduce_g    = (const float*)d_in[5];
    const float* reduce_beta = (const float*)d_in[6];
    const float* filter_w    = (const float*)d_in[7];
    const float* filter_b    = (const float*)d_in[8];
    const float* filter_g    = (const float*)d_in[9];
    const float* filter_beta = (const float*)d_in[10];
    const float* q_w         = (const float*)d_in[11];
    const float* q_b         = (const float*)d_in[12];
    const float* ln_g        = (const float*)d_in[13];
    const float* ln_b        = (const float*)d_in[14];
    const float* kv_w        = (const float*)d_in[15];
    const float* kv_b        = (const float*)d_in[16];
    const float* kve_w       = (const float*)d_in[17];
    const float* kve_b       = (const float*)d_in[18];
    const float* proj_w      = (const float*)d_in[19];
    const float* proj_b      = (const float*)d_in[20];
    float* out = (float*)d_out;
    _Float16* hws = (_Float16*)d_ws;

    _Float16* x16    = hws + OFF_X16;
    _Float16* q16    = hws + OFF_Q16;
    _Float16* cat16  = hws + OFF_CAT;
    _Float16* r16    = hws + OFF_R16;
    _Float16* pad16  = hws + OFF_PAD;
    _Float16* dwtb16 = hws + OFF_DWTB;
    float*    kv_in  = (float*)(hws + OFF_KVIN);
    _Float16* ln16   = hws + OFF_LN16;
    _Float16* kv16   = hws + OFF_KV16;
    _Float16* wT16   = hws + OFF_WT;
    _Float16* kT16   = hws + OFF_KT;
    _Float16* qw16   = hws + OFF_QW;
    _Float16* kvw16  = hws + OFF_KVW;
    _Float16* pw16   = hws + OFF_PW;
    _Float16* rw16   = hws + OFF_RW;
    _Float16* vt16   = hws + OFF_VT;
    float*    partA  = (float*)(hws + OFF_X16);   // partials 0,1 (x16 is dead by then)
    float*    partB  = (float*)(hws + OFF_PART);  // partials 2,3

    // conversions / transposes / padding init
    cvt_f32_f16<<<dim3(6272), dim3(256), 0, stream>>>(x, x16, 1605632);
    cvt_f32_f16<<<dim3(128),  dim3(256), 0, stream>>>(q_w, qw16, 32768);
    cvt_f32_f16<<<dim3(256),  dim3(256), 0, stream>>>(kv_w, kvw16, 65536);
    cvt_f32_f16<<<dim3(160),  dim3(256), 0, stream>>>(proj_w, pw16, 40960);
    cvt_f32_f16<<<dim3(32),   dim3(256), 0, stream>>>(reduce_w, rw16, 8192);
    transpose_filter16<<<dim3(9216), dim3(256), 0, stream>>>(filter_w, wT16);
    transpose_kve16<<<dim3(4096), dim3(256), 0, stream>>>(kve_w, kT16);
    zero_half<<<dim3(1800), dim3(256), 0, stream>>>(pad16, 460800);

    // q = x @ q_w.T + q_b  -> fp16
    gemm16<0, 2><<<dim3(196, 4), dim3(256), 0, stream>>>(
        x16, qw16, q16, 25088, 512, 512, 512, q_b, nullptr, nullptr);

    // r = fp16(relu(bn(conv1x1(x))))  (25088 x 128 NHWC fp16)
    gemm16<0, 1><<<dim3(196, 1), dim3(256), 0, stream>>>(
        x16, rw16, r16, 25088, 512, 512, 128, reduce_b, reduce_g, reduce_beta);

    // DWT -> padded 30x30x512
    dwt_kernel<<<dim3(6272), dim3(128), 0, stream>>>(r16, pad16);

    // 3x3 conv split-K x4 (x16 now dead; partials 0,1 overwrite it)
    conv_splitk<<<dim3(49, 4, 4), dim3(256), 0, stream>>>(pad16, wT16, partA, partB);
    conv_epi<<<dim3(1568), dim3(256), 0, stream>>>(
        partA, partB, dwtb16, filter_b, filter_g, filter_beta);

    // IDWT -> cat cols 512..639
    idwt_kernel<<<dim3(6272), dim3(128), 0, stream>>>(dwtb16, cat16);

    // kve 2x2 s2 conv -> kv_in (fp32)
    gemm16<2, 0><<<dim3(13, 4), dim3(256), 0, stream>>>(
        dwtb16, kT16, kv_in, 1568, 2048, 0, 512, kve_b, nullptr, nullptr);

    // LayerNorm -> fp16
    ln_kernel<<<dim3(392), dim3(256), 0, stream>>>(kv_in, ln16, ln_g, ln_b);

    // kv = ln @ kv_w.T + kv_b -> fp16 (1568 x 1024)
    gemm16<0, 2><<<dim3(13, 8), dim3(256), 0, stream>>>(
        ln16, kvw16, kv16, 1568, 512, 512, 1024, kv_b, nullptr, nullptr);

    // V^T for attention B-operand
    vt_prep<<<dim3(3584), dim3(256), 0, stream>>>(kv16, vt16);

    // attention -> cat cols 0..511
    attn_mfma<<<dim3(3136), dim3(256), 0, stream>>>(q16, kv16, vt16, cat16);

    // out = cat @ proj_w.T + proj_b  (fp32)
    gemm16<0, 0><<<dim3(196, 4), dim3(256), 0, stream>>>(
        cat16, pw16, out, 25088, 640, 640, 512, proj_b, nullptr, nullptr);
}

// Round 4
// 421.502 us; speedup vs baseline: 1.1661x; 1.0739x over previous
//
#include <hip/hip_runtime.h>
#include <math.h>

// Problem constants: B=8, H=W=56, C=512, N=3136, c4=128, HEADS=8, hd=64, SR=2
// kv sequence length = 14*14 = 196 (padded to 224 for attention)

typedef _Float16 half8 __attribute__((ext_vector_type(8)));
typedef _Float16 half4v __attribute__((ext_vector_type(4)));
typedef float f32x4 __attribute__((ext_vector_type(4)));

// ---------------- workspace layout (offsets in halves; all 16B-aligned) ----
static const size_t OFF_X16  = 0;          // 25088*512 (dead after q/r gemms; reused as conv partials 0,1 then kve partials)
static const size_t OFF_Q16  = 12845056;   // 25088*512
static const size_t OFF_CAT  = 25690112;   // 25088*640
static const size_t OFF_R16  = 41746432;   // 25088*128
static const size_t OFF_PAD  = 44957696;   // 8*900*512  (30x30 zero-padded DWT)
static const size_t OFF_DWTB = 48644096;   // 8*784*512
static const size_t OFF_KVIN = 51855360;   // (spare)
static const size_t OFF_LN16 = 55066624;   // 1568*512
static const size_t OFF_KV16 = 55869440;   // 1568*1024
static const size_t OFF_WT   = 57475072;   // 512*4608
static const size_t OFF_KT   = 59834368;   // 512*2048
static const size_t OFF_QW   = 60882944;   // 512*512
static const size_t OFF_KVW  = 61145088;   // 1024*512
static const size_t OFF_PW   = 61669376;   // 512*640
static const size_t OFF_RW   = 61997056;   // 128*512
static const size_t OFF_VT   = 62062592;   // 8*8*64*224 = 917504 (V^T, m-padded)
static const size_t OFF_PART = 62980096;   // conv partials 2,3: 2*3,211,264 floats
// total = 75,825,152 halves = 151.7 MB

#define BN_RSQ 0.9999950000374997f
#define SCL2   0.1803368801111204f   /* 0.125 * log2(e) */
#define PART_STRIDE 3211264          /* 6272*512 floats per conv partial */
#define KVE_STRIDE  802816           /* 1568*512 floats per kve partial */

__device__ __forceinline__ void async_copy16(const _Float16* g, _Float16* l) {
    __builtin_amdgcn_global_load_lds(
        (const __attribute__((address_space(1))) void*)g,
        (__attribute__((address_space(3))) void*)l, 16, 0, 0);
}

// counted-vmcnt barrier (T4): wait until <=N VMEM ops outstanding, then
// barrier — fused in ONE asm so the compiler can neither reorder LDS ops
// between them nor inject its own vmcnt(0) drain. "memory" clobber = IR fence.
#define WAIT4_BARRIER() asm volatile("s_waitcnt vmcnt(4)\n\ts_barrier" ::: "memory")
#define WAIT0_BARRIER() asm volatile("s_waitcnt vmcnt(0)\n\ts_barrier" ::: "memory")

// =====================================================================
// MFMA fp16 NT GEMM: out[m][n] = sum_k A[m][k]*W[n][k] (+ epilogue)
// ALOAD: 0 plain row-major (lda), 2 kve 2x2 stride-2 on 28x28x512 NHWC
//        (for ALOAD=2, lda carries the W row-stride instead)
// EPI:   0 = +bias -> fp32, 1 = +bias,BN,ReLU -> fp16, 2 = +bias -> fp16
//        3 = raw fp32 partial at blockIdx.z*KVE_STRIDE (split-K, no bias)
// 128x128 tile, BK=32, 256 threads (4 waves 2x2), 16x16x32 MFMA.
// 3-buffer LDS, 2-deep prefetch, counted vmcnt(4).
// XCD-chunked blockIdx swizzle (T1) when nwg%8==0: chunk = contiguous
// bx range across all by -> per-XCD A-panel L2 reuse.
// =====================================================================
template <int ALOAD, int EPI>
__global__ __launch_bounds__(256) void gemm16(
    const _Float16* __restrict__ A, const _Float16* __restrict__ W,
    void* __restrict__ outp, int M, int K, int lda, int ldc,
    const float* __restrict__ bias, const float* __restrict__ bng,
    const float* __restrict__ bnb)
{
    __shared__ _Float16 sA[3][128 * 32];
    __shared__ _Float16 sB[3][128 * 32];
    const int t = threadIdx.x;
    const int lane = t & 63, wid = t >> 6;

    int bx = blockIdx.x, by = blockIdx.y;
    {
        int nwg = gridDim.x * gridDim.y;
        if ((nwg & 7) == 0) {            // bijective XCD-chunked remap
            int orig = by * gridDim.x + bx;
            int cs = nwg >> 3;
            int wg = (orig & 7) * cs + (orig >> 3);
            by = wg % gridDim.y;
            bx = wg / gridDim.y;
        }
    }
    const int m0 = bx * 128, n0 = by * 128;
    const int kbase = blockIdx.z * K;        // split-K group (z=0 normally)

    const int sr = wid * 16 + (lane >> 2);   // staging tile row (instr0)
    const int sc = (lane & 3) * 8;           // staging col offset (halves)
    const int stA0 = wid * 512;              // dest offsets within a buffer
    const int stA1 = 2048 + wid * 512;

    const _Float16 *aP0, *aP1;
    if constexpr (ALOAD == 0) {
        int r0 = m0 + sr;      if (r0 > M - 1) r0 = M - 1;
        int r1 = m0 + 64 + sr; if (r1 > M - 1) r1 = M - 1;
        aP0 = A + (size_t)r0 * lda + sc;
        aP1 = A + (size_t)r1 * lda + sc;
    } else {
        int m_ = m0 + sr; if (m_ > M - 1) m_ = M - 1;
        int b_ = m_ / 196, rem = m_ - b_ * 196, i_ = rem / 14, j_ = rem - i_ * 14;
        aP0 = A + ((size_t)(b_ * 784 + 2 * i_ * 28 + 2 * j_)) * 512 + sc;
        m_ = m0 + 64 + sr; if (m_ > M - 1) m_ = M - 1;
        b_ = m_ / 196; rem = m_ - b_ * 196; i_ = rem / 14; j_ = rem - i_ * 14;
        aP1 = A + ((size_t)(b_ * 784 + 2 * i_ * 28 + 2 * j_)) * 512 + sc;
    }
    const int ldw = (ALOAD == 2) ? lda : K;  // W row stride
    const _Float16* bP0 = W + (size_t)(n0 + sr) * ldw + sc;
    const _Float16* bP1 = W + (size_t)(n0 + 64 + sr) * ldw + sc;

    const int mw = wid & 1, nw = wid >> 1;
    const int pAoff = (mw * 64 + (lane & 15)) * 32 + (lane >> 4) * 8;
    const int pBoff = (nw * 64 + (lane & 15)) * 32 + (lane >> 4) * 8;

    f32x4 acc[4][4];
#pragma unroll
    for (int i = 0; i < 4; ++i)
#pragma unroll
        for (int j = 0; j < 4; ++j) acc[i][j] = (f32x4)(0.0f);

    auto aoff_of = [&](int k) -> int {
        if constexpr (ALOAD == 0) {
            return k;
        } else {
            int sub = k >> 9; int ky = sub >> 1, kx = sub & 1;
            return (ky * 28 + kx) * 512 + (k & 511);
        }
    };
    auto stage = [&](int ti, int buf) {
        int k = kbase + ti * 32;
        int aOff = aoff_of(k);
        async_copy16(aP0 + aOff, &sA[buf][stA0]);
        async_copy16(aP1 + aOff, &sA[buf][stA1]);
        async_copy16(bP0 + k, &sB[buf][stA0]);
        async_copy16(bP1 + k, &sB[buf][stA1]);
    };

    const int nt = K >> 5;
    // prologue: 2-deep prefetch
    stage(0, 0);
    if (nt > 1) { stage(1, 1); WAIT4_BARRIER(); }
    else        { WAIT0_BARRIER(); }

    int cur = 0;
    for (int i = 0; i < nt; ++i) {
        const _Float16* pA = &sA[cur][0] + pAoff;
        const _Float16* pB = &sB[cur][0] + pBoff;
        half8 aF[4], bF[4];
#pragma unroll
        for (int u = 0; u < 4; ++u) aF[u] = *(const half8*)(pA + u * 512);
#pragma unroll
        for (int u = 0; u < 4; ++u) bF[u] = *(const half8*)(pB + u * 512);

        const bool st = (i + 2 < nt);
        if (st) {
            int nb = cur + 2; if (nb >= 3) nb -= 3;
            stage(i + 2, nb);
        }
#pragma unroll
        for (int u = 0; u < 4; ++u)
#pragma unroll
            for (int j = 0; j < 4; ++j)
                acc[u][j] = __builtin_amdgcn_mfma_f32_16x16x32_f16(
                    aF[u], bF[j], acc[u][j], 0, 0, 0);

        if (i + 1 < nt) {
            if (st) WAIT4_BARRIER();   // tile i+1 done, tile i+2 stays in flight
            else    WAIT0_BARRIER();   // last tile: drain
        }
        ++cur; if (cur == 3) cur = 0;
    }

    // epilogue: C/D layout col=lane&15, row=(lane>>4)*4+reg
    const int orow = m0 + mw * 64 + (lane >> 4) * 4;
    const int ocol = n0 + nw * 64 + (lane & 15);
#pragma unroll
    for (int j = 0; j < 4; ++j) {
        int col = ocol + j * 16;
        float bv = 0.0f, g = 0.0f, b2 = 0.0f;
        if constexpr (EPI != 3) bv = bias[col];
        if constexpr (EPI == 1) { g = bng[col] * BN_RSQ; b2 = bnb[col]; }
#pragma unroll
        for (int i = 0; i < 4; ++i) {
#pragma unroll
            for (int r = 0; r < 4; ++r) {
                int row = orow + i * 16 + r;
                if (row >= M) continue;
                float v = acc[i][j][r] + bv;
                if constexpr (EPI == 1) v = fmaxf(v * g + b2, 0.0f);
                if constexpr (EPI == 0)
                    ((float*)outp)[(size_t)row * ldc + col] = v;
                else if constexpr (EPI == 3)
                    ((float*)outp)[(size_t)blockIdx.z * KVE_STRIDE
                                   + (size_t)row * ldc + col] = v;
                else
                    ((_Float16*)outp)[(size_t)row * ldc + col] = (_Float16)v;
            }
        }
    }
}

// =====================================================================
// conv3x3 split-K partial GEMM: 784 blocks 1-D; XCD-chunked swizzle maps
// each XCD to contiguous (by,bz) chunks (shared B panel + A slice).
// K-group bz covers k in [bz*1152, (bz+1)*1152). Writes fp32 partial.
// A = padded 30x30x512 NHWC fp16; W = wT[n][(ky*3+kx)*512+ci].
// =====================================================================
__global__ __launch_bounds__(256) void conv_splitk(
    const _Float16* __restrict__ A, const _Float16* __restrict__ W,
    float* __restrict__ partA, float* __restrict__ partB)
{
    __shared__ _Float16 sA[3][128 * 32];
    __shared__ _Float16 sB[3][128 * 32];
    const int t = threadIdx.x;
    const int lane = t & 63, wid = t >> 6;

    // bijective XCD-chunked remap: 784 = 8 * 98; chunk = (by,bz) pair row
    int orig = blockIdx.x;
    int wg = (orig & 7) * 98 + (orig >> 3);
    int bx = wg % 49;  int c = wg / 49;    // c in 0..15
    int by = c & 3,    bz = c >> 2;

    const int m0 = bx * 128, n0 = by * 128;
    const int kbase = bz * 1152;

    const int sr = wid * 16 + (lane >> 2);
    const int sc = (lane & 3) * 8;
    const int stA0 = wid * 512;
    const int stA1 = 2048 + wid * 512;

    int m_ = m0 + sr;
    int b_ = m_ / 784, rem = m_ - b_ * 784, y_ = rem / 28, x_ = rem - y_ * 28;
    const _Float16* aP0 = A + ((size_t)(b_ * 900 + (y_ + 1) * 30 + (x_ + 1))) * 512 + sc;
    m_ = m0 + 64 + sr;
    b_ = m_ / 784; rem = m_ - b_ * 784; y_ = rem / 28; x_ = rem - y_ * 28;
    const _Float16* aP1 = A + ((size_t)(b_ * 900 + (y_ + 1) * 30 + (x_ + 1))) * 512 + sc;
    const _Float16* bP0 = W + (size_t)(n0 + sr) * 4608 + sc;
    const _Float16* bP1 = W + (size_t)(n0 + 64 + sr) * 4608 + sc;

    const int mw = wid & 1, nw = wid >> 1;
    const int pAoff = (mw * 64 + (lane & 15)) * 32 + (lane >> 4) * 8;
    const int pBoff = (nw * 64 + (lane & 15)) * 32 + (lane >> 4) * 8;

    f32x4 acc[4][4];
#pragma unroll
    for (int i = 0; i < 4; ++i)
#pragma unroll
        for (int j = 0; j < 4; ++j) acc[i][j] = (f32x4)(0.0f);

    auto aoff_of = [&](int k) -> int {
        int sub = k >> 9; int s3 = sub / 3;
        int dy = s3 - 1, dx = sub - s3 * 3 - 1;
        return (dy * 30 + dx) * 512 + (k & 511);
    };
    auto stage = [&](int ti, int buf) {
        int k = kbase + ti * 32;
        int aOff = aoff_of(k);
        async_copy16(aP0 + aOff, &sA[buf][stA0]);
        async_copy16(aP1 + aOff, &sA[buf][stA1]);
        async_copy16(bP0 + k, &sB[buf][stA0]);
        async_copy16(bP1 + k, &sB[buf][stA1]);
    };

    const int nt = 36;   // 1152/32
    stage(0, 0);
    stage(1, 1);
    WAIT4_BARRIER();

    int cur = 0;
    for (int i = 0; i < nt; ++i) {
        const _Float16* pA = &sA[cur][0] + pAoff;
        const _Float16* pB = &sB[cur][0] + pBoff;
        half8 aF[4], bF[4];
#pragma unroll
        for (int u = 0; u < 4; ++u) aF[u] = *(const half8*)(pA + u * 512);
#pragma unroll
        for (int u = 0; u < 4; ++u) bF[u] = *(const half8*)(pB + u * 512);

        const bool st = (i + 2 < nt);
        if (st) {
            int nb = cur + 2; if (nb >= 3) nb -= 3;
            stage(i + 2, nb);
        }
#pragma unroll
        for (int u = 0; u < 4; ++u)
#pragma unroll
            for (int j = 0; j < 4; ++j)
                acc[u][j] = __builtin_amdgcn_mfma_f32_16x16x32_f16(
                    aF[u], bF[j], acc[u][j], 0, 0, 0);

        if (i + 1 < nt) {
            if (st) WAIT4_BARRIER();
            else    WAIT0_BARRIER();
        }
        ++cur; if (cur == 3) cur = 0;
    }

    float* dst = (bz < 2) ? (partA + (size_t)bz * PART_STRIDE)
                          : (partB + (size_t)(bz - 2) * PART_STRIDE);
    const int orow = m0 + mw * 64 + (lane >> 4) * 4;
    const int ocol = n0 + nw * 64 + (lane & 15);
#pragma unroll
    for (int j = 0; j < 4; ++j) {
#pragma unroll
        for (int i = 0; i < 4; ++i)
#pragma unroll
            for (int r = 0; r < 4; ++r)
                dst[(size_t)(orow + i * 16 + r) * 512 + ocol + j * 16] = acc[i][j][r];
    }
}

// conv epilogue: dwtb16 = fp16(relu((p0+p1+p2+p3 + bias) * g*BN_RSQ + beta))
__global__ __launch_bounds__(256) void conv_epi(
    const float* __restrict__ pA, const float* __restrict__ pB,
    _Float16* __restrict__ o, const float* __restrict__ bias,
    const float* __restrict__ bng, const float* __restrict__ bnb)
{
    int i = blockIdx.x * 256 + threadIdx.x;      // 401,408 groups of 8
    size_t base = (size_t)i * 8;
    int c = (int)(base & 511);
    half8 hv;
#pragma unroll
    for (int u = 0; u < 8; u += 4) {
        float4 a0 = *(const float4*)(pA + base + u);
        float4 a1 = *(const float4*)(pA + PART_STRIDE + base + u);
        float4 a2 = *(const float4*)(pB + base + u);
        float4 a3 = *(const float4*)(pB + PART_STRIDE + base + u);
        float s[4] = {a0.x + a1.x + a2.x + a3.x, a0.y + a1.y + a2.y + a3.y,
                      a0.z + a1.z + a2.z + a3.z, a0.w + a1.w + a2.w + a3.w};
#pragma unroll
        for (int v = 0; v < 4; ++v) {
            int cc = c + u + v;
            float val = (s[v] + bias[cc]) * (bng[cc] * BN_RSQ) + bnb[cc];
            hv[u + v] = (_Float16)fmaxf(val, 0.0f);
        }
    }
    *(half8*)(o + base) = hv;
}

// =====================================================================
// small utility kernels
// =====================================================================
__global__ __launch_bounds__(256) void cvt_f32_f16(
    const float* __restrict__ s, _Float16* __restrict__ d, int n8)
{
    int i = blockIdx.x * 256 + threadIdx.x;
    if (i >= n8) return;
    const float4* sp = (const float4*)(s + (size_t)i * 8);
    float4 a = sp[0], b = sp[1];
    half8 h;
    h[0] = (_Float16)a.x; h[1] = (_Float16)a.y; h[2] = (_Float16)a.z; h[3] = (_Float16)a.w;
    h[4] = (_Float16)b.x; h[5] = (_Float16)b.y; h[6] = (_Float16)b.z; h[7] = (_Float16)b.w;
    *(half8*)(d + (size_t)i * 8) = h;
}

__global__ __launch_bounds__(256) void zero_half(_Float16* __restrict__ p, int n8)
{
    int i = blockIdx.x * 256 + threadIdx.x;
    if (i < n8) *(float4*)(p + (size_t)i * 8) = make_float4(0.f, 0.f, 0.f, 0.f);
}

__global__ __launch_bounds__(256) void transpose_filter16(
    const float* __restrict__ fw, _Float16* __restrict__ wT)
{   // wT[n][(ky*3+kx)*512 + ci] = fw[n][ci][ky][kx]; 512*4608
    int idx = blockIdx.x * 256 + threadIdx.x;
    int n = idx / 4608; int r = idx - n * 4608;
    int sub = r >> 9; int ci = r & 511;
    wT[idx] = (_Float16)fw[(size_t)n * 4608 + ci * 9 + sub];
}

__global__ __launch_bounds__(256) void transpose_kve16(
    const float* __restrict__ kw, _Float16* __restrict__ kT)
{   // kT[n][(ky*2+kx)*512 + ci] = kw[n][ci][ky][kx]; 512*2048
    int idx = blockIdx.x * 256 + threadIdx.x;
    int n = idx >> 11; int r = idx & 2047;
    int sub = r >> 9; int ci = r & 511;
    kT[idx] = (_Float16)kw[((size_t)n << 11) + (ci << 2) + sub];
}

// V^T prep: vt[((b*8+h)*64+d)*224 + m] = kv[b][m][512 + h*64 + d], 0 for m>=196
__global__ __launch_bounds__(256) void vt_prep(
    const _Float16* __restrict__ kv, _Float16* __restrict__ vt)
{
    int idx = blockIdx.x * 256 + threadIdx.x;   // 917504 total
    int m = idx % 224;
    int rest = idx / 224;
    int d = rest & 63;
    int bh = rest >> 6;
    int b = bh >> 3, h = bh & 7;
    _Float16 v = (_Float16)0.0f;
    if (m < 196)
        v = kv[((size_t)(b * 196 + m)) * 1024 + 512 + h * 64 + d];
    vt[idx] = v;
}

// =====================================================================
// Haar DWT: rbuf16 (B,56,56,128 NHWC fp16) -> padded (B,30,30,512 NHWC fp16)
// =====================================================================
__global__ __launch_bounds__(128) void dwt_kernel(
    const _Float16* __restrict__ r, _Float16* __restrict__ pad)
{
    int bid = blockIdx.x;            // b*784 + i*28 + j
    int b = bid / 784; int rem = bid - b * 784;
    int i = rem / 28;  int j = rem - i * 28;
    int c = threadIdx.x;
    int y = 2 * i, x = 2 * j;
    size_t base = (size_t)b * 3136;
    _Float16 f1 = r[(base + (size_t)y * 56 + x) * 128 + c];
    _Float16 f2 = r[(base + (size_t)(y + 1) * 56 + x) * 128 + c];
    _Float16 f3 = r[(base + (size_t)y * 56 + (x + 1)) * 128 + c];
    _Float16 f4 = r[(base + (size_t)(y + 1) * 56 + (x + 1)) * 128 + c];
    _Float16 h = (_Float16)0.5f;
    _Float16 x1 = f1 * h, x2 = f2 * h, x3 = f3 * h, x4 = f4 * h;
    _Float16 ll = ((x1 + x2) + x3) + x4;
    _Float16 hl = (((-x1) - x2) + x3) + x4;
    _Float16 lh = (((-x1) + x2) - x3) + x4;
    _Float16 hh = ((x1 - x2) - x3) + x4;
    size_t ob = ((size_t)b * 900 + (size_t)(i + 1) * 30 + (j + 1)) * 512;
    pad[ob + c]       = ll;
    pad[ob + 128 + c] = hl;
    pad[ob + 256 + c] = lh;
    pad[ob + 384 + c] = hh;
}

// =====================================================================
// Haar IDWT: dwt_b16 (B,28,28,512 NHWC fp16) -> cat16 cols 512..639
// =====================================================================
__global__ __launch_bounds__(128) void idwt_kernel(
    const _Float16* __restrict__ d, _Float16* __restrict__ cat)
{
    int bid = blockIdx.x;
    int b = bid / 784; int rem = bid - b * 784;
    int i = rem / 28;  int j = rem - i * 28;
    int c = threadIdx.x;
    size_t ib = ((size_t)b * 784 + (size_t)i * 28 + j) * 512;
    _Float16 ll = d[ib + c];
    _Float16 hl = d[ib + 128 + c];
    _Float16 lh = d[ib + 256 + c];
    _Float16 hh = d[ib + 384 + c];
    _Float16 h = (_Float16)0.5f;
    _Float16 p1 = (((ll - hl) - lh) + hh) * h;
    _Float16 p2 = (((ll - hl) + lh) - hh) * h;
    _Float16 p3 = (((ll + hl) - lh) - hh) * h;
    _Float16 p4 = (((ll + hl) + lh) + hh) * h;
    int y = 2 * i, x = 2 * j;
    size_t rb = (size_t)b * 3136;
    cat[(rb + (size_t)y * 56 + x) * 640 + 512 + c]           = p1;
    cat[(rb + (size_t)y * 56 + x + 1) * 640 + 512 + c]       = p3;
    cat[(rb + (size_t)(y + 1) * 56 + x) * 640 + 512 + c]     = p2;
    cat[(rb + (size_t)(y + 1) * 56 + x + 1) * 640 + 512 + c] = p4;
}

// =====================================================================
// LayerNorm over C=512, fused kve split-K reduction:
// in = sum_z part[z*KVE_STRIDE + row*512 + c] + kve_b[c]; fp16 out.
// One wave per row.
// =====================================================================
__global__ __launch_bounds__(256) void ln_kernel(
    const float* __restrict__ part, _Float16* __restrict__ o,
    const float* __restrict__ g, const float* __restrict__ bta,
    const float* __restrict__ kvb)
{
    int wave = threadIdx.x >> 6;
    int lane = threadIdx.x & 63;
    int row = blockIdx.x * 4 + wave;            // 392*4 = 1568
    int c = lane * 8;
    const float* rp = part + (size_t)row * 512 + c;
    float v[8];
#pragma unroll
    for (int i = 0; i < 8; i += 4) {
        float4 a0 = *(const float4*)(rp + i);
        float4 a1 = *(const float4*)(rp + KVE_STRIDE + i);
        float4 a2 = *(const float4*)(rp + 2 * KVE_STRIDE + i);
        float4 a3 = *(const float4*)(rp + 3 * KVE_STRIDE + i);
        v[i + 0] = (a0.x + a1.x) + (a2.x + a3.x) + kvb[c + i + 0];
        v[i + 1] = (a0.y + a1.y) + (a2.y + a3.y) + kvb[c + i + 1];
        v[i + 2] = (a0.z + a1.z) + (a2.z + a3.z) + kvb[c + i + 2];
        v[i + 3] = (a0.w + a1.w) + (a2.w + a3.w) + kvb[c + i + 3];
    }
    float s = ((v[0] + v[1]) + (v[2] + v[3])) + ((v[4] + v[5]) + (v[6] + v[7]));
#pragma unroll
    for (int off = 32; off; off >>= 1) s += __shfl_xor(s, off);
    float mu = s * (1.0f / 512.0f);
    float sq = 0.0f;
#pragma unroll
    for (int i = 0; i < 8; ++i) { v[i] -= mu; sq += v[i] * v[i]; }
#pragma unroll
    for (int off = 32; off; off >>= 1) sq += __shfl_xor(sq, off);
    float inv = 1.0f / sqrtf(sq * (1.0f / 512.0f) + 1e-5f);
    half8 hv;
#pragma unroll
    for (int i = 0; i < 8; ++i) hv[i] = (_Float16)(v[i] * inv * g[c + i] + bta[c + i]);
    *(half8*)(o + (size_t)row * 512 + c) = hv;
}

// =====================================================================
// MFMA flash attention. Block = (b, h, 64 q-rows); 4 waves x 16 q-rows.
// Unnormalized softmax (scores tiny), one reduction at the end.
// =====================================================================
__global__ __launch_bounds__(256) void attn_mfma(
    const _Float16* __restrict__ q, const _Float16* __restrict__ kv,
    const _Float16* __restrict__ vt, _Float16* __restrict__ cat)
{
    __shared__ _Float16 sK[64][72];    // K[m][d]
    __shared__ _Float16 sVT[64][72];   // V^T[d][m-chunk]
    __shared__ _Float16 sP[4][16][40]; // per-wave P round-trip
    int bid = blockIdx.x;
    int qt = bid % 49;
    int h  = (bid / 49) & 7;
    int b  = bid / 392;
    int n0 = qt * 64;
    int t = threadIdx.x, lane = t & 63, wid = t >> 6;
    int quad = lane >> 4, l16 = lane & 15;

    const _Float16* qp = q + ((size_t)(b * 3136 + n0 + wid * 16 + l16)) * 512
                           + h * 64 + quad * 8;
    half8 aQ0 = *(const half8*)qp;
    half8 aQ1 = *(const half8*)(qp + 32);

    f32x4 oacc[4];
#pragma unroll
    for (int i = 0; i < 4; ++i) oacc[i] = (f32x4)(0.0f);
    float lsum[4] = {0.f, 0.f, 0.f, 0.f};

    const _Float16* vtb = vt + ((size_t)((b * 8 + h) * 64)) * 224;

    for (int c0 = 0; c0 < 224; c0 += 64) {
        __syncthreads();
#pragma unroll
        for (int it = 0; it < 2; ++it) {
            int slot = t + 256 * it;
            int row = slot >> 3, c8 = (slot & 7) * 8;
            int m = c0 + row; if (m > 195) m = 195;
            *(half8*)&sK[row][c8] =
                *(const half8*)(kv + ((size_t)(b * 196 + m)) * 1024 + h * 64 + c8);
        }
#pragma unroll
        for (int it = 0; it < 2; ++it) {
            int slot = t + 256 * it;
            int row = slot >> 3, c8 = (slot & 7) * 8;
            *(half8*)&sVT[row][c8] =
                *(const half8*)(vtb + (size_t)row * 224 + c0 + c8);
        }
        __syncthreads();

#pragma unroll
        for (int sc = 0; sc < 64; sc += 32) {
            half8 bk00 = *(const half8*)&sK[sc + l16][quad * 8];
            half8 bk01 = *(const half8*)&sK[sc + l16][32 + quad * 8];
            half8 bk10 = *(const half8*)&sK[sc + 16 + l16][quad * 8];
            half8 bk11 = *(const half8*)&sK[sc + 16 + l16][32 + quad * 8];
            f32x4 s0 = (f32x4)(0.0f), s1 = (f32x4)(0.0f);
            s0 = __builtin_amdgcn_mfma_f32_16x16x32_f16(aQ0, bk00, s0, 0, 0, 0);
            s0 = __builtin_amdgcn_mfma_f32_16x16x32_f16(aQ1, bk01, s0, 0, 0, 0);
            s1 = __builtin_amdgcn_mfma_f32_16x16x32_f16(aQ0, bk10, s1, 0, 0, 0);
            s1 = __builtin_amdgcn_mfma_f32_16x16x32_f16(aQ1, bk11, s1, 0, 0, 0);

            int col0 = c0 + sc + l16;
            float msk0 = (col0 < 196) ? 0.0f : -INFINITY;
            float msk1 = (col0 + 16 < 196) ? 0.0f : -INFINITY;
            float p0[4], p1[4];
#pragma unroll
            for (int r = 0; r < 4; ++r) {
                p0[r] = exp2f(s0[r] * SCL2 + msk0);
                p1[r] = exp2f(s1[r] * SCL2 + msk1);
                lsum[r] += p0[r] + p1[r];
            }
#pragma unroll
            for (int r = 0; r < 4; ++r) {
                sP[wid][quad * 4 + r][l16]      = (_Float16)p0[r];
                sP[wid][quad * 4 + r][16 + l16] = (_Float16)p1[r];
            }
            half8 aP = *(const half8*)&sP[wid][l16][quad * 8];
            half8 bv0 = *(const half8*)&sVT[l16][sc + quad * 8];
            half8 bv1 = *(const half8*)&sVT[16 + l16][sc + quad * 8];
            half8 bv2 = *(const half8*)&sVT[32 + l16][sc + quad * 8];
            half8 bv3 = *(const half8*)&sVT[48 + l16][sc + quad * 8];
            oacc[0] = __builtin_amdgcn_mfma_f32_16x16x32_f16(aP, bv0, oacc[0], 0, 0, 0);
            oacc[1] = __builtin_amdgcn_mfma_f32_16x16x32_f16(aP, bv1, oacc[1], 0, 0, 0);
            oacc[2] = __builtin_amdgcn_mfma_f32_16x16x32_f16(aP, bv2, oacc[2], 0, 0, 0);
            oacc[3] = __builtin_amdgcn_mfma_f32_16x16x32_f16(aP, bv3, oacc[3], 0, 0, 0);
        }
    }

    float inv[4];
#pragma unroll
    for (int r = 0; r < 4; ++r) {
        float s = lsum[r];
        s += __shfl_xor(s, 1);
        s += __shfl_xor(s, 2);
        s += __shfl_xor(s, 4);
        s += __shfl_xor(s, 8);
        inv[r] = 1.0f / s;
    }
#pragma unroll
    for (int r = 0; r < 4; ++r) {
        size_t rowoff = ((size_t)(b * 3136 + n0 + wid * 16 + quad * 4 + r)) * 640
                        + h * 64 + l16;
#pragma unroll
        for (int tv = 0; tv < 4; ++tv)
            cat[rowoff + tv * 16] = (_Float16)(oacc[tv][r] * inv[r]);
    }
}

// =====================================================================
extern "C" void kernel_launch(void* const* d_in, const int* in_sizes, int n_in,
                              void* d_out, int out_size, void* d_ws, size_t ws_size,
                              hipStream_t stream)
{
    const float* x           = (const float*)d_in[0];
    const float* reduce_w    = (const float*)d_in[3];
    const float* reduce_b    = (const float*)d_in[4];
    const float* reduce_g    = (const float*)d_in[5];
    const float* reduce_beta = (const float*)d_in[6];
    const float* filter_w    = (const float*)d_in[7];
    const float* filter_b    = (const float*)d_in[8];
    const float* filter_g    = (const float*)d_in[9];
    const float* filter_beta = (const float*)d_in[10];
    const float* q_w         = (const float*)d_in[11];
    const float* q_b         = (const float*)d_in[12];
    const float* ln_g        = (const float*)d_in[13];
    const float* ln_b        = (const float*)d_in[14];
    const float* kv_w        = (const float*)d_in[15];
    const float* kv_b        = (const float*)d_in[16];
    const float* kve_w       = (const float*)d_in[17];
    const float* kve_b       = (const float*)d_in[18];
    const float* proj_w      = (const float*)d_in[19];
    const float* proj_b      = (const float*)d_in[20];
    float* out = (float*)d_out;
    _Float16* hws = (_Float16*)d_ws;

    _Float16* x16    = hws + OFF_X16;
    _Float16* q16    = hws + OFF_Q16;
    _Float16* cat16  = hws + OFF_CAT;
    _Float16* r16    = hws + OFF_R16;
    _Float16* pad16  = hws + OFF_PAD;
    _Float16* dwtb16 = hws + OFF_DWTB;
    _Float16* ln16   = hws + OFF_LN16;
    _Float16* kv16   = hws + OFF_KV16;
    _Float16* wT16   = hws + OFF_WT;
    _Float16* kT16   = hws + OFF_KT;
    _Float16* qw16   = hws + OFF_QW;
    _Float16* kvw16  = hws + OFF_KVW;
    _Float16* pw16   = hws + OFF_PW;
    _Float16* rw16   = hws + OFF_RW;
    _Float16* vt16   = hws + OFF_VT;
    float*    partA  = (float*)(hws + OFF_X16);   // conv partials 0,1 (x16 dead)
    float*    partB  = (float*)(hws + OFF_PART);  // conv partials 2,3
    float*    kvepart = (float*)(hws + OFF_X16);  // kve partials 0..3 (after conv_epi)

    // conversions / transposes / padding init
    cvt_f32_f16<<<dim3(6272), dim3(256), 0, stream>>>(x, x16, 1605632);
    cvt_f32_f16<<<dim3(128),  dim3(256), 0, stream>>>(q_w, qw16, 32768);
    cvt_f32_f16<<<dim3(256),  dim3(256), 0, stream>>>(kv_w, kvw16, 65536);
    cvt_f32_f16<<<dim3(160),  dim3(256), 0, stream>>>(proj_w, pw16, 40960);
    cvt_f32_f16<<<dim3(32),   dim3(256), 0, stream>>>(reduce_w, rw16, 8192);
    transpose_filter16<<<dim3(9216), dim3(256), 0, stream>>>(filter_w, wT16);
    transpose_kve16<<<dim3(4096), dim3(256), 0, stream>>>(kve_w, kT16);
    zero_half<<<dim3(1800), dim3(256), 0, stream>>>(pad16, 460800);

    // q = x @ q_w.T + q_b  -> fp16
    gemm16<0, 2><<<dim3(196, 4), dim3(256), 0, stream>>>(
        x16, qw16, q16, 25088, 512, 512, 512, q_b, nullptr, nullptr);

    // r = fp16(relu(bn(conv1x1(x))))  (25088 x 128 NHWC fp16)
    gemm16<0, 1><<<dim3(196, 1), dim3(256), 0, stream>>>(
        x16, rw16, r16, 25088, 512, 512, 128, reduce_b, reduce_g, reduce_beta);

    // DWT -> padded 30x30x512
    dwt_kernel<<<dim3(6272), dim3(128), 0, stream>>>(r16, pad16);

    // 3x3 conv split-K x4 (x16 now dead; partials 0,1 overwrite it)
    conv_splitk<<<dim3(784), dim3(256), 0, stream>>>(pad16, wT16, partA, partB);
    conv_epi<<<dim3(1568), dim3(256), 0, stream>>>(
        partA, partB, dwtb16, filter_b, filter_g, filter_beta);

    // IDWT -> cat cols 512..639
    idwt_kernel<<<dim3(6272), dim3(128), 0, stream>>>(dwtb16, cat16);

    // kve 2x2 s2 conv, split-K x4 -> fp32 partials (reuses partA region)
    gemm16<2, 3><<<dim3(13, 4, 4), dim3(256), 0, stream>>>(
        dwtb16, kT16, kvepart, 1568, 512, 2048, 512, nullptr, nullptr, nullptr);

    // LayerNorm (fused kve partial-sum + bias) -> fp16
    ln_kernel<<<dim3(392), dim3(256), 0, stream>>>(kvepart, ln16, ln_g, ln_b, kve_b);

    // kv = ln @ kv_w.T + kv_b -> fp16 (1568 x 1024)
    gemm16<0, 2><<<dim3(13, 8), dim3(256), 0, stream>>>(
        ln16, kvw16, kv16, 1568, 512, 512, 1024, kv_b, nullptr, nullptr);

    // V^T for attention B-operand
    vt_prep<<<dim3(3584), dim3(256), 0, stream>>>(kv16, vt16);

    // attention -> cat cols 0..511
    attn_mfma<<<dim3(3136), dim3(256), 0, stream>>>(q16, kv16, vt16, cat16);

    // out = cat @ proj_w.T + proj_b  (fp32)
    gemm16<0, 0><<<dim3(196, 4), dim3(256), 0, stream>>>(
        cat16, pw16, out, 25088, 640, 640, 512, proj_b, nullptr, nullptr);
}

// Round 5
// 411.208 us; speedup vs baseline: 1.1953x; 1.0250x over previous
//
#include <hip/hip_runtime.h>
#include <math.h>

// Problem constants: B=8, H=W=56, C=512, N=3136, c4=128, HEADS=8, hd=64, SR=2
// kv sequence length = 14*14 = 196 (padded to 224 for attention)

typedef _Float16 half8 __attribute__((ext_vector_type(8)));
typedef _Float16 half4v __attribute__((ext_vector_type(4)));
typedef float f32x4 __attribute__((ext_vector_type(4)));

// ---------------- workspace layout (offsets in halves; all 16B-aligned) ----
static const size_t OFF_X16  = 0;          // 25088*512 (dead after q/r gemm; reused as conv partials 0,1 then kve partials)
static const size_t OFF_Q16  = 12845056;   // 25088*512
static const size_t OFF_CAT  = 25690112;   // 25088*640
static const size_t OFF_R16  = 41746432;   // 25088*128
static const size_t OFF_PAD  = 44957696;   // 8*900*512  (30x30 zero-padded DWT)
static const size_t OFF_DWTB = 48644096;   // 8*784*512
static const size_t OFF_QRW  = 51855360;   // 640*512 fused q+reduce weights (spare region)
static const size_t OFF_LN16 = 55066624;   // 1568*512
static const size_t OFF_KV16 = 55869440;   // 1568*1024
static const size_t OFF_WT   = 57475072;   // 512*4608
static const size_t OFF_KT   = 59834368;   // 512*2048
static const size_t OFF_QW   = 60882944;   // 512*512 (unused now, kept for layout stability)
static const size_t OFF_KVW  = 61145088;   // 1024*512
static const size_t OFF_PW   = 61669376;   // 512*640
static const size_t OFF_RW   = 61997056;   // 128*512 (unused now)
static const size_t OFF_VT   = 62062592;   // 8*8*64*224 = 917504 (V^T, m-padded)
static const size_t OFF_PART = 62980096;   // conv partials 2,3: 2*3,211,264 floats
// total = 75,825,152 halves = 151.7 MB

#define BN_RSQ 0.9999950000374997f
#define SCL2   0.1803368801111204f   /* 0.125 * log2(e) */
#define PART_STRIDE 3211264          /* 6272*512 floats per conv partial */
#define KVE_STRIDE  802816           /* 1568*512 floats per kve partial */

__device__ __forceinline__ void async_copy16(const _Float16* g, _Float16* l) {
    __builtin_amdgcn_global_load_lds(
        (const __attribute__((address_space(1))) void*)g,
        (__attribute__((address_space(3))) void*)l, 16, 0, 0);
}

// counted-vmcnt barrier (T4): wait until <=N VMEM ops outstanding, then
// barrier — fused in ONE asm so the compiler can neither reorder LDS ops
// between them nor inject its own vmcnt(0) drain. "memory" clobber = IR fence.
#define WAIT4_BARRIER() asm volatile("s_waitcnt vmcnt(4)\n\ts_barrier" ::: "memory")
#define WAIT0_BARRIER() asm volatile("s_waitcnt vmcnt(0)\n\ts_barrier" ::: "memory")

// =====================================================================
// MFMA fp16 NT GEMM: out[m][n] = sum_k A[m][k]*W[n][k] (+ epilogue)
// ALOAD: 0 plain row-major (lda), 2 kve 2x2 stride-2 on 28x28x512 NHWC
//        (for ALOAD=2, lda carries the W row-stride instead)
// EPI:   0 = +bias -> fp32 (nontemporal; final out, never re-read)
//        1 = +bias,BN,ReLU -> fp16
//        2 = +bias -> fp16
//        3 = raw fp32 partial at blockIdx.z*KVE_STRIDE (split-K, nt store)
//        4 = fused q/r: n0<512 -> +bias->fp16 q16; n0>=512 -> BN+ReLU->r16
// 128x128 tile, BK=32, 256 threads (4 waves 2x2), 16x16x32 MFMA.
// 3-buffer LDS, 2-deep prefetch, counted vmcnt(4).
// XCD-chunked blockIdx swizzle (T1) when nwg%8==0.
// =====================================================================
template <int ALOAD, int EPI>
__global__ __launch_bounds__(256) void gemm16(
    const _Float16* __restrict__ A, const _Float16* __restrict__ W,
    void* __restrict__ outp, int M, int K, int lda, int ldc,
    const float* __restrict__ bias, const float* __restrict__ bng,
    const float* __restrict__ bnb, const float* __restrict__ bias2,
    void* __restrict__ outp2)
{
    __shared__ _Float16 sA[3][128 * 32];
    __shared__ _Float16 sB[3][128 * 32];
    const int t = threadIdx.x;
    const int lane = t & 63, wid = t >> 6;

    int bx = blockIdx.x, by = blockIdx.y;
    {
        int nwg = gridDim.x * gridDim.y;
        if ((nwg & 7) == 0) {            // bijective XCD-chunked remap
            int orig = by * gridDim.x + bx;
            int cs = nwg >> 3;
            int wg = (orig & 7) * cs + (orig >> 3);
            by = wg % gridDim.y;
            bx = wg / gridDim.y;
        }
    }
    const int m0 = bx * 128, n0 = by * 128;
    const int kbase = blockIdx.z * K;        // split-K group (z=0 normally)

    const int sr = wid * 16 + (lane >> 2);   // staging tile row (instr0)
    const int sc = (lane & 3) * 8;           // staging col offset (halves)
    const int stA0 = wid * 512;              // dest offsets within a buffer
    const int stA1 = 2048 + wid * 512;

    const _Float16 *aP0, *aP1;
    if constexpr (ALOAD == 0) {
        int r0 = m0 + sr;      if (r0 > M - 1) r0 = M - 1;
        int r1 = m0 + 64 + sr; if (r1 > M - 1) r1 = M - 1;
        aP0 = A + (size_t)r0 * lda + sc;
        aP1 = A + (size_t)r1 * lda + sc;
    } else {
        int m_ = m0 + sr; if (m_ > M - 1) m_ = M - 1;
        int b_ = m_ / 196, rem = m_ - b_ * 196, i_ = rem / 14, j_ = rem - i_ * 14;
        aP0 = A + ((size_t)(b_ * 784 + 2 * i_ * 28 + 2 * j_)) * 512 + sc;
        m_ = m0 + 64 + sr; if (m_ > M - 1) m_ = M - 1;
        b_ = m_ / 196; rem = m_ - b_ * 196; i_ = rem / 14; j_ = rem - i_ * 14;
        aP1 = A + ((size_t)(b_ * 784 + 2 * i_ * 28 + 2 * j_)) * 512 + sc;
    }
    const int ldw = (ALOAD == 2) ? lda : K;  // W row stride
    const _Float16* bP0 = W + (size_t)(n0 + sr) * ldw + sc;
    const _Float16* bP1 = W + (size_t)(n0 + 64 + sr) * ldw + sc;

    const int mw = wid & 1, nw = wid >> 1;
    const int pAoff = (mw * 64 + (lane & 15)) * 32 + (lane >> 4) * 8;
    const int pBoff = (nw * 64 + (lane & 15)) * 32 + (lane >> 4) * 8;

    f32x4 acc[4][4];
#pragma unroll
    for (int i = 0; i < 4; ++i)
#pragma unroll
        for (int j = 0; j < 4; ++j) acc[i][j] = (f32x4)(0.0f);

    auto aoff_of = [&](int k) -> int {
        if constexpr (ALOAD == 0) {
            return k;
        } else {
            int sub = k >> 9; int ky = sub >> 1, kx = sub & 1;
            return (ky * 28 + kx) * 512 + (k & 511);
        }
    };
    auto stage = [&](int ti, int buf) {
        int k = kbase + ti * 32;
        int aOff = aoff_of(k);
        async_copy16(aP0 + aOff, &sA[buf][stA0]);
        async_copy16(aP1 + aOff, &sA[buf][stA1]);
        async_copy16(bP0 + k, &sB[buf][stA0]);
        async_copy16(bP1 + k, &sB[buf][stA1]);
    };

    const int nt = K >> 5;
    // prologue: 2-deep prefetch
    stage(0, 0);
    if (nt > 1) { stage(1, 1); WAIT4_BARRIER(); }
    else        { WAIT0_BARRIER(); }

    int cur = 0;
    for (int i = 0; i < nt; ++i) {
        const _Float16* pA = &sA[cur][0] + pAoff;
        const _Float16* pB = &sB[cur][0] + pBoff;
        half8 aF[4], bF[4];
#pragma unroll
        for (int u = 0; u < 4; ++u) aF[u] = *(const half8*)(pA + u * 512);
#pragma unroll
        for (int u = 0; u < 4; ++u) bF[u] = *(const half8*)(pB + u * 512);

        const bool st = (i + 2 < nt);
        if (st) {
            int nb = cur + 2; if (nb >= 3) nb -= 3;
            stage(i + 2, nb);
        }
#pragma unroll
        for (int u = 0; u < 4; ++u)
#pragma unroll
            for (int j = 0; j < 4; ++j)
                acc[u][j] = __builtin_amdgcn_mfma_f32_16x16x32_f16(
                    aF[u], bF[j], acc[u][j], 0, 0, 0);

        if (i + 1 < nt) {
            if (st) WAIT4_BARRIER();   // tile i+1 done, tile i+2 stays in flight
            else    WAIT0_BARRIER();   // last tile: drain
        }
        ++cur; if (cur == 3) cur = 0;
    }

    // epilogue: C/D layout col=lane&15, row=(lane>>4)*4+reg
    const int orow = m0 + mw * 64 + (lane >> 4) * 4;
    const int ocol = n0 + nw * 64 + (lane & 15);
#pragma unroll
    for (int j = 0; j < 4; ++j) {
        int col = ocol + j * 16;
        float bv = 0.0f, g = 0.0f, b2 = 0.0f;
        if constexpr (EPI == 4) {
            if (n0 >= 512) {           // r path (block-uniform branch)
                bv = bias2[col - 512];
                g = bng[col - 512] * BN_RSQ;
                b2 = bnb[col - 512];
            } else {
                bv = bias[col];
            }
        } else if constexpr (EPI != 3) {
            bv = bias[col];
        }
        if constexpr (EPI == 1) { g = bng[col] * BN_RSQ; b2 = bnb[col]; }
#pragma unroll
        for (int i = 0; i < 4; ++i) {
#pragma unroll
            for (int r = 0; r < 4; ++r) {
                int row = orow + i * 16 + r;
                if (row >= M) continue;
                float v = acc[i][j][r] + bv;
                if constexpr (EPI == 1) v = fmaxf(v * g + b2, 0.0f);
                if constexpr (EPI == 0) {
                    __builtin_nontemporal_store(
                        v, (float*)outp + (size_t)row * ldc + col);
                } else if constexpr (EPI == 3) {
                    __builtin_nontemporal_store(
                        v, (float*)outp + (size_t)blockIdx.z * KVE_STRIDE
                           + (size_t)row * ldc + col);
                } else if constexpr (EPI == 4) {
                    if (n0 >= 512) {
                        v = fmaxf(v * g + b2, 0.0f);
                        ((_Float16*)outp2)[(size_t)row * 128 + (col - 512)] =
                            (_Float16)v;
                    } else {
                        ((_Float16*)outp)[(size_t)row * ldc + col] = (_Float16)v;
                    }
                } else {
                    ((_Float16*)outp)[(size_t)row * ldc + col] = (_Float16)v;
                }
            }
        }
    }
}

// =====================================================================
// conv3x3 split-K partial GEMM: 784 blocks 1-D; XCD-chunked swizzle maps
// each XCD to contiguous (by,bz) chunks (shared B panel + A slice).
// K-group bz covers k in [bz*1152, (bz+1)*1152). Writes fp32 partial with
// NON-TEMPORAL stores: the 51 MB write-once partial stream must not cycle
// L2 (it was evicting the A/B panels -> every reuse load missed to HBM).
// A = padded 30x30x512 NHWC fp16; W = wT[n][(ky*3+kx)*512+ci].
// =====================================================================
__global__ __launch_bounds__(256) void conv_splitk(
    const _Float16* __restrict__ A, const _Float16* __restrict__ W,
    float* __restrict__ partA, float* __restrict__ partB)
{
    __shared__ _Float16 sA[3][128 * 32];
    __shared__ _Float16 sB[3][128 * 32];
    const int t = threadIdx.x;
    const int lane = t & 63, wid = t >> 6;

    // bijective XCD-chunked remap: 784 = 8 * 98; chunk = (by,bz) pair row
    int orig = blockIdx.x;
    int wg = (orig & 7) * 98 + (orig >> 3);
    int bx = wg % 49;  int c = wg / 49;    // c in 0..15
    int by = c & 3,    bz = c >> 2;

    const int m0 = bx * 128, n0 = by * 128;
    const int kbase = bz * 1152;

    const int sr = wid * 16 + (lane >> 2);
    const int sc = (lane & 3) * 8;
    const int stA0 = wid * 512;
    const int stA1 = 2048 + wid * 512;

    int m_ = m0 + sr;
    int b_ = m_ / 784, rem = m_ - b_ * 784, y_ = rem / 28, x_ = rem - y_ * 28;
    const _Float16* aP0 = A + ((size_t)(b_ * 900 + (y_ + 1) * 30 + (x_ + 1))) * 512 + sc;
    m_ = m0 + 64 + sr;
    b_ = m_ / 784; rem = m_ - b_ * 784; y_ = rem / 28; x_ = rem - y_ * 28;
    const _Float16* aP1 = A + ((size_t)(b_ * 900 + (y_ + 1) * 30 + (x_ + 1))) * 512 + sc;
    const _Float16* bP0 = W + (size_t)(n0 + sr) * 4608 + sc;
    const _Float16* bP1 = W + (size_t)(n0 + 64 + sr) * 4608 + sc;

    const int mw = wid & 1, nw = wid >> 1;
    const int pAoff = (mw * 64 + (lane & 15)) * 32 + (lane >> 4) * 8;
    const int pBoff = (nw * 64 + (lane & 15)) * 32 + (lane >> 4) * 8;

    f32x4 acc[4][4];
#pragma unroll
    for (int i = 0; i < 4; ++i)
#pragma unroll
        for (int j = 0; j < 4; ++j) acc[i][j] = (f32x4)(0.0f);

    auto aoff_of = [&](int k) -> int {
        int sub = k >> 9; int s3 = sub / 3;
        int dy = s3 - 1, dx = sub - s3 * 3 - 1;
        return (dy * 30 + dx) * 512 + (k & 511);
    };
    auto stage = [&](int ti, int buf) {
        int k = kbase + ti * 32;
        int aOff = aoff_of(k);
        async_copy16(aP0 + aOff, &sA[buf][stA0]);
        async_copy16(aP1 + aOff, &sA[buf][stA1]);
        async_copy16(bP0 + k, &sB[buf][stA0]);
        async_copy16(bP1 + k, &sB[buf][stA1]);
    };

    const int nt = 36;   // 1152/32
    stage(0, 0);
    stage(1, 1);
    WAIT4_BARRIER();

    int cur = 0;
    for (int i = 0; i < nt; ++i) {
        const _Float16* pA = &sA[cur][0] + pAoff;
        const _Float16* pB = &sB[cur][0] + pBoff;
        half8 aF[4], bF[4];
#pragma unroll
        for (int u = 0; u < 4; ++u) aF[u] = *(const half8*)(pA + u * 512);
#pragma unroll
        for (int u = 0; u < 4; ++u) bF[u] = *(const half8*)(pB + u * 512);

        const bool st = (i + 2 < nt);
        if (st) {
            int nb = cur + 2; if (nb >= 3) nb -= 3;
            stage(i + 2, nb);
        }
#pragma unroll
        for (int u = 0; u < 4; ++u)
#pragma unroll
            for (int j = 0; j < 4; ++j)
                acc[u][j] = __builtin_amdgcn_mfma_f32_16x16x32_f16(
                    aF[u], bF[j], acc[u][j], 0, 0, 0);

        if (i + 1 < nt) {
            if (st) WAIT4_BARRIER();
            else    WAIT0_BARRIER();
        }
        ++cur; if (cur == 3) cur = 0;
    }

    float* dst = (bz < 2) ? (partA + (size_t)bz * PART_STRIDE)
                          : (partB + (size_t)(bz - 2) * PART_STRIDE);
    const int orow = m0 + mw * 64 + (lane >> 4) * 4;
    const int ocol = n0 + nw * 64 + (lane & 15);
#pragma unroll
    for (int j = 0; j < 4; ++j) {
#pragma unroll
        for (int i = 0; i < 4; ++i)
#pragma unroll
            for (int r = 0; r < 4; ++r)
                __builtin_nontemporal_store(
                    acc[i][j][r],
                    &dst[(size_t)(orow + i * 16 + r) * 512 + ocol + j * 16]);
    }
}

// conv epilogue: dwtb16 = fp16(relu((p0+p1+p2+p3 + bias) * g*BN_RSQ + beta))
// nontemporal partial loads (read-once 51 MB stream).
__global__ __launch_bounds__(256) void conv_epi(
    const float* __restrict__ pA, const float* __restrict__ pB,
    _Float16* __restrict__ o, const float* __restrict__ bias,
    const float* __restrict__ bng, const float* __restrict__ bnb)
{
    int i = blockIdx.x * 256 + threadIdx.x;      // 401,408 groups of 8
    size_t base = (size_t)i * 8;
    int c = (int)(base & 511);
    half8 hv;
#pragma unroll
    for (int u = 0; u < 8; u += 4) {
        f32x4 a0 = __builtin_nontemporal_load((const f32x4*)(pA + base + u));
        f32x4 a1 = __builtin_nontemporal_load((const f32x4*)(pA + PART_STRIDE + base + u));
        f32x4 a2 = __builtin_nontemporal_load((const f32x4*)(pB + base + u));
        f32x4 a3 = __builtin_nontemporal_load((const f32x4*)(pB + PART_STRIDE + base + u));
#pragma unroll
        for (int v = 0; v < 4; ++v) {
            int cc = c + u + v;
            float s = (a0[v] + a1[v]) + (a2[v] + a3[v]);
            float val = (s + bias[cc]) * (bng[cc] * BN_RSQ) + bnb[cc];
            hv[u + v] = (_Float16)fmaxf(val, 0.0f);
        }
    }
    *(half8*)(o + base) = hv;
}

// =====================================================================
// small utility kernels
// =====================================================================
__global__ __launch_bounds__(256) void cvt_f32_f16(
    const float* __restrict__ s, _Float16* __restrict__ d, int n8)
{
    int i = blockIdx.x * 256 + threadIdx.x;
    if (i >= n8) return;
    const float4* sp = (const float4*)(s + (size_t)i * 8);
    float4 a = sp[0], b = sp[1];
    half8 h;
    h[0] = (_Float16)a.x; h[1] = (_Float16)a.y; h[2] = (_Float16)a.z; h[3] = (_Float16)a.w;
    h[4] = (_Float16)b.x; h[5] = (_Float16)b.y; h[6] = (_Float16)b.z; h[7] = (_Float16)b.w;
    *(half8*)(d + (size_t)i * 8) = h;
}

__global__ __launch_bounds__(256) void zero_half(_Float16* __restrict__ p, int n8)
{
    int i = blockIdx.x * 256 + threadIdx.x;
    if (i < n8) *(float4*)(p + (size_t)i * 8) = make_float4(0.f, 0.f, 0.f, 0.f);
}

__global__ __launch_bounds__(256) void transpose_filter16(
    const float* __restrict__ fw, _Float16* __restrict__ wT)
{   // wT[n][(ky*3+kx)*512 + ci] = fw[n][ci][ky][kx]; 512*4608
    int idx = blockIdx.x * 256 + threadIdx.x;
    int n = idx / 4608; int r = idx - n * 4608;
    int sub = r >> 9; int ci = r & 511;
    wT[idx] = (_Float16)fw[(size_t)n * 4608 + ci * 9 + sub];
}

__global__ __launch_bounds__(256) void transpose_kve16(
    const float* __restrict__ kw, _Float16* __restrict__ kT)
{   // kT[n][(ky*2+kx)*512 + ci] = kw[n][ci][ky][kx]; 512*2048
    int idx = blockIdx.x * 256 + threadIdx.x;
    int n = idx >> 11; int r = idx & 2047;
    int sub = r >> 9; int ci = r & 511;
    kT[idx] = (_Float16)kw[((size_t)n << 11) + (ci << 2) + sub];
}

// V^T prep: vt[((b*8+h)*64+d)*224 + m] = kv[b][m][512 + h*64 + d], 0 for m>=196
__global__ __launch_bounds__(256) void vt_prep(
    const _Float16* __restrict__ kv, _Float16* __restrict__ vt)
{
    int idx = blockIdx.x * 256 + threadIdx.x;   // 917504 total
    int m = idx % 224;
    int rest = idx / 224;
    int d = rest & 63;
    int bh = rest >> 6;
    int b = bh >> 3, h = bh & 7;
    _Float16 v = (_Float16)0.0f;
    if (m < 196)
        v = kv[((size_t)(b * 196 + m)) * 1024 + 512 + h * 64 + d];
    vt[idx] = v;
}

// =====================================================================
// Haar DWT: rbuf16 (B,56,56,128 NHWC fp16) -> padded (B,30,30,512 NHWC fp16)
// =====================================================================
__global__ __launch_bounds__(128) void dwt_kernel(
    const _Float16* __restrict__ r, _Float16* __restrict__ pad)
{
    int bid = blockIdx.x;            // b*784 + i*28 + j
    int b = bid / 784; int rem = bid - b * 784;
    int i = rem / 28;  int j = rem - i * 28;
    int c = threadIdx.x;
    int y = 2 * i, x = 2 * j;
    size_t base = (size_t)b * 3136;
    _Float16 f1 = r[(base + (size_t)y * 56 + x) * 128 + c];
    _Float16 f2 = r[(base + (size_t)(y + 1) * 56 + x) * 128 + c];
    _Float16 f3 = r[(base + (size_t)y * 56 + (x + 1)) * 128 + c];
    _Float16 f4 = r[(base + (size_t)(y + 1) * 56 + (x + 1)) * 128 + c];
    _Float16 h = (_Float16)0.5f;
    _Float16 x1 = f1 * h, x2 = f2 * h, x3 = f3 * h, x4 = f4 * h;
    _Float16 ll = ((x1 + x2) + x3) + x4;
    _Float16 hl = (((-x1) - x2) + x3) + x4;
    _Float16 lh = (((-x1) + x2) - x3) + x4;
    _Float16 hh = ((x1 - x2) - x3) + x4;
    size_t ob = ((size_t)b * 900 + (size_t)(i + 1) * 30 + (j + 1)) * 512;
    pad[ob + c]       = ll;
    pad[ob + 128 + c] = hl;
    pad[ob + 256 + c] = lh;
    pad[ob + 384 + c] = hh;
}

// =====================================================================
// Haar IDWT: dwt_b16 (B,28,28,512 NHWC fp16) -> cat16 cols 512..639
// nt stores: cat is consumed much later (proj); don't pollute L2.
// =====================================================================
__global__ __launch_bounds__(128) void idwt_kernel(
    const _Float16* __restrict__ d, _Float16* __restrict__ cat)
{
    int bid = blockIdx.x;
    int b = bid / 784; int rem = bid - b * 784;
    int i = rem / 28;  int j = rem - i * 28;
    int c = threadIdx.x;
    size_t ib = ((size_t)b * 784 + (size_t)i * 28 + j) * 512;
    _Float16 ll = d[ib + c];
    _Float16 hl = d[ib + 128 + c];
    _Float16 lh = d[ib + 256 + c];
    _Float16 hh = d[ib + 384 + c];
    _Float16 h = (_Float16)0.5f;
    _Float16 p1 = (((ll - hl) - lh) + hh) * h;
    _Float16 p2 = (((ll - hl) + lh) - hh) * h;
    _Float16 p3 = (((ll + hl) - lh) - hh) * h;
    _Float16 p4 = (((ll + hl) + lh) + hh) * h;
    int y = 2 * i, x = 2 * j;
    size_t rb = (size_t)b * 3136;
    __builtin_nontemporal_store(p1, &cat[(rb + (size_t)y * 56 + x) * 640 + 512 + c]);
    __builtin_nontemporal_store(p3, &cat[(rb + (size_t)y * 56 + x + 1) * 640 + 512 + c]);
    __builtin_nontemporal_store(p2, &cat[(rb + (size_t)(y + 1) * 56 + x) * 640 + 512 + c]);
    __builtin_nontemporal_store(p4, &cat[(rb + (size_t)(y + 1) * 56 + x + 1) * 640 + 512 + c]);
}

// =====================================================================
// LayerNorm over C=512, fused kve split-K reduction:
// in = sum_z part[z*KVE_STRIDE + row*512 + c] + kve_b[c]; fp16 out.
// One wave per row.
// =====================================================================
__global__ __launch_bounds__(256) void ln_kernel(
    const float* __restrict__ part, _Float16* __restrict__ o,
    const float* __restrict__ g, const float* __restrict__ bta,
    const float* __restrict__ kvb)
{
    int wave = threadIdx.x >> 6;
    int lane = threadIdx.x & 63;
    int row = blockIdx.x * 4 + wave;            // 392*4 = 1568
    int c = lane * 8;
    const float* rp = part + (size_t)row * 512 + c;
    float v[8];
#pragma unroll
    for (int i = 0; i < 8; i += 4) {
        float4 a0 = *(const float4*)(rp + i);
        float4 a1 = *(const float4*)(rp + KVE_STRIDE + i);
        float4 a2 = *(const float4*)(rp + 2 * KVE_STRIDE + i);
        float4 a3 = *(const float4*)(rp + 3 * KVE_STRIDE + i);
        v[i + 0] = (a0.x + a1.x) + (a2.x + a3.x) + kvb[c + i + 0];
        v[i + 1] = (a0.y + a1.y) + (a2.y + a3.y) + kvb[c + i + 1];
        v[i + 2] = (a0.z + a1.z) + (a2.z + a3.z) + kvb[c + i + 2];
        v[i + 3] = (a0.w + a1.w) + (a2.w + a3.w) + kvb[c + i + 3];
    }
    float s = ((v[0] + v[1]) + (v[2] + v[3])) + ((v[4] + v[5]) + (v[6] + v[7]));
#pragma unroll
    for (int off = 32; off; off >>= 1) s += __shfl_xor(s, off);
    float mu = s * (1.0f / 512.0f);
    float sq = 0.0f;
#pragma unroll
    for (int i = 0; i < 8; ++i) { v[i] -= mu; sq += v[i] * v[i]; }
#pragma unroll
    for (int off = 32; off; off >>= 1) sq += __shfl_xor(sq, off);
    float inv = 1.0f / sqrtf(sq * (1.0f / 512.0f) + 1e-5f);
    half8 hv;
#pragma unroll
    for (int i = 0; i < 8; ++i) hv[i] = (_Float16)(v[i] * inv * g[c + i] + bta[c + i]);
    *(half8*)(o + (size_t)row * 512 + c) = hv;
}

// =====================================================================
// MFMA flash attention. Block = (b, h, 64 q-rows); 4 waves x 16 q-rows.
// Unnormalized softmax (scores tiny), one reduction at the end.
// cat writes are nontemporal (consumed later by proj; protects K/V in L2).
// =====================================================================
__global__ __launch_bounds__(256) void attn_mfma(
    const _Float16* __restrict__ q, const _Float16* __restrict__ kv,
    const _Float16* __restrict__ vt, _Float16* __restrict__ cat)
{
    __shared__ _Float16 sK[64][72];    // K[m][d]
    __shared__ _Float16 sVT[64][72];   // V^T[d][m-chunk]
    __shared__ _Float16 sP[4][16][40]; // per-wave P round-trip
    int bid = blockIdx.x;
    int qt = bid % 49;
    int h  = (bid / 49) & 7;
    int b  = bid / 392;
    int n0 = qt * 64;
    int t = threadIdx.x, lane = t & 63, wid = t >> 6;
    int quad = lane >> 4, l16 = lane & 15;

    const _Float16* qp = q + ((size_t)(b * 3136 + n0 + wid * 16 + l16)) * 512
                           + h * 64 + quad * 8;
    half8 aQ0 = *(const half8*)qp;
    half8 aQ1 = *(const half8*)(qp + 32);

    f32x4 oacc[4];
#pragma unroll
    for (int i = 0; i < 4; ++i) oacc[i] = (f32x4)(0.0f);
    float lsum[4] = {0.f, 0.f, 0.f, 0.f};

    const _Float16* vtb = vt + ((size_t)((b * 8 + h) * 64)) * 224;

    for (int c0 = 0; c0 < 224; c0 += 64) {
        __syncthreads();
#pragma unroll
        for (int it = 0; it < 2; ++it) {
            int slot = t + 256 * it;
            int row = slot >> 3, c8 = (slot & 7) * 8;
            int m = c0 + row; if (m > 195) m = 195;
            *(half8*)&sK[row][c8] =
                *(const half8*)(kv + ((size_t)(b * 196 + m)) * 1024 + h * 64 + c8);
        }
#pragma unroll
        for (int it = 0; it < 2; ++it) {
            int slot = t + 256 * it;
            int row = slot >> 3, c8 = (slot & 7) * 8;
            *(half8*)&sVT[row][c8] =
                *(const half8*)(vtb + (size_t)row * 224 + c0 + c8);
        }
        __syncthreads();

#pragma unroll
        for (int sc = 0; sc < 64; sc += 32) {
            half8 bk00 = *(const half8*)&sK[sc + l16][quad * 8];
            half8 bk01 = *(const half8*)&sK[sc + l16][32 + quad * 8];
            half8 bk10 = *(const half8*)&sK[sc + 16 + l16][quad * 8];
            half8 bk11 = *(const half8*)&sK[sc + 16 + l16][32 + quad * 8];
            f32x4 s0 = (f32x4)(0.0f), s1 = (f32x4)(0.0f);
            s0 = __builtin_amdgcn_mfma_f32_16x16x32_f16(aQ0, bk00, s0, 0, 0, 0);
            s0 = __builtin_amdgcn_mfma_f32_16x16x32_f16(aQ1, bk01, s0, 0, 0, 0);
            s1 = __builtin_amdgcn_mfma_f32_16x16x32_f16(aQ0, bk10, s1, 0, 0, 0);
            s1 = __builtin_amdgcn_mfma_f32_16x16x32_f16(aQ1, bk11, s1, 0, 0, 0);

            int col0 = c0 + sc + l16;
            float msk0 = (col0 < 196) ? 0.0f : -INFINITY;
            float msk1 = (col0 + 16 < 196) ? 0.0f : -INFINITY;
            float p0[4], p1[4];
#pragma unroll
            for (int r = 0; r < 4; ++r) {
                p0[r] = exp2f(s0[r] * SCL2 + msk0);
                p1[r] = exp2f(s1[r] * SCL2 + msk1);
                lsum[r] += p0[r] + p1[r];
            }
#pragma unroll
            for (int r = 0; r < 4; ++r) {
                sP[wid][quad * 4 + r][l16]      = (_Float16)p0[r];
                sP[wid][quad * 4 + r][16 + l16] = (_Float16)p1[r];
            }
            half8 aP = *(const half8*)&sP[wid][l16][quad * 8];
            half8 bv0 = *(const half8*)&sVT[l16][sc + quad * 8];
            half8 bv1 = *(const half8*)&sVT[16 + l16][sc + quad * 8];
            half8 bv2 = *(const half8*)&sVT[32 + l16][sc + quad * 8];
            half8 bv3 = *(const half8*)&sVT[48 + l16][sc + quad * 8];
            oacc[0] = __builtin_amdgcn_mfma_f32_16x16x32_f16(aP, bv0, oacc[0], 0, 0, 0);
            oacc[1] = __builtin_amdgcn_mfma_f32_16x16x32_f16(aP, bv1, oacc[1], 0, 0, 0);
            oacc[2] = __builtin_amdgcn_mfma_f32_16x16x32_f16(aP, bv2, oacc[2], 0, 0, 0);
            oacc[3] = __builtin_amdgcn_mfma_f32_16x16x32_f16(aP, bv3, oacc[3], 0, 0, 0);
        }
    }

    float inv[4];
#pragma unroll
    for (int r = 0; r < 4; ++r) {
        float s = lsum[r];
        s += __shfl_xor(s, 1);
        s += __shfl_xor(s, 2);
        s += __shfl_xor(s, 4);
        s += __shfl_xor(s, 8);
        inv[r] = 1.0f / s;
    }
#pragma unroll
    for (int r = 0; r < 4; ++r) {
        size_t rowoff = ((size_t)(b * 3136 + n0 + wid * 16 + quad * 4 + r)) * 640
                        + h * 64 + l16;
#pragma unroll
        for (int tv = 0; tv < 4; ++tv)
            __builtin_nontemporal_store(
                (_Float16)(oacc[tv][r] * inv[r]), &cat[rowoff + tv * 16]);
    }
}

// =====================================================================
extern "C" void kernel_launch(void* const* d_in, const int* in_sizes, int n_in,
                              void* d_out, int out_size, void* d_ws, size_t ws_size,
                              hipStream_t stream)
{
    const float* x           = (const float*)d_in[0];
    const float* reduce_w    = (const float*)d_in[3];
    const float* reduce_b    = (const float*)d_in[4];
    const float* reduce_g    = (const float*)d_in[5];
    const float* reduce_beta = (const float*)d_in[6];
    const float* filter_w    = (const float*)d_in[7];
    const float* filter_b    = (const float*)d_in[8];
    const float* filter_g    = (const float*)d_in[9];
    const float* filter_beta = (const float*)d_in[10];
    const float* q_w         = (const float*)d_in[11];
    const float* q_b         = (const float*)d_in[12];
    const float* ln_g        = (const float*)d_in[13];
    const float* ln_b        = (const float*)d_in[14];
    const float* kv_w        = (const float*)d_in[15];
    const float* kv_b        = (const float*)d_in[16];
    const float* kve_w       = (const float*)d_in[17];
    const float* kve_b       = (const float*)d_in[18];
    const float* proj_w      = (const float*)d_in[19];
    const float* proj_b      = (const float*)d_in[20];
    float* out = (float*)d_out;
    _Float16* hws = (_Float16*)d_ws;

    _Float16* x16    = hws + OFF_X16;
    _Float16* q16    = hws + OFF_Q16;
    _Float16* cat16  = hws + OFF_CAT;
    _Float16* r16    = hws + OFF_R16;
    _Float16* pad16  = hws + OFF_PAD;
    _Float16* dwtb16 = hws + OFF_DWTB;
    _Float16* qrw16  = hws + OFF_QRW;
    _Float16* ln16   = hws + OFF_LN16;
    _Float16* kv16   = hws + OFF_KV16;
    _Float16* wT16   = hws + OFF_WT;
    _Float16* kT16   = hws + OFF_KT;
    _Float16* kvw16  = hws + OFF_KVW;
    _Float16* pw16   = hws + OFF_PW;
    _Float16* vt16   = hws + OFF_VT;
    float*    partA  = (float*)(hws + OFF_X16);   // conv partials 0,1 (x16 dead)
    float*    partB  = (float*)(hws + OFF_PART);  // conv partials 2,3
    float*    kvepart = (float*)(hws + OFF_X16);  // kve partials 0..3 (after conv_epi)

    // conversions / transposes / padding init
    cvt_f32_f16<<<dim3(6272), dim3(256), 0, stream>>>(x, x16, 1605632);
    cvt_f32_f16<<<dim3(128),  dim3(256), 0, stream>>>(q_w, qrw16, 32768);
    cvt_f32_f16<<<dim3(32),   dim3(256), 0, stream>>>(reduce_w, qrw16 + 262144, 8192);
    cvt_f32_f16<<<dim3(256),  dim3(256), 0, stream>>>(kv_w, kvw16, 65536);
    cvt_f32_f16<<<dim3(160),  dim3(256), 0, stream>>>(proj_w, pw16, 40960);
    transpose_filter16<<<dim3(9216), dim3(256), 0, stream>>>(filter_w, wT16);
    transpose_kve16<<<dim3(4096), dim3(256), 0, stream>>>(kve_w, kT16);
    zero_half<<<dim3(1800), dim3(256), 0, stream>>>(pad16, 460800);

    // fused q + r gemm: cols 0..511 -> q16 (+q_b), cols 512..639 -> BN+ReLU r16
    gemm16<0, 4><<<dim3(196, 5), dim3(256), 0, stream>>>(
        x16, qrw16, q16, 25088, 512, 512, 512, q_b, reduce_g, reduce_beta,
        reduce_b, r16);

    // DWT -> padded 30x30x512
    dwt_kernel<<<dim3(6272), dim3(128), 0, stream>>>(r16, pad16);

    // 3x3 conv split-K x4 (x16 now dead; partials 0,1 overwrite it)
    conv_splitk<<<dim3(784), dim3(256), 0, stream>>>(pad16, wT16, partA, partB);
    conv_epi<<<dim3(1568), dim3(256), 0, stream>>>(
        partA, partB, dwtb16, filter_b, filter_g, filter_beta);

    // IDWT -> cat cols 512..639
    idwt_kernel<<<dim3(6272), dim3(128), 0, stream>>>(dwtb16, cat16);

    // kve 2x2 s2 conv, split-K x4 -> fp32 partials (reuses partA region)
    gemm16<2, 3><<<dim3(13, 4, 4), dim3(256), 0, stream>>>(
        dwtb16, kT16, kvepart, 1568, 512, 2048, 512, nullptr, nullptr, nullptr,
        nullptr, nullptr);

    // LayerNorm (fused kve partial-sum + bias) -> fp16
    ln_kernel<<<dim3(392), dim3(256), 0, stream>>>(kvepart, ln16, ln_g, ln_b, kve_b);

    // kv = ln @ kv_w.T + kv_b -> fp16 (1568 x 1024)
    gemm16<0, 2><<<dim3(13, 8), dim3(256), 0, stream>>>(
        ln16, kvw16, kv16, 1568, 512, 512, 1024, kv_b, nullptr, nullptr,
        nullptr, nullptr);

    // V^T for attention B-operand
    vt_prep<<<dim3(3584), dim3(256), 0, stream>>>(kv16, vt16);

    // attention -> cat cols 0..511
    attn_mfma<<<dim3(3136), dim3(256), 0, stream>>>(q16, kv16, vt16, cat16);

    // out = cat @ proj_w.T + proj_b  (fp32, nt store)
    gemm16<0, 0><<<dim3(196, 4), dim3(256), 0, stream>>>(
        cat16, pw16, out, 25088, 640, 640, 512, proj_b, nullptr, nullptr,
        nullptr, nullptr);
}

// Round 6
// 398.994 us; speedup vs baseline: 1.2319x; 1.0306x over previous
//
#include <hip/hip_runtime.h>
#include <math.h>

// Problem constants: B=8, H=W=56, C=512, N=3136, c4=128, HEADS=8, hd=64, SR=2
// kv sequence length = 14*14 = 196 (padded to 224 for attention)

typedef _Float16 half8 __attribute__((ext_vector_type(8)));
typedef float f32x4 __attribute__((ext_vector_type(4)));

// ---------------- workspace layout (offsets in halves; all 16B-aligned) ----
static const size_t OFF_X16  = 0;          // 25088*512 (dead after q/r gemm; reused as conv partials 0,1 then kve partials)
static const size_t OFF_Q16  = 12845056;   // 25088*512
static const size_t OFF_CAT  = 25690112;   // 25088*640
static const size_t OFF_R16  = 41746432;   // 25088*128
static const size_t OFF_PAD  = 44957696;   // 8*900*512  (30x30 zero-padded DWT)
static const size_t OFF_DWTB = 48644096;   // 8*784*512
static const size_t OFF_QRW  = 51855360;   // 640*512 fused q+reduce weights
static const size_t OFF_LN16 = 55066624;   // 1568*512
static const size_t OFF_KV16 = 55869440;   // 1568*1024
static const size_t OFF_WT   = 57475072;   // 512*4608
static const size_t OFF_KT   = 59834368;   // 512*2048
static const size_t OFF_KVW  = 61145088;   // 1024*512
static const size_t OFF_PW   = 61669376;   // 512*640
static const size_t OFF_VT   = 62062592;   // 8*8*64*224 = 917504 (V^T, m-padded)
static const size_t OFF_PART = 62980096;   // conv partials 2,3: 2*3,211,264 floats
// total = 75,825,152 halves = 151.7 MB

#define BN_RSQ 0.9999950000374997f
#define SCL2   0.1803368801111204f   /* 0.125 * log2(e) */
#define PART_STRIDE 3211264          /* 6272*512 floats per conv partial */
#define KVE_STRIDE  802816           /* 1568*512 floats per kve partial */

__device__ __forceinline__ void async_copy16(const _Float16* g, _Float16* l) {
    __builtin_amdgcn_global_load_lds(
        (const __attribute__((address_space(1))) void*)g,
        (__attribute__((address_space(3))) void*)l, 16, 0, 0);
}

// counted-vmcnt barrier (T4) fused in one asm (compiler can't inject vmcnt(0))
#define WAIT4_BARRIER() asm volatile("s_waitcnt vmcnt(4)\n\ts_barrier" ::: "memory")
#define WAIT0_BARRIER() asm volatile("s_waitcnt vmcnt(0)\n\ts_barrier" ::: "memory")

// =====================================================================
// MFMA fp16 NT GEMM: out[m][n] = sum_k A[m][k]*W[n][k] (+ epilogue)
// ALOAD: 0 plain row-major (lda), 2 kve 2x2 stride-2 on 28x28x512 NHWC
//        (for ALOAD=2, lda carries the W row-stride instead)
// EPI:   0 = +bias -> fp32 nontemporal (final out)
//        2 = +bias -> fp16
//        3 = raw fp32 partial at blockIdx.z*KVE_STRIDE (split-K)
//        4 = fused q/r: n0<512 -> +bias->fp16 q16; n0>=512 -> BN+ReLU->r16
//        5 = fused kv/vt: n0<512 -> +bias->fp16 kv16; n0>=512 -> V^T scatter
// 128x128 tile, BK=32, 256 threads (4 waves 2x2), 16x16x32 MFMA.
// 3-buffer LDS, 2-deep prefetch, counted vmcnt(4).
// XCD-chunked blockIdx swizzle (T1) when nwg%8==0.
// =====================================================================
template <int ALOAD, int EPI>
__global__ __launch_bounds__(256) void gemm16(
    const _Float16* __restrict__ A, const _Float16* __restrict__ W,
    void* __restrict__ outp, int M, int K, int lda, int ldc,
    const float* __restrict__ bias, const float* __restrict__ bng,
    const float* __restrict__ bnb, const float* __restrict__ bias2,
    void* __restrict__ outp2)
{
    __shared__ _Float16 sA[3][128 * 32];
    __shared__ _Float16 sB[3][128 * 32];
    const int t = threadIdx.x;
    const int lane = t & 63, wid = t >> 6;

    int bx = blockIdx.x, by = blockIdx.y;
    {
        int nwg = gridDim.x * gridDim.y;
        if ((nwg & 7) == 0) {            // bijective XCD-chunked remap
            int orig = by * gridDim.x + bx;
            int cs = nwg >> 3;
            int wg = (orig & 7) * cs + (orig >> 3);
            by = wg % gridDim.y;
            bx = wg / gridDim.y;
        }
    }
    const int m0 = bx * 128, n0 = by * 128;
    const int kbase = blockIdx.z * K;        // split-K group (z=0 normally)

    const int sr = wid * 16 + (lane >> 2);   // staging tile row
    const int sc = (lane & 3) * 8;           // staging col offset (halves)
    const int stA0 = wid * 512;
    const int stA1 = 2048 + wid * 512;

    const _Float16 *aP0, *aP1;
    if constexpr (ALOAD == 0) {
        int r0 = m0 + sr;      if (r0 > M - 1) r0 = M - 1;
        int r1 = m0 + 64 + sr; if (r1 > M - 1) r1 = M - 1;
        aP0 = A + (size_t)r0 * lda + sc;
        aP1 = A + (size_t)r1 * lda + sc;
    } else {
        int m_ = m0 + sr; if (m_ > M - 1) m_ = M - 1;
        int b_ = m_ / 196, rem = m_ - b_ * 196, i_ = rem / 14, j_ = rem - i_ * 14;
        aP0 = A + ((size_t)(b_ * 784 + 2 * i_ * 28 + 2 * j_)) * 512 + sc;
        m_ = m0 + 64 + sr; if (m_ > M - 1) m_ = M - 1;
        b_ = m_ / 196; rem = m_ - b_ * 196; i_ = rem / 14; j_ = rem - i_ * 14;
        aP1 = A + ((size_t)(b_ * 784 + 2 * i_ * 28 + 2 * j_)) * 512 + sc;
    }
    const int ldw = (ALOAD == 2) ? lda : K;  // W row stride
    const _Float16* bP0 = W + (size_t)(n0 + sr) * ldw + sc;
    const _Float16* bP1 = W + (size_t)(n0 + 64 + sr) * ldw + sc;

    const int mw = wid & 1, nw = wid >> 1;
    const int pAoff = (mw * 64 + (lane & 15)) * 32 + (lane >> 4) * 8;
    const int pBoff = (nw * 64 + (lane & 15)) * 32 + (lane >> 4) * 8;

    f32x4 acc[4][4];
#pragma unroll
    for (int i = 0; i < 4; ++i)
#pragma unroll
        for (int j = 0; j < 4; ++j) acc[i][j] = (f32x4)(0.0f);

    auto aoff_of = [&](int k) -> int {
        if constexpr (ALOAD == 0) {
            return k;
        } else {
            int sub = k >> 9; int ky = sub >> 1, kx = sub & 1;
            return (ky * 28 + kx) * 512 + (k & 511);
        }
    };
    auto stage = [&](int ti, int buf) {
        int k = kbase + ti * 32;
        int aOff = aoff_of(k);
        async_copy16(aP0 + aOff, &sA[buf][stA0]);
        async_copy16(aP1 + aOff, &sA[buf][stA1]);
        async_copy16(bP0 + k, &sB[buf][stA0]);
        async_copy16(bP1 + k, &sB[buf][stA1]);
    };

    const int nt = K >> 5;
    stage(0, 0);
    if (nt > 1) { stage(1, 1); WAIT4_BARRIER(); }
    else        { WAIT0_BARRIER(); }

    int cur = 0;
    for (int i = 0; i < nt; ++i) {
        const _Float16* pA = &sA[cur][0] + pAoff;
        const _Float16* pB = &sB[cur][0] + pBoff;
        half8 aF[4], bF[4];
#pragma unroll
        for (int u = 0; u < 4; ++u) aF[u] = *(const half8*)(pA + u * 512);
#pragma unroll
        for (int u = 0; u < 4; ++u) bF[u] = *(const half8*)(pB + u * 512);

        const bool st = (i + 2 < nt);
        if (st) {
            int nb = cur + 2; if (nb >= 3) nb -= 3;
            stage(i + 2, nb);
        }
#pragma unroll
        for (int u = 0; u < 4; ++u)
#pragma unroll
            for (int j = 0; j < 4; ++j)
                acc[u][j] = __builtin_amdgcn_mfma_f32_16x16x32_f16(
                    aF[u], bF[j], acc[u][j], 0, 0, 0);

        if (i + 1 < nt) {
            if (st) WAIT4_BARRIER();
            else    WAIT0_BARRIER();
        }
        ++cur; if (cur == 3) cur = 0;
    }

    // epilogue: C/D layout col=lane&15, row=(lane>>4)*4+reg
    const int orow = m0 + mw * 64 + (lane >> 4) * 4;
    const int ocol = n0 + nw * 64 + (lane & 15);
#pragma unroll
    for (int j = 0; j < 4; ++j) {
        int col = ocol + j * 16;
        float bv = 0.0f, g = 0.0f, b2 = 0.0f;
        if constexpr (EPI == 4) {
            if (n0 >= 512) {           // r path (block-uniform branch)
                bv = bias2[col - 512];
                g = bng[col - 512] * BN_RSQ;
                b2 = bnb[col - 512];
            } else {
                bv = bias[col];
            }
        } else if constexpr (EPI != 3) {
            bv = bias[col];
        }
#pragma unroll
        for (int i = 0; i < 4; ++i) {
#pragma unroll
            for (int r = 0; r < 4; ++r) {
                int row = orow + i * 16 + r;
                if (row >= M) continue;
                float v = acc[i][j][r] + bv;
                if constexpr (EPI == 0) {
                    __builtin_nontemporal_store(
                        v, (float*)outp + (size_t)row * ldc + col);
                } else if constexpr (EPI == 3) {
                    ((float*)outp)[(size_t)blockIdx.z * KVE_STRIDE
                                   + (size_t)row * ldc + col] = v;
                } else if constexpr (EPI == 4) {
                    if (n0 >= 512) {
                        v = fmaxf(v * g + b2, 0.0f);
                        ((_Float16*)outp2)[(size_t)row * 128 + (col - 512)] =
                            (_Float16)v;
                    } else {
                        ((_Float16*)outp)[(size_t)row * ldc + col] = (_Float16)v;
                    }
                } else if constexpr (EPI == 5) {
                    if (n0 >= 512) {   // V^T scatter: vt[((b*8+h)*64+d)*224+m]
                        int hd_ = col - 512;
                        int h_ = hd_ >> 6, d_ = hd_ & 63;
                        int b_ = row / 196, m_ = row - b_ * 196;
                        ((_Float16*)outp2)[((size_t)((b_ * 8 + h_) * 64 + d_)) * 224
                                           + m_] = (_Float16)v;
                    } else {
                        ((_Float16*)outp)[(size_t)row * ldc + col] = (_Float16)v;
                    }
                } else {
                    ((_Float16*)outp)[(size_t)row * ldc + col] = (_Float16)v;
                }
            }
        }
    }
}

// =====================================================================
// conv3x3 split-K partial GEMM: 784 blocks 1-D; XCD-chunked swizzle.
// K-group bz covers k in [bz*1152, (bz+1)*1152). Plain fp32 partial stores
// (nt stores regressed WRITE_SIZE in R5). Frozen structure (local ceiling).
// =====================================================================
__global__ __launch_bounds__(256) void conv_splitk(
    const _Float16* __restrict__ A, const _Float16* __restrict__ W,
    float* __restrict__ partA, float* __restrict__ partB)
{
    __shared__ _Float16 sA[3][128 * 32];
    __shared__ _Float16 sB[3][128 * 32];
    const int t = threadIdx.x;
    const int lane = t & 63, wid = t >> 6;

    // bijective XCD-chunked remap: 784 = 8 * 98
    int orig = blockIdx.x;
    int wg = (orig & 7) * 98 + (orig >> 3);
    int bx = wg % 49;  int c = wg / 49;    // c in 0..15
    int by = c & 3,    bz = c >> 2;

    const int m0 = bx * 128, n0 = by * 128;
    const int kbase = bz * 1152;

    const int sr = wid * 16 + (lane >> 2);
    const int sc = (lane & 3) * 8;
    const int stA0 = wid * 512;
    const int stA1 = 2048 + wid * 512;

    int m_ = m0 + sr;
    int b_ = m_ / 784, rem = m_ - b_ * 784, y_ = rem / 28, x_ = rem - y_ * 28;
    const _Float16* aP0 = A + ((size_t)(b_ * 900 + (y_ + 1) * 30 + (x_ + 1))) * 512 + sc;
    m_ = m0 + 64 + sr;
    b_ = m_ / 784; rem = m_ - b_ * 784; y_ = rem / 28; x_ = rem - y_ * 28;
    const _Float16* aP1 = A + ((size_t)(b_ * 900 + (y_ + 1) * 30 + (x_ + 1))) * 512 + sc;
    const _Float16* bP0 = W + (size_t)(n0 + sr) * 4608 + sc;
    const _Float16* bP1 = W + (size_t)(n0 + 64 + sr) * 4608 + sc;

    const int mw = wid & 1, nw = wid >> 1;
    const int pAoff = (mw * 64 + (lane & 15)) * 32 + (lane >> 4) * 8;
    const int pBoff = (nw * 64 + (lane & 15)) * 32 + (lane >> 4) * 8;

    f32x4 acc[4][4];
#pragma unroll
    for (int i = 0; i < 4; ++i)
#pragma unroll
        for (int j = 0; j < 4; ++j) acc[i][j] = (f32x4)(0.0f);

    auto aoff_of = [&](int k) -> int {
        int sub = k >> 9; int s3 = sub / 3;
        int dy = s3 - 1, dx = sub - s3 * 3 - 1;
        return (dy * 30 + dx) * 512 + (k & 511);
    };
    auto stage = [&](int ti, int buf) {
        int k = kbase + ti * 32;
        int aOff = aoff_of(k);
        async_copy16(aP0 + aOff, &sA[buf][stA0]);
        async_copy16(aP1 + aOff, &sA[buf][stA1]);
        async_copy16(bP0 + k, &sB[buf][stA0]);
        async_copy16(bP1 + k, &sB[buf][stA1]);
    };

    const int nt = 36;   // 1152/32
    stage(0, 0);
    stage(1, 1);
    WAIT4_BARRIER();

    int cur = 0;
    for (int i = 0; i < nt; ++i) {
        const _Float16* pA = &sA[cur][0] + pAoff;
        const _Float16* pB = &sB[cur][0] + pBoff;
        half8 aF[4], bF[4];
#pragma unroll
        for (int u = 0; u < 4; ++u) aF[u] = *(const half8*)(pA + u * 512);
#pragma unroll
        for (int u = 0; u < 4; ++u) bF[u] = *(const half8*)(pB + u * 512);

        const bool st = (i + 2 < nt);
        if (st) {
            int nb = cur + 2; if (nb >= 3) nb -= 3;
            stage(i + 2, nb);
        }
#pragma unroll
        for (int u = 0; u < 4; ++u)
#pragma unroll
            for (int j = 0; j < 4; ++j)
                acc[u][j] = __builtin_amdgcn_mfma_f32_16x16x32_f16(
                    aF[u], bF[j], acc[u][j], 0, 0, 0);

        if (i + 1 < nt) {
            if (st) WAIT4_BARRIER();
            else    WAIT0_BARRIER();
        }
        ++cur; if (cur == 3) cur = 0;
    }

    float* dst = (bz < 2) ? (partA + (size_t)bz * PART_STRIDE)
                          : (partB + (size_t)(bz - 2) * PART_STRIDE);
    const int orow = m0 + mw * 64 + (lane >> 4) * 4;
    const int ocol = n0 + nw * 64 + (lane & 15);
#pragma unroll
    for (int j = 0; j < 4; ++j) {
#pragma unroll
        for (int i = 0; i < 4; ++i)
#pragma unroll
            for (int r = 0; r < 4; ++r)
                dst[(size_t)(orow + i * 16 + r) * 512 + ocol + j * 16] = acc[i][j][r];
    }
}

// =====================================================================
// FUSED conv epilogue + Haar IDWT. One block per output pixel (6272),
// 128 threads (channel c of 128). Computes fp16(relu(bn(sum partials)))
// for all 4 channel groups, writes dwtb16, and does the IDWT from the
// in-register fp16 values -> cat cols 512..639 (nt: read much later).
// =====================================================================
__global__ __launch_bounds__(128) void conv_epi_idwt(
    const float* __restrict__ pA, const float* __restrict__ pB,
    _Float16* __restrict__ dwtb, _Float16* __restrict__ cat,
    const float* __restrict__ bias, const float* __restrict__ bng,
    const float* __restrict__ bnb)
{
    int p = blockIdx.x;              // b*784 + i*28 + j
    int b = p / 784; int rem = p - b * 784;
    int i = rem / 28;  int j = rem - i * 28;
    int c = threadIdx.x;
    size_t base = (size_t)p * 512;
    _Float16 g16[4];
#pragma unroll
    for (int g = 0; g < 4; ++g) {
        int ch = g * 128 + c;
        float s = (pA[base + ch] + pA[PART_STRIDE + base + ch])
                + (pB[base + ch] + pB[PART_STRIDE + base + ch]);
        float v = (s + bias[ch]) * (bng[ch] * BN_RSQ) + bnb[ch];
        g16[g] = (_Float16)fmaxf(v, 0.0f);
        dwtb[base + ch] = g16[g];
    }
    _Float16 ll = g16[0], hl = g16[1], lh = g16[2], hh = g16[3];
    _Float16 h = (_Float16)0.5f;
    _Float16 p1 = (((ll - hl) - lh) + hh) * h;
    _Float16 p2 = (((ll - hl) + lh) - hh) * h;
    _Float16 p3 = (((ll + hl) - lh) - hh) * h;
    _Float16 p4 = (((ll + hl) + lh) + hh) * h;
    int y = 2 * i, x = 2 * j;
    size_t rb = (size_t)b * 3136;
    __builtin_nontemporal_store(p1, &cat[(rb + (size_t)y * 56 + x) * 640 + 512 + c]);
    __builtin_nontemporal_store(p3, &cat[(rb + (size_t)y * 56 + x + 1) * 640 + 512 + c]);
    __builtin_nontemporal_store(p2, &cat[(rb + (size_t)(y + 1) * 56 + x) * 640 + 512 + c]);
    __builtin_nontemporal_store(p4, &cat[(rb + (size_t)(y + 1) * 56 + x + 1) * 640 + 512 + c]);
}

// =====================================================================
// MEGA-PREP: all weight conversions + transposes + zero-fills, one launch.
// Block ranges (256 thr each, all exact):
//  [0,128)      q_w cvt -> qrw16            (32768 x8)
//  [128,160)    reduce_w cvt -> qrw16+262144 (8192 x8)
//  [160,416)    kv_w cvt -> kvw16           (65536 x8)
//  [416,576)    proj_w cvt -> pw16          (40960 x8)
//  [576,9792)   filter transpose -> wT      (2359296 scalar)
//  [9792,13888) kve transpose -> kT         (1048576 scalar)
//  [13888,15688) zero pad16                 (460800 x8)
//  [15688,16136) zero vt16                  (114688 x8)
// =====================================================================
__device__ __forceinline__ void cvt8_at(
    const float* __restrict__ s, _Float16* __restrict__ d, int i)
{
    const float4* sp = (const float4*)(s + (size_t)i * 8);
    float4 a = sp[0], b = sp[1];
    half8 h;
    h[0] = (_Float16)a.x; h[1] = (_Float16)a.y; h[2] = (_Float16)a.z; h[3] = (_Float16)a.w;
    h[4] = (_Float16)b.x; h[5] = (_Float16)b.y; h[6] = (_Float16)b.z; h[7] = (_Float16)b.w;
    *(half8*)(d + (size_t)i * 8) = h;
}

__global__ __launch_bounds__(256) void prep_kernel(
    const float* __restrict__ qw, const float* __restrict__ rw,
    const float* __restrict__ kvw, const float* __restrict__ pw,
    const float* __restrict__ fw, const float* __restrict__ kw,
    _Float16* __restrict__ qrw16, _Float16* __restrict__ kvw16,
    _Float16* __restrict__ pw16, _Float16* __restrict__ wT,
    _Float16* __restrict__ kT, _Float16* __restrict__ pad,
    _Float16* __restrict__ vt)
{
    int bid = blockIdx.x, tid = threadIdx.x;
    if (bid < 128) {
        cvt8_at(qw, qrw16, bid * 256 + tid);
    } else if (bid < 160) {
        cvt8_at(rw, qrw16 + 262144, (bid - 128) * 256 + tid);
    } else if (bid < 416) {
        cvt8_at(kvw, kvw16, (bid - 160) * 256 + tid);
    } else if (bid < 576) {
        cvt8_at(pw, pw16, (bid - 416) * 256 + tid);
    } else if (bid < 9792) {
        int idx = (bid - 576) * 256 + tid;
        int n = idx / 4608; int r = idx - n * 4608;
        int sub = r >> 9; int ci = r & 511;
        wT[idx] = (_Float16)fw[(size_t)n * 4608 + ci * 9 + sub];
    } else if (bid < 13888) {
        int idx = (bid - 9792) * 256 + tid;
        int n = idx >> 11; int r = idx & 2047;
        int sub = r >> 9; int ci = r & 511;
        kT[idx] = (_Float16)kw[((size_t)n << 11) + (ci << 2) + sub];
    } else if (bid < 15688) {
        int i = (bid - 13888) * 256 + tid;
        *(float4*)(pad + (size_t)i * 8) = make_float4(0.f, 0.f, 0.f, 0.f);
    } else {
        int i = (bid - 15688) * 256 + tid;
        *(float4*)(vt + (size_t)i * 8) = make_float4(0.f, 0.f, 0.f, 0.f);
    }
}

// x cvt stays standalone (large, fully parallel)
__global__ __launch_bounds__(256) void cvt_f32_f16(
    const float* __restrict__ s, _Float16* __restrict__ d, int n8)
{
    int i = blockIdx.x * 256 + threadIdx.x;
    if (i >= n8) return;
    cvt8_at(s, d, i);
}

// =====================================================================
// Haar DWT: rbuf16 (B,56,56,128 NHWC fp16) -> padded (B,30,30,512 NHWC fp16)
// =====================================================================
__global__ __launch_bounds__(128) void dwt_kernel(
    const _Float16* __restrict__ r, _Float16* __restrict__ pad)
{
    int bid = blockIdx.x;            // b*784 + i*28 + j
    int b = bid / 784; int rem = bid - b * 784;
    int i = rem / 28;  int j = rem - i * 28;
    int c = threadIdx.x;
    int y = 2 * i, x = 2 * j;
    size_t base = (size_t)b * 3136;
    _Float16 f1 = r[(base + (size_t)y * 56 + x) * 128 + c];
    _Float16 f2 = r[(base + (size_t)(y + 1) * 56 + x) * 128 + c];
    _Float16 f3 = r[(base + (size_t)y * 56 + (x + 1)) * 128 + c];
    _Float16 f4 = r[(base + (size_t)(y + 1) * 56 + (x + 1)) * 128 + c];
    _Float16 h = (_Float16)0.5f;
    _Float16 x1 = f1 * h, x2 = f2 * h, x3 = f3 * h, x4 = f4 * h;
    _Float16 ll = ((x1 + x2) + x3) + x4;
    _Float16 hl = (((-x1) - x2) + x3) + x4;
    _Float16 lh = (((-x1) + x2) - x3) + x4;
    _Float16 hh = ((x1 - x2) - x3) + x4;
    size_t ob = ((size_t)b * 900 + (size_t)(i + 1) * 30 + (j + 1)) * 512;
    pad[ob + c]       = ll;
    pad[ob + 128 + c] = hl;
    pad[ob + 256 + c] = lh;
    pad[ob + 384 + c] = hh;
}

// =====================================================================
// LayerNorm over C=512, fused kve split-K reduction. One wave per row.
// =====================================================================
__global__ __launch_bounds__(256) void ln_kernel(
    const float* __restrict__ part, _Float16* __restrict__ o,
    const float* __restrict__ g, const float* __restrict__ bta,
    const float* __restrict__ kvb)
{
    int wave = threadIdx.x >> 6;
    int lane = threadIdx.x & 63;
    int row = blockIdx.x * 4 + wave;            // 392*4 = 1568
    int c = lane * 8;
    const float* rp = part + (size_t)row * 512 + c;
    float v[8];
#pragma unroll
    for (int i = 0; i < 8; i += 4) {
        float4 a0 = *(const float4*)(rp + i);
        float4 a1 = *(const float4*)(rp + KVE_STRIDE + i);
        float4 a2 = *(const float4*)(rp + 2 * KVE_STRIDE + i);
        float4 a3 = *(const float4*)(rp + 3 * KVE_STRIDE + i);
        v[i + 0] = (a0.x + a1.x) + (a2.x + a3.x) + kvb[c + i + 0];
        v[i + 1] = (a0.y + a1.y) + (a2.y + a3.y) + kvb[c + i + 1];
        v[i + 2] = (a0.z + a1.z) + (a2.z + a3.z) + kvb[c + i + 2];
        v[i + 3] = (a0.w + a1.w) + (a2.w + a3.w) + kvb[c + i + 3];
    }
    float s = ((v[0] + v[1]) + (v[2] + v[3])) + ((v[4] + v[5]) + (v[6] + v[7]));
#pragma unroll
    for (int off = 32; off; off >>= 1) s += __shfl_xor(s, off);
    float mu = s * (1.0f / 512.0f);
    float sq = 0.0f;
#pragma unroll
    for (int i = 0; i < 8; ++i) { v[i] -= mu; sq += v[i] * v[i]; }
#pragma unroll
    for (int off = 32; off; off >>= 1) sq += __shfl_xor(sq, off);
    float inv = 1.0f / sqrtf(sq * (1.0f / 512.0f) + 1e-5f);
    half8 hv;
#pragma unroll
    for (int i = 0; i < 8; ++i) hv[i] = (_Float16)(v[i] * inv * g[c + i] + bta[c + i]);
    *(half8*)(o + (size_t)row * 512 + c) = hv;
}

// =====================================================================
// MFMA flash attention. Block = (b, h, 64 q-rows); 4 waves x 16 q-rows.
// Unnormalized softmax (scores tiny), one reduction at the end.
// =====================================================================
__global__ __launch_bounds__(256) void attn_mfma(
    const _Float16* __restrict__ q, const _Float16* __restrict__ kv,
    const _Float16* __restrict__ vt, _Float16* __restrict__ cat)
{
    __shared__ _Float16 sK[64][72];    // K[m][d]
    __shared__ _Float16 sVT[64][72];   // V^T[d][m-chunk]
    __shared__ _Float16 sP[4][16][40]; // per-wave P round-trip
    int bid = blockIdx.x;
    int qt = bid % 49;
    int h  = (bid / 49) & 7;
    int b  = bid / 392;
    int n0 = qt * 64;
    int t = threadIdx.x, lane = t & 63, wid = t >> 6;
    int quad = lane >> 4, l16 = lane & 15;

    const _Float16* qp = q + ((size_t)(b * 3136 + n0 + wid * 16 + l16)) * 512
                           + h * 64 + quad * 8;
    half8 aQ0 = *(const half8*)qp;
    half8 aQ1 = *(const half8*)(qp + 32);

    f32x4 oacc[4];
#pragma unroll
    for (int i = 0; i < 4; ++i) oacc[i] = (f32x4)(0.0f);
    float lsum[4] = {0.f, 0.f, 0.f, 0.f};

    const _Float16* vtb = vt + ((size_t)((b * 8 + h) * 64)) * 224;

    for (int c0 = 0; c0 < 224; c0 += 64) {
        __syncthreads();
#pragma unroll
        for (int it = 0; it < 2; ++it) {
            int slot = t + 256 * it;
            int row = slot >> 3, c8 = (slot & 7) * 8;
            int m = c0 + row; if (m > 195) m = 195;
            *(half8*)&sK[row][c8] =
                *(const half8*)(kv + ((size_t)(b * 196 + m)) * 1024 + h * 64 + c8);
        }
#pragma unroll
        for (int it = 0; it < 2; ++it) {
            int slot = t + 256 * it;
            int row = slot >> 3, c8 = (slot & 7) * 8;
            *(half8*)&sVT[row][c8] =
                *(const half8*)(vtb + (size_t)row * 224 + c0 + c8);
        }
        __syncthreads();

#pragma unroll
        for (int sc = 0; sc < 64; sc += 32) {
            half8 bk00 = *(const half8*)&sK[sc + l16][quad * 8];
            half8 bk01 = *(const half8*)&sK[sc + l16][32 + quad * 8];
            half8 bk10 = *(const half8*)&sK[sc + 16 + l16][quad * 8];
            half8 bk11 = *(const half8*)&sK[sc + 16 + l16][32 + quad * 8];
            f32x4 s0 = (f32x4)(0.0f), s1 = (f32x4)(0.0f);
            s0 = __builtin_amdgcn_mfma_f32_16x16x32_f16(aQ0, bk00, s0, 0, 0, 0);
            s0 = __builtin_amdgcn_mfma_f32_16x16x32_f16(aQ1, bk01, s0, 0, 0, 0);
            s1 = __builtin_amdgcn_mfma_f32_16x16x32_f16(aQ0, bk10, s1, 0, 0, 0);
            s1 = __builtin_amdgcn_mfma_f32_16x16x32_f16(aQ1, bk11, s1, 0, 0, 0);

            int col0 = c0 + sc + l16;
            float msk0 = (col0 < 196) ? 0.0f : -INFINITY;
            float msk1 = (col0 + 16 < 196) ? 0.0f : -INFINITY;
            float p0[4], p1[4];
#pragma unroll
            for (int r = 0; r < 4; ++r) {
                p0[r] = exp2f(s0[r] * SCL2 + msk0);
                p1[r] = exp2f(s1[r] * SCL2 + msk1);
                lsum[r] += p0[r] + p1[r];
            }
#pragma unroll
            for (int r = 0; r < 4; ++r) {
                sP[wid][quad * 4 + r][l16]      = (_Float16)p0[r];
                sP[wid][quad * 4 + r][16 + l16] = (_Float16)p1[r];
            }
            half8 aP = *(const half8*)&sP[wid][l16][quad * 8];
            half8 bv0 = *(const half8*)&sVT[l16][sc + quad * 8];
            half8 bv1 = *(const half8*)&sVT[16 + l16][sc + quad * 8];
            half8 bv2 = *(const half8*)&sVT[32 + l16][sc + quad * 8];
            half8 bv3 = *(const half8*)&sVT[48 + l16][sc + quad * 8];
            oacc[0] = __builtin_amdgcn_mfma_f32_16x16x32_f16(aP, bv0, oacc[0], 0, 0, 0);
            oacc[1] = __builtin_amdgcn_mfma_f32_16x16x32_f16(aP, bv1, oacc[1], 0, 0, 0);
            oacc[2] = __builtin_amdgcn_mfma_f32_16x16x32_f16(aP, bv2, oacc[2], 0, 0, 0);
            oacc[3] = __builtin_amdgcn_mfma_f32_16x16x32_f16(aP, bv3, oacc[3], 0, 0, 0);
        }
    }

    float inv[4];
#pragma unroll
    for (int r = 0; r < 4; ++r) {
        float s = lsum[r];
        s += __shfl_xor(s, 1);
        s += __shfl_xor(s, 2);
        s += __shfl_xor(s, 4);
        s += __shfl_xor(s, 8);
        inv[r] = 1.0f / s;
    }
#pragma unroll
    for (int r = 0; r < 4; ++r) {
        size_t rowoff = ((size_t)(b * 3136 + n0 + wid * 16 + quad * 4 + r)) * 640
                        + h * 64 + l16;
#pragma unroll
        for (int tv = 0; tv < 4; ++tv)
            cat[rowoff + tv * 16] = (_Float16)(oacc[tv][r] * inv[r]);
    }
}

// =====================================================================
extern "C" void kernel_launch(void* const* d_in, const int* in_sizes, int n_in,
                              void* d_out, int out_size, void* d_ws, size_t ws_size,
                              hipStream_t stream)
{
    const float* x           = (const float*)d_in[0];
    const float* reduce_w    = (const float*)d_in[3];
    const float* reduce_b    = (const float*)d_in[4];
    const float* reduce_g    = (const float*)d_in[5];
    const float* reduce_beta = (const float*)d_in[6];
    const float* filter_w    = (const float*)d_in[7];
    const float* filter_b    = (const float*)d_in[8];
    const float* filter_g    = (const float*)d_in[9];
    const float* filter_beta = (const float*)d_in[10];
    const float* q_w         = (const float*)d_in[11];
    const float* q_b         = (const float*)d_in[12];
    const float* ln_g        = (const float*)d_in[13];
    const float* ln_b        = (const float*)d_in[14];
    const float* kv_w        = (const float*)d_in[15];
    const float* kv_b        = (const float*)d_in[16];
    const float* kve_w       = (const float*)d_in[17];
    const float* kve_b       = (const float*)d_in[18];
    const float* proj_w      = (const float*)d_in[19];
    const float* proj_b      = (const float*)d_in[20];
    float* out = (float*)d_out;
    _Float16* hws = (_Float16*)d_ws;

    _Float16* x16    = hws + OFF_X16;
    _Float16* q16    = hws + OFF_Q16;
    _Float16* cat16  = hws + OFF_CAT;
    _Float16* r16    = hws + OFF_R16;
    _Float16* pad16  = hws + OFF_PAD;
    _Float16* dwtb16 = hws + OFF_DWTB;
    _Float16* qrw16  = hws + OFF_QRW;
    _Float16* ln16   = hws + OFF_LN16;
    _Float16* kv16   = hws + OFF_KV16;
    _Float16* wT16   = hws + OFF_WT;
    _Float16* kT16   = hws + OFF_KT;
    _Float16* kvw16  = hws + OFF_KVW;
    _Float16* pw16   = hws + OFF_PW;
    _Float16* vt16   = hws + OFF_VT;
    float*    partA  = (float*)(hws + OFF_X16);   // conv partials 0,1 (x16 dead)
    float*    partB  = (float*)(hws + OFF_PART);  // conv partials 2,3
    float*    kvepart = (float*)(hws + OFF_X16);  // kve partials 0..3

    // one mega-prep launch: weight cvts + transposes + zero-fills
    prep_kernel<<<dim3(16136), dim3(256), 0, stream>>>(
        q_w, reduce_w, kv_w, proj_w, filter_w, kve_w,
        qrw16, kvw16, pw16, wT16, kT16, pad16, vt16);

    // x -> fp16
    cvt_f32_f16<<<dim3(6272), dim3(256), 0, stream>>>(x, x16, 1605632);

    // fused q + r gemm: cols 0..511 -> q16 (+q_b), cols 512..639 -> BN+ReLU r16
    gemm16<0, 4><<<dim3(196, 5), dim3(256), 0, stream>>>(
        x16, qrw16, q16, 25088, 512, 512, 512, q_b, reduce_g, reduce_beta,
        reduce_b, r16);

    // DWT -> padded 30x30x512
    dwt_kernel<<<dim3(6272), dim3(128), 0, stream>>>(r16, pad16);

    // 3x3 conv split-K x4 (x16 now dead; partials 0,1 overwrite it)
    conv_splitk<<<dim3(784), dim3(256), 0, stream>>>(pad16, wT16, partA, partB);

    // fused conv epilogue + IDWT (writes dwtb16 and cat cols 512..639)
    conv_epi_idwt<<<dim3(6272), dim3(128), 0, stream>>>(
        partA, partB, dwtb16, cat16, filter_b, filter_g, filter_beta);

    // kve 2x2 s2 conv, split-K x4 -> fp32 partials (reuses partA region)
    gemm16<2, 3><<<dim3(13, 4, 4), dim3(256), 0, stream>>>(
        dwtb16, kT16, kvepart, 1568, 512, 2048, 512, nullptr, nullptr, nullptr,
        nullptr, nullptr);

    // LayerNorm (fused kve partial-sum + bias) -> fp16
    ln_kernel<<<dim3(392), dim3(256), 0, stream>>>(kvepart, ln16, ln_g, ln_b, kve_b);

    // kv gemm: cols 0..511 -> kv16 K-half; cols 512..1023 -> V^T scatter to vt16
    gemm16<0, 5><<<dim3(13, 8), dim3(256), 0, stream>>>(
        ln16, kvw16, kv16, 1568, 512, 512, 1024, kv_b, nullptr, nullptr,
        nullptr, vt16);

    // attention -> cat cols 0..511
    attn_mfma<<<dim3(3136), dim3(256), 0, stream>>>(q16, kv16, vt16, cat16);

    // out = cat @ proj_w.T + proj_b  (fp32, nt store)
    gemm16<0, 0><<<dim3(196, 4), dim3(256), 0, stream>>>(
        cat16, pw16, out, 25088, 640, 640, 512, proj_b, nullptr, nullptr,
        nullptr, nullptr);
}